// Round 9
// baseline (422.743 us; speedup 1.0000x reference)
//
#include <hip/hip_runtime.h>
#include <math.h>

#define BATCH 16
#define TWIN 8
#define SEQIN 129
#define DMODEL 192
#define GLEN 2048           // TWIN*256
#define NH 24
#define HD 32
#define DS 128
#define NCC 896             // conv channels (x | B); dt handled separately
#define MTOT (BATCH*GLEN)   // 32768
#define NVALID (BATCH*TWIN*128) // 16384 rows with real input (s<128)
#define PADK 40             // GEMM LDS row pitch in bf16

typedef __attribute__((ext_vector_type(8))) short bf16x8;
typedef __attribute__((ext_vector_type(4))) float f32x4;

__device__ __forceinline__ float softplus_f(float x){
  return x > 20.f ? x : log1pf(expf(x));
}
__device__ __forceinline__ float silu_f(float x){
  return x / (1.f + __expf(-x));
}
__device__ __forceinline__ unsigned short tobf16(float f){
  union { float f; unsigned u; } v; v.f = f;
  unsigned r = v.u + 0x7FFF + ((v.u >> 16) & 1);
  return (unsigned short)(r >> 16);
}
__device__ __forceinline__ float frombf16(unsigned short u){
  union { unsigned u; float f; } v; v.u = ((unsigned)u) << 16; return v.f;
}

// Build PE-added input for the 16384 REAL rows only (s<128) + bf16 weight copy.
__global__ __launch_bounds__(256) void k_build_xg(const float* __restrict__ in,
    const float* __restrict__ inw, float* __restrict__ xg,
    unsigned short* __restrict__ xh, unsigned short* __restrict__ wh){
  int idx = blockIdx.x*256 + threadIdx.x;
  if (idx < NVALID*DMODEL){
    int d = idx % DMODEL;
    int v = idx / DMODEL;
    int s = v & 127;
    int t = (v >> 7) & 7;
    int b = v >> 10;
    float val = in[((size_t)(b*TWIN + t)*SEQIN + (s+1))*DMODEL + d];
    float div = expf(-(float)(d & ~1) * (logf(10000.f)/(float)DMODEL));
    float ang = (float)t * div;
    val += (d & 1) ? cosf(ang) : sinf(ang);
    size_t row = (size_t)b*GLEN + t*256 + s;
    xg[row*DMODEL + d] = val;
    xh[row*DMODEL + d] = tobf16(val);
  } else {
    int j = idx - NVALID*DMODEL;
    if (j < NCC*DMODEL) wh[j] = tobf16(inw[(size_t)768*DMODEL + j]);
  }
}

// PE-projection table: ptab[t][e] = sum_d PE[t][d]*W[row(e)][d]
// e<896 -> conv channel e (W row 768+e); e in [896,920) -> dt head (W row 1792+h).
// Inputs rounded to bf16 to match the MFMA path's rounding.
__global__ __launch_bounds__(256) void k_petab(const float* __restrict__ inw,
    float* __restrict__ ptab){
  int t = blockIdx.x;
  for (int e = threadIdx.x; e < 920; e += 256){
    int row = (e < 896) ? (768 + e) : (1792 + (e - 896));
    float s = 0.f;
    for (int d = 0; d < DMODEL; d++){
      float div = expf(-(float)(d & ~1) * (logf(10000.f)/(float)DMODEL));
      float ang = (float)t * div;
      float pe = (d & 1) ? cosf(ang) : sinf(ang);
      s += frombf16(tobf16(pe)) * frombf16(tobf16(inw[(size_t)row*DMODEL + d]));
    }
    ptab[t*920 + e] = s;
  }
}

// Fill the padded rows (s>=128) of projh and dtraw from ptab.
__global__ __launch_bounds__(256) void k_pad(const float* __restrict__ ptab,
    unsigned short* __restrict__ projh, float* __restrict__ dtraw){
  int bx = blockIdx.x;            // 256 blocks
  int bt = bx >> 1, half = bx & 1;
  int b = bt >> 3, t = bt & 7;
  int tid = threadIdx.x;
  __shared__ float pt[920];
  for (int e = tid; e < 920; e += 256) pt[e] = ptab[t*920 + e];
  __syncthreads();
  size_t g0 = (size_t)b*GLEN + t*256 + 128 + half*64;
  // projh: 64 rows x 896 bf16 (as ushort4)
  for (int i = tid; i < 64*224; i += 256){
    int r = i / 224, c4 = (i - r*224)*4;
    ushort4 v;
    v.x = tobf16(pt[c4+0]); v.y = tobf16(pt[c4+1]);
    v.z = tobf16(pt[c4+2]); v.w = tobf16(pt[c4+3]);
    *(ushort4*)&projh[(g0 + r)*NCC + c4] = v;
  }
  // dtraw: 64 rows x 24 f32
  for (int i = tid; i < 64*NH; i += 256){
    int r = i / NH, h = i - r*NH;
    dtraw[(g0 + r)*NH + h] = pt[896 + h];
  }
}

// MFMA GEMM over REAL row-tiles only: m0 = blockIdx.x*256 (offsets 0..127 valid).
__global__ __launch_bounds__(256) void k_gemm_mfma(const unsigned short* __restrict__ xh,
    const unsigned short* __restrict__ wh, unsigned short* __restrict__ projh){
  __shared__ unsigned short As[128*PADK];
  __shared__ unsigned short Bs[128*PADK];
  int tid = threadIdx.x;
  int m0 = blockIdx.x*256, n0 = blockIdx.y*128;
  int wid = tid >> 6, lane = tid & 63;
  int wm = (wid >> 1)*64, wn = (wid & 1)*64;
  int quad = lane >> 4, lm = lane & 15;
  int sr = tid >> 2, sq = tid & 3;
  f32x4 acc[4][4];
  #pragma unroll
  for (int i=0;i<4;i++)
    #pragma unroll
    for (int j=0;j<4;j++) acc[i][j] = (f32x4){0.f,0.f,0.f,0.f};
  for (int k0 = 0; k0 < DMODEL; k0 += 32){
    #pragma unroll
    for (int half=0; half<2; half++){
      int r = sr + half*64;
      *(bf16x8*)&As[r*PADK + sq*8] =
        *(const bf16x8*)&xh[(size_t)(m0+r)*DMODEL + k0 + sq*8];
      *(bf16x8*)&Bs[r*PADK + sq*8] =
        *(const bf16x8*)&wh[(size_t)(n0+r)*DMODEL + k0 + sq*8];
    }
    __syncthreads();
    bf16x8 aF[4], bF[4];
    #pragma unroll
    for (int i=0;i<4;i++){
      aF[i] = *(const bf16x8*)&As[(wm + i*16 + lm)*PADK + quad*8];
      bF[i] = *(const bf16x8*)&Bs[(wn + i*16 + lm)*PADK + quad*8];
    }
    #pragma unroll
    for (int i=0;i<4;i++)
      #pragma unroll
      for (int j=0;j<4;j++)
        acc[i][j] = __builtin_amdgcn_mfma_f32_16x16x32_bf16(aF[i], bF[j], acc[i][j], 0,0,0);
    __syncthreads();
  }
  #pragma unroll
  for (int i=0;i<4;i++){
    #pragma unroll
    for (int r=0;r<4;r++){
      int m = m0 + wm + i*16 + quad*4 + r;
      unsigned short* dst = projh + (size_t)m*NCC + n0 + wn + lm;
      #pragma unroll
      for (int j=0;j<4;j++)
        dst[j*16] = tobf16(acc[i][j][r]);
    }
  }
}

// fp32 GEMM for the 24 dt channels, REAL row-tiles only.
__global__ __launch_bounds__(256) void k_gemm_dt(const float* __restrict__ xg,
    const float* __restrict__ inw, float* __restrict__ dtraw){
  __shared__ float As[16][64];
  __shared__ float Bs[16][64];
  int tid = threadIdx.x;
  int p = blockIdx.x >> 1, q = blockIdx.x & 1;
  int m0 = p*256 + q*64;
  int ty = tid >> 4, tx = tid & 15;
  int lr = tid >> 2, lq = tid & 3;
  float acc[4][4] = {};
  for (int k0 = 0; k0 < DMODEL; k0 += 16){
    float4 av = *(const float4*)(xg + (size_t)(m0+lr)*DMODEL + k0 + lq*4);
    As[lq*4+0][lr] = av.x; As[lq*4+1][lr] = av.y;
    As[lq*4+2][lr] = av.z; As[lq*4+3][lr] = av.w;
    float4 bv = make_float4(0.f,0.f,0.f,0.f);
    if (lr < NH) bv = *(const float4*)(inw + (size_t)(1792+lr)*DMODEL + k0 + lq*4);
    Bs[lq*4+0][lr] = bv.x; Bs[lq*4+1][lr] = bv.y;
    Bs[lq*4+2][lr] = bv.z; Bs[lq*4+3][lr] = bv.w;
    __syncthreads();
    #pragma unroll
    for (int kk = 0; kk < 16; kk++){
      float4 a = *(const float4*)&As[kk][ty*4];
      float4 bq = *(const float4*)&Bs[kk][tx*4];
      float avr[4] = {a.x, a.y, a.z, a.w};
      float bvr[4] = {bq.x, bq.y, bq.z, bq.w};
      #pragma unroll
      for (int i=0;i<4;i++)
        #pragma unroll
        for (int j=0;j<4;j++)
          acc[i][j] += avr[i]*bvr[j];
    }
    __syncthreads();
  }
  #pragma unroll
  for (int i=0;i<4;i++){
    int m = m0 + ty*4 + i;
    #pragma unroll
    for (int j=0;j<4;j++){
      int n = tx*4 + j;
      if (n < NH) dtraw[(size_t)m*NH + n] = acc[i][j];
    }
  }
}

// Per (b,h): w[g] = exp(csum_total - csum[g]) * dt[g]
__global__ __launch_bounds__(256) void k_scan_w(const float* __restrict__ dtraw,
    const float* __restrict__ dt_bias, const float* __restrict__ A_log,
    float* __restrict__ wbuf){
  int h = blockIdx.x, b = blockIdx.y;
  int tid = threadIdx.x;
  float dtb = dt_bias[h];
  float negA = -expf(A_log[h]);
  float dtv[8], pre[8];
  float run = 0.f;
  size_t base = (size_t)b*GLEN;
  #pragma unroll
  for (int i=0;i<8;i++){
    int g = tid*8 + i;
    float v = dtraw[(base + g)*NH + h];
    float dt = softplus_f(v + dtb);
    run += dt * negA;
    dtv[i] = dt; pre[i] = run;
  }
  __shared__ float s[256];
  float tot_thread = run;
  s[tid] = run;
  __syncthreads();
  for (int off=1; off<256; off<<=1){
    float v = (tid>=off) ? s[tid-off] : 0.f;
    __syncthreads();
    s[tid] += v;
    __syncthreads();
  }
  float total = s[255];
  float excl = s[tid] - tot_thread;
  #pragma unroll
  for (int i=0;i<8;i++){
    int g = tid*8+i;
    float w = expf(total - (excl + pre[i])) * dtv[i];
    wbuf[(base + g)*NH + h] = w;
  }
}

// One wave per 8-position strip: conv history in registers, weights per wave.
__global__ __launch_bounds__(256) void k_fold(const unsigned short* __restrict__ projh,
    const float* __restrict__ conv_w, const float* __restrict__ conv_b,
    const float* __restrict__ wbuf, float* __restrict__ yB){
  int wave = threadIdx.x >> 6, lane = threadIdx.x & 63;
  int strip = blockIdx.x*4 + wave;     // 0..255
  int b = blockIdx.y;
  int g0 = strip*8;
  size_t rbase = (size_t)b*GLEN;
  float cb[7][2], cw[7][2][4];
  #pragma unroll
  for (int k=0;k<7;k++){
    int c = 2*lane + 128*k;
    float2 t = *(const float2*)&conv_b[c];
    cb[k][0]=t.x; cb[k][1]=t.y;
    float4 w0 = *(const float4*)&conv_w[c*4];
    float4 w1 = *(const float4*)&conv_w[(c+1)*4];
    cw[k][0][0]=w0.x; cw[k][0][1]=w0.y; cw[k][0][2]=w0.z; cw[k][0][3]=w0.w;
    cw[k][1][0]=w1.x; cw[k][1][1]=w1.y; cw[k][1][2]=w1.z; cw[k][1][3]=w1.w;
  }
  float h0[7][2], h1[7][2], h2[7][2];
  #pragma unroll
  for (int k=0;k<7;k++){
    h0[k][0]=h0[k][1]=h1[k][0]=h1[k][1]=h2[k][0]=h2[k][1]=0.f;
  }
  if (g0 >= 3){
    #pragma unroll
    for (int k=0;k<7;k++){
      int c = 2*lane + 128*k;
      ushort2 p0 = *(const ushort2*)&projh[(rbase+g0-3)*NCC + c];
      ushort2 p1 = *(const ushort2*)&projh[(rbase+g0-2)*NCC + c];
      ushort2 p2 = *(const ushort2*)&projh[(rbase+g0-1)*NCC + c];
      h0[k][0]=frombf16(p0.x); h0[k][1]=frombf16(p0.y);
      h1[k][0]=frombf16(p1.x); h1[k][1]=frombf16(p1.y);
      h2[k][0]=frombf16(p2.x); h2[k][1]=frombf16(p2.y);
    }
  }
  #pragma unroll
  for (int i=0;i<8;i++){
    size_t row = rbase + g0 + i;
    float wreg = (lane < NH) ? wbuf[row*NH + lane] : 0.f;
    float cur[7][2];
    #pragma unroll
    for (int k=0;k<7;k++){
      int c = 2*lane + 128*k;
      ushort2 pv = *(const ushort2*)&projh[row*NCC + c];
      cur[k][0]=frombf16(pv.x); cur[k][1]=frombf16(pv.y);
    }
    float py0=0.f, py1=0.f, b0v=0.f, b1v=0.f;
    #pragma unroll
    for (int k=0;k<7;k++){
      float a0 = cb[k][0] + h0[k][0]*cw[k][0][0] + h1[k][0]*cw[k][0][1]
                          + h2[k][0]*cw[k][0][2] + cur[k][0]*cw[k][0][3];
      float a1 = cb[k][1] + h0[k][1]*cw[k][1][0] + h1[k][1]*cw[k][1][1]
                          + h2[k][1]*cw[k][1][2] + cur[k][1]*cw[k][1][3];
      float s0 = silu_f(a0), s1 = silu_f(a1);
      if (k < 6){
        float wh_ = __shfl(wreg, (lane>>4) + 4*k, 64);
        py0 += wh_*s0; py1 += wh_*s1;
      } else { b0v = s0; b1v = s1; }
    }
    py0 += __shfl_xor(py0, 16, 64); py0 += __shfl_xor(py0, 32, 64);
    py1 += __shfl_xor(py1, 16, 64); py1 += __shfl_xor(py1, 32, 64);
    float* dst = yB + row*160;
    if (lane < 16) *(float2*)&dst[2*lane] = make_float2(py0, py1);
    *(float2*)&dst[32 + 2*lane] = make_float2(b0v, b1v);
    #pragma unroll
    for (int k=0;k<7;k++){
      h0[k][0]=h1[k][0]; h0[k][1]=h1[k][1];
      h1[k][0]=h2[k][0]; h1[k][1]=h2[k][1];
      h2[k][0]=cur[k][0]; h2[k][1]=cur[k][1];
    }
  }
}

// Chunk partials: partial[b][t][sub][32][128] over 64 positions each
__global__ __launch_bounds__(256) void k_partial(const float* __restrict__ yB,
    float* __restrict__ partial){
  int t = blockIdx.x & 7, b = blockIdx.x >> 3, sub = blockIdx.y;
  int tid = threadIdx.x;
  __shared__ float buf[8*160];
  int p0 = (tid >> 5) * 4;
  int n0 = (tid & 31) * 4;
  float acc[4][4] = {};
  size_t rbase = (size_t)b*GLEN;
  int gstart = t*256 + sub*64;
  for (int gb = gstart; gb < gstart+64; gb += 8){
    for (int idx = tid; idx < 8*160; idx += 256)
      buf[idx] = yB[(rbase+gb)*160 + idx];
    __syncthreads();
    #pragma unroll
    for (int gi=0; gi<8; gi++){
      float4 yv = *(const float4*)&buf[gi*160 + p0];
      float4 bv = *(const float4*)&buf[gi*160 + 32 + n0];
      float ya[4] = {yv.x,yv.y,yv.z,yv.w};
      float ba[4] = {bv.x,bv.y,bv.z,bv.w};
      #pragma unroll
      for (int i=0;i<4;i++)
        #pragma unroll
        for (int j=0;j<4;j++)
          acc[i][j] += ya[i]*ba[j];
    }
    __syncthreads();
  }
  size_t pb = (((size_t)(b*TWIN + t))*4 + sub)*4096;
  #pragma unroll
  for (int i=0;i<4;i++)
    #pragma unroll
    for (int j=0;j<4;j++)
      partial[pb + (p0+i)*128 + n0+j] = acc[i][j];
}

// Suffix-sum partials over t
__global__ __launch_bounds__(256) void k_suffix(const float* __restrict__ partial,
    float* __restrict__ feat){
  int b = blockIdx.y;
  int e = blockIdx.x*256 + threadIdx.x;   // 0..4095
  float s = 0.f;
  for (int t = TWIN-1; t >= 0; t--){
    size_t pb = ((size_t)(b*TWIN + t))*4*4096;
    #pragma unroll
    for (int sub=0; sub<4; sub++) s += partial[pb + sub*4096 + e];
    feat[((size_t)(b*TWIN + t))*4096 + e] = s;
  }
}

// Boundary corrections for t>0
__global__ __launch_bounds__(256) void k_correct(const unsigned short* __restrict__ projh,
    const float* __restrict__ conv_w, const float* __restrict__ conv_b,
    const float* __restrict__ wbuf, float* __restrict__ feat){
  int t = blockIdx.x + 1, b = blockIdx.y;
  int tid = threadIdx.x;
  __shared__ float xsw[NCC], xsg[NCC];
  __shared__ float wv[NH];
  __shared__ float bufw[3*160], bufg[3*160];
  size_t rbase = (size_t)b*GLEN;
  int g0 = t*256;
  for (int gi=0; gi<3; gi++){
    int g = g0 + gi;
    if (tid < NH) wv[tid] = wbuf[(rbase+g)*NH + tid];
    for (int c = tid; c < NCC; c += 256){
      float aw = conv_b[c], ag = conv_b[c];
      #pragma unroll
      for (int k=0;k<4;k++){
        int gp = g - 3 + k;
        float term = frombf16(projh[(rbase+gp)*NCC + c]) * conv_w[c*4+k];
        ag += term;
        if (gp >= g0) aw += term;
      }
      xsw[c] = silu_f(aw);
      xsg[c] = silu_f(ag);
    }
    __syncthreads();
    if (tid < 32){
      float yw = 0.f, yg = 0.f;
      #pragma unroll
      for (int h=0;h<NH;h++){ yw += wv[h]*xsw[h*32+tid]; yg += wv[h]*xsg[h*32+tid]; }
      bufw[gi*160 + tid] = yw;
      bufg[gi*160 + tid] = yg;
    } else if (tid < 160){
      bufw[gi*160 + tid] = xsw[768 + tid - 32];
      bufg[gi*160 + tid] = xsg[768 + tid - 32];
    }
    __syncthreads();
  }
  int p0 = (tid >> 5) * 4;
  int n0 = (tid & 31) * 4;
  float acc[4][4] = {};
  #pragma unroll
  for (int gi=0; gi<3; gi++){
    float4 ywv = *(const float4*)&bufw[gi*160 + p0];
    float4 bwv = *(const float4*)&bufw[gi*160 + 32 + n0];
    float4 ygv = *(const float4*)&bufg[gi*160 + p0];
    float4 bgv = *(const float4*)&bufg[gi*160 + 32 + n0];
    float yw[4]={ywv.x,ywv.y,ywv.z,ywv.w}, bw[4]={bwv.x,bwv.y,bwv.z,bwv.w};
    float yg[4]={ygv.x,ygv.y,ygv.z,ygv.w}, bg[4]={bgv.x,bgv.y,bgv.z,bgv.w};
    #pragma unroll
    for (int i=0;i<4;i++)
      #pragma unroll
      for (int j=0;j<4;j++)
        acc[i][j] += yw[i]*bw[j] - yg[i]*bg[j];
  }
  size_t fb = (size_t)(b*TWIN + t)*4096;
  #pragma unroll
  for (int i=0;i<4;i++)
    #pragma unroll
    for (int j=0;j<4;j++)
      feat[fb + (p0+i)*128 + n0+j] += acc[i][j];
}

// out[bt][k] = feat[bt] . cls_w[k] + cls_b[k]; one wave per (bt,k)
__global__ __launch_bounds__(256) void k_classifier(const float* __restrict__ feat,
    const float* __restrict__ cls_w, const float* __restrict__ cls_b,
    float* __restrict__ out){
  int bt = blockIdx.x;
  int wave = threadIdx.x >> 6, lane = threadIdx.x & 63;
  int k = blockIdx.y*4 + wave;
  if (k >= 100) return;
  const float* f  = feat  + (size_t)bt*4096;
  const float* wr = cls_w + (size_t)k*4096;
  float s = 0.f;
  #pragma unroll
  for (int j0 = 0; j0 < 4096; j0 += 256){
    int j = j0 + lane*4;
    float4 fv = *(const float4*)(f + j);
    float4 wv = *(const float4*)(wr + j);
    s += fv.x*wv.x + fv.y*wv.y + fv.z*wv.z + fv.w*wv.w;
  }
  #pragma unroll
  for (int off=32; off>0; off>>=1) s += __shfl_down(s, off, 64);
  if (lane==0) out[bt*100 + k] = s + cls_b[k];
}

extern "C" void kernel_launch(void* const* d_in, const int* in_sizes, int n_in,
                              void* d_out, int out_size, void* d_ws, size_t ws_size,
                              hipStream_t stream){
  const float* inputs    = (const float*)d_in[0];
  const float* in_proj_w = (const float*)d_in[1];
  const float* conv_w    = (const float*)d_in[2];
  const float* conv_b    = (const float*)d_in[3];
  const float* dt_bias   = (const float*)d_in[4];
  const float* A_log     = (const float*)d_in[5];
  const float* cls_w     = (const float*)d_in[6];
  const float* cls_b     = (const float*)d_in[7];
  float* out = (float*)d_out;

  float* xg            = (float*)d_ws;                          // MTOT*192 f32
  unsigned short* projh= (unsigned short*)(xg + (size_t)MTOT*DMODEL); // MTOT*896 bf16
  float* dtraw         = (float*)(projh + (size_t)MTOT*NCC);    // MTOT*24 f32
  float* wbuf          = dtraw + (size_t)MTOT*NH;               // MTOT*24 f32
  unsigned short* xh   = (unsigned short*)(wbuf + (size_t)MTOT*NH); // MTOT*192 bf16
  unsigned short* wh   = xh + (size_t)MTOT*DMODEL;              // NCC*192 bf16
  float* yB            = (float*)(wh + (size_t)NCC*DMODEL);     // MTOT*160 f32
  float* partial       = yB + (size_t)MTOT*160;                 // 512*4096 f32
  float* feat          = partial + (size_t)512*4096;            // 128*4096 f32
  float* ptab          = feat + (size_t)128*4096;               // 8*920 f32
  size_t need = (size_t)((char*)(ptab + 8*920) - (char*)d_ws);
  if (ws_size < need) return;

  k_build_xg   <<<((NVALID+NCC)*DMODEL + 255)/256, 256, 0, stream>>>(inputs, in_proj_w, xg, xh, wh);
  k_petab      <<<TWIN, 256, 0, stream>>>(in_proj_w, ptab);
  k_pad        <<<256, 256, 0, stream>>>(ptab, projh, dtraw);
  k_gemm_mfma  <<<dim3(MTOT/256, NCC/128), 256, 0, stream>>>(xh, wh, projh);
  k_gemm_dt    <<<dim3(NVALID/64, 1), 256, 0, stream>>>(xg, in_proj_w, dtraw);
  k_scan_w     <<<dim3(NH, BATCH), 256, 0, stream>>>(dtraw, dt_bias, A_log, wbuf);
  k_fold       <<<dim3(GLEN/8/4, BATCH), 256, 0, stream>>>(projh, conv_w, conv_b, wbuf, yB);
  k_partial    <<<dim3(BATCH*TWIN, 4), 256, 0, stream>>>(yB, partial);
  k_suffix     <<<dim3(16, BATCH), 256, 0, stream>>>(partial, feat);
  k_correct    <<<dim3(TWIN-1, BATCH), 256, 0, stream>>>(projh, conv_w, conv_b, wbuf, feat);
  k_classifier <<<dim3(BATCH*TWIN, 25), 256, 0, stream>>>(feat, cls_w, cls_b, out);
}

// Round 10
// 224.101 us; speedup vs baseline: 1.8864x; 1.8864x over previous
//
#include <hip/hip_runtime.h>
#include <math.h>

#define BATCH 16
#define TWIN 8
#define SEQIN 129
#define DMODEL 192
#define GLEN 2048           // TWIN*256
#define NH 24
#define HD 32
#define DS 128
#define NCC 896             // conv channels (x | B); dt handled separately
#define MTOT (BATCH*GLEN)   // 32768
#define NVALID (BATCH*TWIN*128) // 16384 rows with real input (s<128)
#define PADK 40             // GEMM LDS row pitch in bf16

typedef __attribute__((ext_vector_type(8))) short bf16x8;
typedef __attribute__((ext_vector_type(4))) float f32x4;

__device__ __forceinline__ float softplus_f(float x){
  return x > 20.f ? x : log1pf(expf(x));
}
__device__ __forceinline__ float silu_f(float x){
  return x / (1.f + __expf(-x));
}
__device__ __forceinline__ unsigned short tobf16(float f){
  union { float f; unsigned u; } v; v.f = f;
  unsigned r = v.u + 0x7FFF + ((v.u >> 16) & 1);
  return (unsigned short)(r >> 16);
}
__device__ __forceinline__ float frombf16(unsigned short u){
  union { unsigned u; float f; } v; v.u = ((unsigned)u) << 16; return v.f;
}

// Build PE-added input for the 16384 REAL rows only (s<128) + bf16 weight copy.
__global__ __launch_bounds__(256) void k_build_xg(const float* __restrict__ in,
    const float* __restrict__ inw, float* __restrict__ xg,
    unsigned short* __restrict__ xh, unsigned short* __restrict__ wh){
  int idx = blockIdx.x*256 + threadIdx.x;
  if (idx < NVALID*DMODEL){
    int d = idx % DMODEL;
    int v = idx / DMODEL;
    int s = v & 127;
    int t = (v >> 7) & 7;
    int b = v >> 10;
    float val = in[((size_t)(b*TWIN + t)*SEQIN + (s+1))*DMODEL + d];
    float div = expf(-(float)(d & ~1) * (logf(10000.f)/(float)DMODEL));
    float ang = (float)t * div;
    val += (d & 1) ? cosf(ang) : sinf(ang);
    size_t row = (size_t)b*GLEN + t*256 + s;
    xg[row*DMODEL + d] = val;
    xh[row*DMODEL + d] = tobf16(val);
  } else {
    int j = idx - NVALID*DMODEL;
    if (j < NCC*DMODEL) wh[j] = tobf16(inw[(size_t)768*DMODEL + j]);
  }
}

// PE-projection table: ptab[t][e] = sum_d PE[t][d]*W[row(e)][d]
// Grid (TWIN, 8): block computes 115-e slice. PE computed once into LDS.
// Inputs rounded to bf16 to match the MFMA path's rounding.
__global__ __launch_bounds__(256) void k_petab(const float* __restrict__ inw,
    float* __restrict__ ptab){
  int t = blockIdx.x;
  int eslice = blockIdx.y;            // 0..7, 115 e-values each
  int tid = threadIdx.x;
  __shared__ float pe[DMODEL];
  if (tid < DMODEL){
    int d = tid;
    float div = expf(-(float)(d & ~1) * (logf(10000.f)/(float)DMODEL));
    float ang = (float)t * div;
    pe[d] = frombf16(tobf16((d & 1) ? cosf(ang) : sinf(ang)));
  }
  __syncthreads();
  int e0 = eslice*115;
  int e1 = min(920, e0 + 115);
  for (int e = e0 + tid; e < e1; e += 256){
    int row = (e < 896) ? (768 + e) : (1792 + (e - 896));
    const float* wr = inw + (size_t)row*DMODEL;
    float s = 0.f;
    #pragma unroll 4
    for (int d = 0; d < DMODEL; d++)
      s += pe[d] * frombf16(tobf16(wr[d]));
    ptab[t*920 + e] = s;
  }
}

// Fill the padded rows (s>=128) of projh and dtraw from ptab.
__global__ __launch_bounds__(256) void k_pad(const float* __restrict__ ptab,
    unsigned short* __restrict__ projh, float* __restrict__ dtraw){
  int bx = blockIdx.x;            // 256 blocks
  int bt = bx >> 1, half = bx & 1;
  int b = bt >> 3, t = bt & 7;
  int tid = threadIdx.x;
  __shared__ float pt[920];
  for (int e = tid; e < 920; e += 256) pt[e] = ptab[t*920 + e];
  __syncthreads();
  size_t g0 = (size_t)b*GLEN + t*256 + 128 + half*64;
  // projh: 64 rows x 896 bf16 (as ushort4)
  for (int i = tid; i < 64*224; i += 256){
    int r = i / 224, c4 = (i - r*224)*4;
    ushort4 v;
    v.x = tobf16(pt[c4+0]); v.y = tobf16(pt[c4+1]);
    v.z = tobf16(pt[c4+2]); v.w = tobf16(pt[c4+3]);
    *(ushort4*)&projh[(g0 + r)*NCC + c4] = v;
  }
  // dtraw: 64 rows x 24 f32
  for (int i = tid; i < 64*NH; i += 256){
    int r = i / NH, h = i - r*NH;
    dtraw[(g0 + r)*NH + h] = pt[896 + h];
  }
}

// MFMA GEMM over REAL row-tiles only: m0 = blockIdx.x*256 (offsets 0..127 valid).
__global__ __launch_bounds__(256) void k_gemm_mfma(const unsigned short* __restrict__ xh,
    const unsigned short* __restrict__ wh, unsigned short* __restrict__ projh){
  __shared__ unsigned short As[128*PADK];
  __shared__ unsigned short Bs[128*PADK];
  int tid = threadIdx.x;
  int m0 = blockIdx.x*256, n0 = blockIdx.y*128;
  int wid = tid >> 6, lane = tid & 63;
  int wm = (wid >> 1)*64, wn = (wid & 1)*64;
  int quad = lane >> 4, lm = lane & 15;
  int sr = tid >> 2, sq = tid & 3;
  f32x4 acc[4][4];
  #pragma unroll
  for (int i=0;i<4;i++)
    #pragma unroll
    for (int j=0;j<4;j++) acc[i][j] = (f32x4){0.f,0.f,0.f,0.f};
  for (int k0 = 0; k0 < DMODEL; k0 += 32){
    #pragma unroll
    for (int half=0; half<2; half++){
      int r = sr + half*64;
      *(bf16x8*)&As[r*PADK + sq*8] =
        *(const bf16x8*)&xh[(size_t)(m0+r)*DMODEL + k0 + sq*8];
      *(bf16x8*)&Bs[r*PADK + sq*8] =
        *(const bf16x8*)&wh[(size_t)(n0+r)*DMODEL + k0 + sq*8];
    }
    __syncthreads();
    bf16x8 aF[4], bF[4];
    #pragma unroll
    for (int i=0;i<4;i++){
      aF[i] = *(const bf16x8*)&As[(wm + i*16 + lm)*PADK + quad*8];
      bF[i] = *(const bf16x8*)&Bs[(wn + i*16 + lm)*PADK + quad*8];
    }
    #pragma unroll
    for (int i=0;i<4;i++)
      #pragma unroll
      for (int j=0;j<4;j++)
        acc[i][j] = __builtin_amdgcn_mfma_f32_16x16x32_bf16(aF[i], bF[j], acc[i][j], 0,0,0);
    __syncthreads();
  }
  #pragma unroll
  for (int i=0;i<4;i++){
    #pragma unroll
    for (int r=0;r<4;r++){
      int m = m0 + wm + i*16 + quad*4 + r;
      unsigned short* dst = projh + (size_t)m*NCC + n0 + wn + lm;
      #pragma unroll
      for (int j=0;j<4;j++)
        dst[j*16] = tobf16(acc[i][j][r]);
    }
  }
}

// fp32 GEMM for the 24 dt channels, REAL row-tiles only.
__global__ __launch_bounds__(256) void k_gemm_dt(const float* __restrict__ xg,
    const float* __restrict__ inw, float* __restrict__ dtraw){
  __shared__ float As[16][64];
  __shared__ float Bs[16][64];
  int tid = threadIdx.x;
  int p = blockIdx.x >> 1, q = blockIdx.x & 1;
  int m0 = p*256 + q*64;
  int ty = tid >> 4, tx = tid & 15;
  int lr = tid >> 2, lq = tid & 3;
  float acc[4][4] = {};
  for (int k0 = 0; k0 < DMODEL; k0 += 16){
    float4 av = *(const float4*)(xg + (size_t)(m0+lr)*DMODEL + k0 + lq*4);
    As[lq*4+0][lr] = av.x; As[lq*4+1][lr] = av.y;
    As[lq*4+2][lr] = av.z; As[lq*4+3][lr] = av.w;
    float4 bv = make_float4(0.f,0.f,0.f,0.f);
    if (lr < NH) bv = *(const float4*)(inw + (size_t)(1792+lr)*DMODEL + k0 + lq*4);
    Bs[lq*4+0][lr] = bv.x; Bs[lq*4+1][lr] = bv.y;
    Bs[lq*4+2][lr] = bv.z; Bs[lq*4+3][lr] = bv.w;
    __syncthreads();
    #pragma unroll
    for (int kk = 0; kk < 16; kk++){
      float4 a = *(const float4*)&As[kk][ty*4];
      float4 bq = *(const float4*)&Bs[kk][tx*4];
      float avr[4] = {a.x, a.y, a.z, a.w};
      float bvr[4] = {bq.x, bq.y, bq.z, bq.w};
      #pragma unroll
      for (int i=0;i<4;i++)
        #pragma unroll
        for (int j=0;j<4;j++)
          acc[i][j] += avr[i]*bvr[j];
    }
    __syncthreads();
  }
  #pragma unroll
  for (int i=0;i<4;i++){
    int m = m0 + ty*4 + i;
    #pragma unroll
    for (int j=0;j<4;j++){
      int n = tx*4 + j;
      if (n < NH) dtraw[(size_t)m*NH + n] = acc[i][j];
    }
  }
}

// Per (b,h): w[g] = exp(csum_total - csum[g]) * dt[g]
__global__ __launch_bounds__(256) void k_scan_w(const float* __restrict__ dtraw,
    const float* __restrict__ dt_bias, const float* __restrict__ A_log,
    float* __restrict__ wbuf){
  int h = blockIdx.x, b = blockIdx.y;
  int tid = threadIdx.x;
  float dtb = dt_bias[h];
  float negA = -expf(A_log[h]);
  float dtv[8], pre[8];
  float run = 0.f;
  size_t base = (size_t)b*GLEN;
  #pragma unroll
  for (int i=0;i<8;i++){
    int g = tid*8 + i;
    float v = dtraw[(base + g)*NH + h];
    float dt = softplus_f(v + dtb);
    run += dt * negA;
    dtv[i] = dt; pre[i] = run;
  }
  __shared__ float s[256];
  float tot_thread = run;
  s[tid] = run;
  __syncthreads();
  for (int off=1; off<256; off<<=1){
    float v = (tid>=off) ? s[tid-off] : 0.f;
    __syncthreads();
    s[tid] += v;
    __syncthreads();
  }
  float total = s[255];
  float excl = s[tid] - tot_thread;
  #pragma unroll
  for (int i=0;i<8;i++){
    int g = tid*8+i;
    float w = expf(total - (excl + pre[i])) * dtv[i];
    wbuf[(base + g)*NH + h] = w;
  }
}

// One wave per 8-position strip: conv history in registers, weights per wave.
__global__ __launch_bounds__(256) void k_fold(const unsigned short* __restrict__ projh,
    const float* __restrict__ conv_w, const float* __restrict__ conv_b,
    const float* __restrict__ wbuf, float* __restrict__ yB){
  int wave = threadIdx.x >> 6, lane = threadIdx.x & 63;
  int strip = blockIdx.x*4 + wave;     // 0..255
  int b = blockIdx.y;
  int g0 = strip*8;
  size_t rbase = (size_t)b*GLEN;
  float cb[7][2], cw[7][2][4];
  #pragma unroll
  for (int k=0;k<7;k++){
    int c = 2*lane + 128*k;
    float2 t = *(const float2*)&conv_b[c];
    cb[k][0]=t.x; cb[k][1]=t.y;
    float4 w0 = *(const float4*)&conv_w[c*4];
    float4 w1 = *(const float4*)&conv_w[(c+1)*4];
    cw[k][0][0]=w0.x; cw[k][0][1]=w0.y; cw[k][0][2]=w0.z; cw[k][0][3]=w0.w;
    cw[k][1][0]=w1.x; cw[k][1][1]=w1.y; cw[k][1][2]=w1.z; cw[k][1][3]=w1.w;
  }
  float h0[7][2], h1[7][2], h2[7][2];
  #pragma unroll
  for (int k=0;k<7;k++){
    h0[k][0]=h0[k][1]=h1[k][0]=h1[k][1]=h2[k][0]=h2[k][1]=0.f;
  }
  if (g0 >= 3){
    #pragma unroll
    for (int k=0;k<7;k++){
      int c = 2*lane + 128*k;
      ushort2 p0 = *(const ushort2*)&projh[(rbase+g0-3)*NCC + c];
      ushort2 p1 = *(const ushort2*)&projh[(rbase+g0-2)*NCC + c];
      ushort2 p2 = *(const ushort2*)&projh[(rbase+g0-1)*NCC + c];
      h0[k][0]=frombf16(p0.x); h0[k][1]=frombf16(p0.y);
      h1[k][0]=frombf16(p1.x); h1[k][1]=frombf16(p1.y);
      h2[k][0]=frombf16(p2.x); h2[k][1]=frombf16(p2.y);
    }
  }
  #pragma unroll
  for (int i=0;i<8;i++){
    size_t row = rbase + g0 + i;
    float wreg = (lane < NH) ? wbuf[row*NH + lane] : 0.f;
    float cur[7][2];
    #pragma unroll
    for (int k=0;k<7;k++){
      int c = 2*lane + 128*k;
      ushort2 pv = *(const ushort2*)&projh[row*NCC + c];
      cur[k][0]=frombf16(pv.x); cur[k][1]=frombf16(pv.y);
    }
    float py0=0.f, py1=0.f, b0v=0.f, b1v=0.f;
    #pragma unroll
    for (int k=0;k<7;k++){
      float a0 = cb[k][0] + h0[k][0]*cw[k][0][0] + h1[k][0]*cw[k][0][1]
                          + h2[k][0]*cw[k][0][2] + cur[k][0]*cw[k][0][3];
      float a1 = cb[k][1] + h0[k][1]*cw[k][1][0] + h1[k][1]*cw[k][1][1]
                          + h2[k][1]*cw[k][1][2] + cur[k][1]*cw[k][1][3];
      float s0 = silu_f(a0), s1 = silu_f(a1);
      if (k < 6){
        float wh_ = __shfl(wreg, (lane>>4) + 4*k, 64);
        py0 += wh_*s0; py1 += wh_*s1;
      } else { b0v = s0; b1v = s1; }
    }
    py0 += __shfl_xor(py0, 16, 64); py0 += __shfl_xor(py0, 32, 64);
    py1 += __shfl_xor(py1, 16, 64); py1 += __shfl_xor(py1, 32, 64);
    float* dst = yB + row*160;
    if (lane < 16) *(float2*)&dst[2*lane] = make_float2(py0, py1);
    *(float2*)&dst[32 + 2*lane] = make_float2(b0v, b1v);
    #pragma unroll
    for (int k=0;k<7;k++){
      h0[k][0]=h1[k][0]; h0[k][1]=h1[k][1];
      h1[k][0]=h2[k][0]; h1[k][1]=h2[k][1];
      h2[k][0]=cur[k][0]; h2[k][1]=cur[k][1];
    }
  }
}

// Chunk partials: partial[b][t][sub][32][128] over 64 positions each
__global__ __launch_bounds__(256) void k_partial(const float* __restrict__ yB,
    float* __restrict__ partial){
  int t = blockIdx.x & 7, b = blockIdx.x >> 3, sub = blockIdx.y;
  int tid = threadIdx.x;
  __shared__ float buf[8*160];
  int p0 = (tid >> 5) * 4;
  int n0 = (tid & 31) * 4;
  float acc[4][4] = {};
  size_t rbase = (size_t)b*GLEN;
  int gstart = t*256 + sub*64;
  for (int gb = gstart; gb < gstart+64; gb += 8){
    for (int idx = tid; idx < 8*160; idx += 256)
      buf[idx] = yB[(rbase+gb)*160 + idx];
    __syncthreads();
    #pragma unroll
    for (int gi=0; gi<8; gi++){
      float4 yv = *(const float4*)&buf[gi*160 + p0];
      float4 bv = *(const float4*)&buf[gi*160 + 32 + n0];
      float ya[4] = {yv.x,yv.y,yv.z,yv.w};
      float ba[4] = {bv.x,bv.y,bv.z,bv.w};
      #pragma unroll
      for (int i=0;i<4;i++)
        #pragma unroll
        for (int j=0;j<4;j++)
          acc[i][j] += ya[i]*ba[j];
    }
    __syncthreads();
  }
  size_t pb = (((size_t)(b*TWIN + t))*4 + sub)*4096;
  #pragma unroll
  for (int i=0;i<4;i++)
    #pragma unroll
    for (int j=0;j<4;j++)
      partial[pb + (p0+i)*128 + n0+j] = acc[i][j];
}

// Suffix-sum partials over t
__global__ __launch_bounds__(256) void k_suffix(const float* __restrict__ partial,
    float* __restrict__ feat){
  int b = blockIdx.y;
  int e = blockIdx.x*256 + threadIdx.x;   // 0..4095
  float s = 0.f;
  for (int t = TWIN-1; t >= 0; t--){
    size_t pb = ((size_t)(b*TWIN + t))*4*4096;
    #pragma unroll
    for (int sub=0; sub<4; sub++) s += partial[pb + sub*4096 + e];
    feat[((size_t)(b*TWIN + t))*4096 + e] = s;
  }
}

// Boundary corrections for t>0
__global__ __launch_bounds__(256) void k_correct(const unsigned short* __restrict__ projh,
    const float* __restrict__ conv_w, const float* __restrict__ conv_b,
    const float* __restrict__ wbuf, float* __restrict__ feat){
  int t = blockIdx.x + 1, b = blockIdx.y;
  int tid = threadIdx.x;
  __shared__ float xsw[NCC], xsg[NCC];
  __shared__ float wv[NH];
  __shared__ float bufw[3*160], bufg[3*160];
  size_t rbase = (size_t)b*GLEN;
  int g0 = t*256;
  for (int gi=0; gi<3; gi++){
    int g = g0 + gi;
    if (tid < NH) wv[tid] = wbuf[(rbase+g)*NH + tid];
    for (int c = tid; c < NCC; c += 256){
      float aw = conv_b[c], ag = conv_b[c];
      #pragma unroll
      for (int k=0;k<4;k++){
        int gp = g - 3 + k;
        float term = frombf16(projh[(rbase+gp)*NCC + c]) * conv_w[c*4+k];
        ag += term;
        if (gp >= g0) aw += term;
      }
      xsw[c] = silu_f(aw);
      xsg[c] = silu_f(ag);
    }
    __syncthreads();
    if (tid < 32){
      float yw = 0.f, yg = 0.f;
      #pragma unroll
      for (int h=0;h<NH;h++){ yw += wv[h]*xsw[h*32+tid]; yg += wv[h]*xsg[h*32+tid]; }
      bufw[gi*160 + tid] = yw;
      bufg[gi*160 + tid] = yg;
    } else if (tid < 160){
      bufw[gi*160 + tid] = xsw[768 + tid - 32];
      bufg[gi*160 + tid] = xsg[768 + tid - 32];
    }
    __syncthreads();
  }
  int p0 = (tid >> 5) * 4;
  int n0 = (tid & 31) * 4;
  float acc[4][4] = {};
  #pragma unroll
  for (int gi=0; gi<3; gi++){
    float4 ywv = *(const float4*)&bufw[gi*160 + p0];
    float4 bwv = *(const float4*)&bufw[gi*160 + 32 + n0];
    float4 ygv = *(const float4*)&bufg[gi*160 + p0];
    float4 bgv = *(const float4*)&bufg[gi*160 + 32 + n0];
    float yw[4]={ywv.x,ywv.y,ywv.z,ywv.w}, bw[4]={bwv.x,bwv.y,bwv.z,bwv.w};
    float yg[4]={ygv.x,ygv.y,ygv.z,ygv.w}, bg[4]={bgv.x,bgv.y,bgv.z,bgv.w};
    #pragma unroll
    for (int i=0;i<4;i++)
      #pragma unroll
      for (int j=0;j<4;j++)
        acc[i][j] += yw[i]*bw[j] - yg[i]*bg[j];
  }
  size_t fb = (size_t)(b*TWIN + t)*4096;
  #pragma unroll
  for (int i=0;i<4;i++)
    #pragma unroll
    for (int j=0;j<4;j++)
      feat[fb + (p0+i)*128 + n0+j] += acc[i][j];
}

// out[bt][k] = feat[bt] . cls_w[k] + cls_b[k]; one wave per (bt,k)
__global__ __launch_bounds__(256) void k_classifier(const float* __restrict__ feat,
    const float* __restrict__ cls_w, const float* __restrict__ cls_b,
    float* __restrict__ out){
  int bt = blockIdx.x;
  int wave = threadIdx.x >> 6, lane = threadIdx.x & 63;
  int k = blockIdx.y*4 + wave;
  if (k >= 100) return;
  const float* f  = feat  + (size_t)bt*4096;
  const float* wr = cls_w + (size_t)k*4096;
  float s = 0.f;
  #pragma unroll
  for (int j0 = 0; j0 < 4096; j0 += 256){
    int j = j0 + lane*4;
    float4 fv = *(const float4*)(f + j);
    float4 wv = *(const float4*)(wr + j);
    s += fv.x*wv.x + fv.y*wv.y + fv.z*wv.z + fv.w*wv.w;
  }
  #pragma unroll
  for (int off=32; off>0; off>>=1) s += __shfl_down(s, off, 64);
  if (lane==0) out[bt*100 + k] = s + cls_b[k];
}

extern "C" void kernel_launch(void* const* d_in, const int* in_sizes, int n_in,
                              void* d_out, int out_size, void* d_ws, size_t ws_size,
                              hipStream_t stream){
  const float* inputs    = (const float*)d_in[0];
  const float* in_proj_w = (const float*)d_in[1];
  const float* conv_w    = (const float*)d_in[2];
  const float* conv_b    = (const float*)d_in[3];
  const float* dt_bias   = (const float*)d_in[4];
  const float* A_log     = (const float*)d_in[5];
  const float* cls_w     = (const float*)d_in[6];
  const float* cls_b     = (const float*)d_in[7];
  float* out = (float*)d_out;

  float* xg            = (float*)d_ws;                          // MTOT*192 f32
  unsigned short* projh= (unsigned short*)(xg + (size_t)MTOT*DMODEL); // MTOT*896 bf16
  float* dtraw         = (float*)(projh + (size_t)MTOT*NCC);    // MTOT*24 f32
  float* wbuf          = dtraw + (size_t)MTOT*NH;               // MTOT*24 f32
  unsigned short* xh   = (unsigned short*)(wbuf + (size_t)MTOT*NH); // MTOT*192 bf16
  unsigned short* wh   = xh + (size_t)MTOT*DMODEL;              // NCC*192 bf16
  float* yB            = (float*)(wh + (size_t)NCC*DMODEL);     // MTOT*160 f32
  float* partial       = yB + (size_t)MTOT*160;                 // 512*4096 f32
  float* feat          = partial + (size_t)512*4096;            // 128*4096 f32
  float* ptab          = feat + (size_t)128*4096;               // 8*920 f32
  size_t need = (size_t)((char*)(ptab + 8*920) - (char*)d_ws);
  if (ws_size < need) return;

  k_build_xg   <<<((NVALID+NCC)*DMODEL + 255)/256, 256, 0, stream>>>(inputs, in_proj_w, xg, xh, wh);
  k_petab      <<<dim3(TWIN, 8), 256, 0, stream>>>(in_proj_w, ptab);
  k_pad        <<<256, 256, 0, stream>>>(ptab, projh, dtraw);
  k_gemm_mfma  <<<dim3(MTOT/256, NCC/128), 256, 0, stream>>>(xh, wh, projh);
  k_gemm_dt    <<<dim3(NVALID/64, 1), 256, 0, stream>>>(xg, in_proj_w, dtraw);
  k_scan_w     <<<dim3(NH, BATCH), 256, 0, stream>>>(dtraw, dt_bias, A_log, wbuf);
  k_fold       <<<dim3(GLEN/8/4, BATCH), 256, 0, stream>>>(projh, conv_w, conv_b, wbuf, yB);
  k_partial    <<<dim3(BATCH*TWIN, 4), 256, 0, stream>>>(yB, partial);
  k_suffix     <<<dim3(16, BATCH), 256, 0, stream>>>(partial, feat);
  k_correct    <<<dim3(TWIN-1, BATCH), 256, 0, stream>>>(projh, conv_w, conv_b, wbuf, feat);
  k_classifier <<<dim3(BATCH*TWIN, 25), 256, 0, stream>>>(feat, cls_w, cls_b, out);
}

// Round 11
// 206.992 us; speedup vs baseline: 2.0423x; 1.0827x over previous
//
#include <hip/hip_runtime.h>
#include <math.h>

#define BATCH 16
#define TWIN 8
#define SEQIN 129
#define DMODEL 192
#define GLEN 2048           // TWIN*256
#define NH 24
#define HD 32
#define DS 128
#define NCC 896             // conv channels (x | B); dt handled separately
#define MTOT (BATCH*GLEN)   // 32768
#define NVALID (BATCH*TWIN*128) // 16384 rows with real input (s<128)
#define PADK 40             // GEMM LDS row pitch in bf16

typedef __attribute__((ext_vector_type(8))) short bf16x8;
typedef __attribute__((ext_vector_type(4))) float f32x4;

__device__ __forceinline__ float softplus_f(float x){
  return x > 20.f ? x : log1pf(expf(x));
}
__device__ __forceinline__ float silu_f(float x){
  return x / (1.f + __expf(-x));
}
__device__ __forceinline__ unsigned short tobf16(float f){
  union { float f; unsigned u; } v; v.f = f;
  unsigned r = v.u + 0x7FFF + ((v.u >> 16) & 1);
  return (unsigned short)(r >> 16);
}
__device__ __forceinline__ float frombf16(unsigned short u){
  union { unsigned u; float f; } v; v.u = ((unsigned)u) << 16; return v.f;
}

// Build PE-added input for the 16384 REAL rows only (s<128) + bf16 weight copy.
__global__ __launch_bounds__(256) void k_build_xg(const float* __restrict__ in,
    const float* __restrict__ inw, float* __restrict__ xg,
    unsigned short* __restrict__ xh, unsigned short* __restrict__ wh){
  int idx = blockIdx.x*256 + threadIdx.x;
  if (idx < NVALID*DMODEL){
    int d = idx % DMODEL;
    int v = idx / DMODEL;
    int s = v & 127;
    int t = (v >> 7) & 7;
    int b = v >> 10;
    float val = in[((size_t)(b*TWIN + t)*SEQIN + (s+1))*DMODEL + d];
    float div = expf(-(float)(d & ~1) * (logf(10000.f)/(float)DMODEL));
    float ang = (float)t * div;
    val += (d & 1) ? cosf(ang) : sinf(ang);
    size_t row = (size_t)b*GLEN + t*256 + s;
    xg[row*DMODEL + d] = val;
    xh[row*DMODEL + d] = tobf16(val);
  } else {
    int j = idx - NVALID*DMODEL;
    if (j < NCC*DMODEL) wh[j] = tobf16(inw[(size_t)768*DMODEL + j]);
  }
}

// PE-projection table: ptab[t][e] = sum_d PE[t][d]*W[row(e)][d]
__global__ __launch_bounds__(256) void k_petab(const float* __restrict__ inw,
    float* __restrict__ ptab){
  int t = blockIdx.x;
  int eslice = blockIdx.y;            // 0..7
  int tid = threadIdx.x;
  __shared__ float pe[DMODEL];
  if (tid < DMODEL){
    int d = tid;
    float div = expf(-(float)(d & ~1) * (logf(10000.f)/(float)DMODEL));
    float ang = (float)t * div;
    pe[d] = frombf16(tobf16((d & 1) ? cosf(ang) : sinf(ang)));
  }
  __syncthreads();
  int e0 = eslice*115;
  int e1 = min(920, e0 + 115);
  for (int e = e0 + tid; e < e1; e += 256){
    int row = (e < 896) ? (768 + e) : (1792 + (e - 896));
    const float* wr = inw + (size_t)row*DMODEL;
    float s = 0.f;
    #pragma unroll 4
    for (int d = 0; d < DMODEL; d++)
      s += pe[d] * frombf16(tobf16(wr[d]));
    ptab[t*920 + e] = s;
  }
}

// Fill ONLY the padded projh rows the pipeline actually reads
// (s in {128..135} for fold's boundary strip, {252..255} for next window's
// conv history) + ALL padded dtraw rows (full csum needs them).
__global__ __launch_bounds__(256) void k_pad(const float* __restrict__ ptab,
    unsigned short* __restrict__ projh, float* __restrict__ dtraw){
  int bt = blockIdx.x;            // 0..127
  int b = bt >> 3, t = bt & 7;
  int tid = threadIdx.x;
  __shared__ float pt[920];
  for (int e = tid; e < 920; e += 256) pt[e] = ptab[t*920 + e];
  __syncthreads();
  size_t base = (size_t)b*GLEN + t*256;
  for (int i = tid; i < 12*224; i += 256){
    int r = i / 224, c4 = (i - r*224)*4;
    int s = (r < 8) ? (128 + r) : (244 + r);   // r=8..11 -> 252..255
    ushort4 v;
    v.x = tobf16(pt[c4+0]); v.y = tobf16(pt[c4+1]);
    v.z = tobf16(pt[c4+2]); v.w = tobf16(pt[c4+3]);
    *(ushort4*)&projh[(base + s)*NCC + c4] = v;
  }
  for (int i = tid; i < 128*NH; i += 256){
    int r = i / NH, h = i - r*NH;
    dtraw[(base + 128 + r)*NH + h] = pt[896 + h];
  }
}

// MFMA GEMM over REAL row-tiles only: m0 = blockIdx.x*256 (offsets 0..127 valid).
__global__ __launch_bounds__(256) void k_gemm_mfma(const unsigned short* __restrict__ xh,
    const unsigned short* __restrict__ wh, unsigned short* __restrict__ projh){
  __shared__ unsigned short As[128*PADK];
  __shared__ unsigned short Bs[128*PADK];
  int tid = threadIdx.x;
  int m0 = blockIdx.x*256, n0 = blockIdx.y*128;
  int wid = tid >> 6, lane = tid & 63;
  int wm = (wid >> 1)*64, wn = (wid & 1)*64;
  int quad = lane >> 4, lm = lane & 15;
  int sr = tid >> 2, sq = tid & 3;
  f32x4 acc[4][4];
  #pragma unroll
  for (int i=0;i<4;i++)
    #pragma unroll
    for (int j=0;j<4;j++) acc[i][j] = (f32x4){0.f,0.f,0.f,0.f};
  for (int k0 = 0; k0 < DMODEL; k0 += 32){
    #pragma unroll
    for (int half=0; half<2; half++){
      int r = sr + half*64;
      *(bf16x8*)&As[r*PADK + sq*8] =
        *(const bf16x8*)&xh[(size_t)(m0+r)*DMODEL + k0 + sq*8];
      *(bf16x8*)&Bs[r*PADK + sq*8] =
        *(const bf16x8*)&wh[(size_t)(n0+r)*DMODEL + k0 + sq*8];
    }
    __syncthreads();
    bf16x8 aF[4], bF[4];
    #pragma unroll
    for (int i=0;i<4;i++){
      aF[i] = *(const bf16x8*)&As[(wm + i*16 + lm)*PADK + quad*8];
      bF[i] = *(const bf16x8*)&Bs[(wn + i*16 + lm)*PADK + quad*8];
    }
    #pragma unroll
    for (int i=0;i<4;i++)
      #pragma unroll
      for (int j=0;j<4;j++)
        acc[i][j] = __builtin_amdgcn_mfma_f32_16x16x32_bf16(aF[i], bF[j], acc[i][j], 0,0,0);
    __syncthreads();
  }
  #pragma unroll
  for (int i=0;i<4;i++){
    #pragma unroll
    for (int r=0;r<4;r++){
      int m = m0 + wm + i*16 + quad*4 + r;
      unsigned short* dst = projh + (size_t)m*NCC + n0 + wn + lm;
      #pragma unroll
      for (int j=0;j<4;j++)
        dst[j*16] = tobf16(acc[i][j][r]);
    }
  }
}

// fp32 GEMM for the 24 dt channels, REAL row-tiles only.
__global__ __launch_bounds__(256) void k_gemm_dt(const float* __restrict__ xg,
    const float* __restrict__ inw, float* __restrict__ dtraw){
  __shared__ float As[16][64];
  __shared__ float Bs[16][64];
  int tid = threadIdx.x;
  int p = blockIdx.x >> 1, q = blockIdx.x & 1;
  int m0 = p*256 + q*64;
  int ty = tid >> 4, tx = tid & 15;
  int lr = tid >> 2, lq = tid & 3;
  float acc[4][4] = {};
  for (int k0 = 0; k0 < DMODEL; k0 += 16){
    float4 av = *(const float4*)(xg + (size_t)(m0+lr)*DMODEL + k0 + lq*4);
    As[lq*4+0][lr] = av.x; As[lq*4+1][lr] = av.y;
    As[lq*4+2][lr] = av.z; As[lq*4+3][lr] = av.w;
    float4 bv = make_float4(0.f,0.f,0.f,0.f);
    if (lr < NH) bv = *(const float4*)(inw + (size_t)(1792+lr)*DMODEL + k0 + lq*4);
    Bs[lq*4+0][lr] = bv.x; Bs[lq*4+1][lr] = bv.y;
    Bs[lq*4+2][lr] = bv.z; Bs[lq*4+3][lr] = bv.w;
    __syncthreads();
    #pragma unroll
    for (int kk = 0; kk < 16; kk++){
      float4 a = *(const float4*)&As[kk][ty*4];
      float4 bq = *(const float4*)&Bs[kk][tx*4];
      float avr[4] = {a.x, a.y, a.z, a.w};
      float bvr[4] = {bq.x, bq.y, bq.z, bq.w};
      #pragma unroll
      for (int i=0;i<4;i++)
        #pragma unroll
        for (int j=0;j<4;j++)
          acc[i][j] += avr[i]*bvr[j];
    }
    __syncthreads();
  }
  #pragma unroll
  for (int i=0;i<4;i++){
    int m = m0 + ty*4 + i;
    #pragma unroll
    for (int j=0;j<4;j++){
      int n = tx*4 + j;
      if (n < NH) dtraw[(size_t)m*NH + n] = acc[i][j];
    }
  }
}

// Per (b,h): w[g] = exp(csum_total - csum[g]) * dt[g].
// Also emits Wsum[b][t][h] = sum_{s>=136} w (const-region weight per window).
__global__ __launch_bounds__(256) void k_scan_w(const float* __restrict__ dtraw,
    const float* __restrict__ dt_bias, const float* __restrict__ A_log,
    float* __restrict__ wbuf, float* __restrict__ wsum){
  int h = blockIdx.x, b = blockIdx.y;
  int tid = threadIdx.x;
  float dtb = dt_bias[h];
  float negA = -expf(A_log[h]);
  float dtv[8], pre[8];
  float run = 0.f;
  size_t base = (size_t)b*GLEN;
  #pragma unroll
  for (int i=0;i<8;i++){
    int g = tid*8 + i;
    float v = dtraw[(base + g)*NH + h];
    float dt = softplus_f(v + dtb);
    run += dt * negA;
    dtv[i] = dt; pre[i] = run;
  }
  __shared__ float s[256];
  float tot_thread = run;
  s[tid] = run;
  __syncthreads();
  for (int off=1; off<256; off<<=1){
    float v = (tid>=off) ? s[tid-off] : 0.f;
    __syncthreads();
    s[tid] += v;
    __syncthreads();
  }
  float total = s[255];
  float excl = s[tid] - tot_thread;
  float ls = 0.f;
  #pragma unroll
  for (int i=0;i<8;i++){
    int g = tid*8+i;
    float w = expf(total - (excl + pre[i])) * dtv[i];
    wbuf[(base + g)*NH + h] = w;
    ls += w;
  }
  // const-region sum: thread's 8 positions lie in s>=136 iff (tid&31)>=17
  __syncthreads();
  s[tid] = ls;
  __syncthreads();
  int j = tid & 31, tw = tid >> 5;
  if (j == 17){
    float acc = 0.f;
    for (int q = 17; q < 32; q++) acc += s[tw*32 + q];
    wsum[((size_t)b*TWIN + tw)*NH + h] = acc;
  }
}

// Const-tail row per (b,t): cB = [yc(32)|Bc(128)], where Xc is the silu(conv)
// of the constant padded row and yc[p] = sum_h Wsum[b,t,h]*Xc[h*32+p].
__global__ __launch_bounds__(256) void k_const(const float* __restrict__ ptab,
    const float* __restrict__ conv_w, const float* __restrict__ conv_b,
    const float* __restrict__ wsum, float* __restrict__ cB){
  int t = blockIdx.x, b = blockIdx.y;
  int tid = threadIdx.x;
  __shared__ float Xc[NCC];
  __shared__ float Ws[NH];
  for (int c = tid; c < NCC; c += 256){
    float4 w = *(const float4*)&conv_w[c*4];
    float sw = w.x + w.y + w.z + w.w;
    float a = conv_b[c] + frombf16(tobf16(ptab[t*920 + c])) * sw;
    Xc[c] = silu_f(a);
  }
  if (tid < NH) Ws[tid] = wsum[((size_t)b*TWIN + t)*NH + tid];
  __syncthreads();
  float* dst = cB + ((size_t)(b*TWIN + t))*160;
  if (tid < 32){
    float y = 0.f;
    #pragma unroll
    for (int h=0;h<NH;h++) y += Ws[h]*Xc[h*32 + tid];
    dst[tid] = y;
  } else if (tid < 160){
    dst[tid] = Xc[768 + tid - 32];
  }
}

// One wave per 8-position strip, only s<136 per window (17 strips/window).
__global__ __launch_bounds__(256) void k_fold(const unsigned short* __restrict__ projh,
    const float* __restrict__ conv_w, const float* __restrict__ conv_b,
    const float* __restrict__ wbuf, float* __restrict__ yB){
  int wave = threadIdx.x >> 6, lane = threadIdx.x & 63;
  int strip = blockIdx.x*4 + wave;     // 0..135
  int b = blockIdx.y;
  int tw = strip / 17, k17 = strip - tw*17;
  int g0 = tw*256 + k17*8;
  size_t rbase = (size_t)b*GLEN;
  float cb[7][2], cw[7][2][4];
  #pragma unroll
  for (int k=0;k<7;k++){
    int c = 2*lane + 128*k;
    float2 t = *(const float2*)&conv_b[c];
    cb[k][0]=t.x; cb[k][1]=t.y;
    float4 w0 = *(const float4*)&conv_w[c*4];
    float4 w1 = *(const float4*)&conv_w[(c+1)*4];
    cw[k][0][0]=w0.x; cw[k][0][1]=w0.y; cw[k][0][2]=w0.z; cw[k][0][3]=w0.w;
    cw[k][1][0]=w1.x; cw[k][1][1]=w1.y; cw[k][1][2]=w1.z; cw[k][1][3]=w1.w;
  }
  float h0[7][2], h1[7][2], h2[7][2];
  #pragma unroll
  for (int k=0;k<7;k++){
    h0[k][0]=h0[k][1]=h1[k][0]=h1[k][1]=h2[k][0]=h2[k][1]=0.f;
  }
  if (g0 >= 3){
    #pragma unroll
    for (int k=0;k<7;k++){
      int c = 2*lane + 128*k;
      ushort2 p0 = *(const ushort2*)&projh[(rbase+g0-3)*NCC + c];
      ushort2 p1 = *(const ushort2*)&projh[(rbase+g0-2)*NCC + c];
      ushort2 p2 = *(const ushort2*)&projh[(rbase+g0-1)*NCC + c];
      h0[k][0]=frombf16(p0.x); h0[k][1]=frombf16(p0.y);
      h1[k][0]=frombf16(p1.x); h1[k][1]=frombf16(p1.y);
      h2[k][0]=frombf16(p2.x); h2[k][1]=frombf16(p2.y);
    }
  }
  #pragma unroll
  for (int i=0;i<8;i++){
    size_t row = rbase + g0 + i;
    float wreg = (lane < NH) ? wbuf[row*NH + lane] : 0.f;
    float cur[7][2];
    #pragma unroll
    for (int k=0;k<7;k++){
      int c = 2*lane + 128*k;
      ushort2 pv = *(const ushort2*)&projh[row*NCC + c];
      cur[k][0]=frombf16(pv.x); cur[k][1]=frombf16(pv.y);
    }
    float py0=0.f, py1=0.f, b0v=0.f, b1v=0.f;
    #pragma unroll
    for (int k=0;k<7;k++){
      float a0 = cb[k][0] + h0[k][0]*cw[k][0][0] + h1[k][0]*cw[k][0][1]
                          + h2[k][0]*cw[k][0][2] + cur[k][0]*cw[k][0][3];
      float a1 = cb[k][1] + h0[k][1]*cw[k][1][0] + h1[k][1]*cw[k][1][1]
                          + h2[k][1]*cw[k][1][2] + cur[k][1]*cw[k][1][3];
      float s0 = silu_f(a0), s1 = silu_f(a1);
      if (k < 6){
        float wh_ = __shfl(wreg, (lane>>4) + 4*k, 64);
        py0 += wh_*s0; py1 += wh_*s1;
      } else { b0v = s0; b1v = s1; }
    }
    py0 += __shfl_xor(py0, 16, 64); py0 += __shfl_xor(py0, 32, 64);
    py1 += __shfl_xor(py1, 16, 64); py1 += __shfl_xor(py1, 32, 64);
    float* dst = yB + row*160;
    if (lane < 16) *(float2*)&dst[2*lane] = make_float2(py0, py1);
    *(float2*)&dst[32 + 2*lane] = make_float2(b0v, b1v);
    #pragma unroll
    for (int k=0;k<7;k++){
      h0[k][0]=h1[k][0]; h0[k][1]=h1[k][1];
      h1[k][0]=h2[k][0]; h1[k][1]=h2[k][1];
      h2[k][0]=cur[k][0]; h2[k][1]=cur[k][1];
    }
  }
}

// Chunk partials over the 136 computed positions/window: 2 subs of 68.
__global__ __launch_bounds__(256) void k_partial(const float* __restrict__ yB,
    float* __restrict__ partial){
  int bt = blockIdx.x;            // b*8+t
  int sub = blockIdx.y;           // 0..1
  int b = bt >> 3, t = bt & 7;
  int tid = threadIdx.x;
  __shared__ float buf[8*160];
  int p0 = (tid >> 5) * 4;
  int n0 = (tid & 31) * 4;
  float acc[4][4] = {};
  size_t rbase = (size_t)b*GLEN;
  int gstart = t*256 + sub*68;
  int gend = gstart + 68;
  for (int gb = gstart; gb < gend; gb += 8){
    int cnt = min(8, gend - gb);
    for (int idx = tid; idx < cnt*160; idx += 256)
      buf[idx] = yB[(rbase+gb)*160 + idx];
    __syncthreads();
    for (int gi=0; gi<cnt; gi++){
      float4 yv = *(const float4*)&buf[gi*160 + p0];
      float4 bv = *(const float4*)&buf[gi*160 + 32 + n0];
      float ya[4] = {yv.x,yv.y,yv.z,yv.w};
      float ba[4] = {bv.x,bv.y,bv.z,bv.w};
      #pragma unroll
      for (int i=0;i<4;i++)
        #pragma unroll
        for (int j=0;j<4;j++)
          acc[i][j] += ya[i]*ba[j];
    }
    __syncthreads();
  }
  size_t pb = ((size_t)bt*2 + sub)*4096;
  #pragma unroll
  for (int i=0;i<4;i++)
    #pragma unroll
    for (int j=0;j<4;j++)
      partial[pb + (p0+i)*128 + n0+j] = acc[i][j];
}

// Suffix-sum: feat[b][t] = sum_{t'>=t} (2 subs + const-tail outer product)
__global__ __launch_bounds__(256) void k_suffix(const float* __restrict__ partial,
    const float* __restrict__ cB, float* __restrict__ feat){
  int b = blockIdx.y;
  int e = blockIdx.x*256 + threadIdx.x;   // 0..4095
  int p = e >> 7, n = e & 127;
  float s = 0.f;
  for (int t = TWIN-1; t >= 0; t--){
    size_t pb = ((size_t)(b*TWIN + t))*2*4096;
    s += partial[pb + e] + partial[pb + 4096 + e];
    const float* cb_ = cB + ((size_t)(b*TWIN + t))*160;
    s += cb_[p] * cb_[32 + n];
    feat[((size_t)(b*TWIN + t))*4096 + e] = s;
  }
}

// Boundary corrections for t>0
__global__ __launch_bounds__(256) void k_correct(const unsigned short* __restrict__ projh,
    const float* __restrict__ conv_w, const float* __restrict__ conv_b,
    const float* __restrict__ wbuf, float* __restrict__ feat){
  int t = blockIdx.x + 1, b = blockIdx.y;
  int tid = threadIdx.x;
  __shared__ float xsw[NCC], xsg[NCC];
  __shared__ float wv[NH];
  __shared__ float bufw[3*160], bufg[3*160];
  size_t rbase = (size_t)b*GLEN;
  int g0 = t*256;
  for (int gi=0; gi<3; gi++){
    int g = g0 + gi;
    if (tid < NH) wv[tid] = wbuf[(rbase+g)*NH + tid];
    for (int c = tid; c < NCC; c += 256){
      float aw = conv_b[c], ag = conv_b[c];
      #pragma unroll
      for (int k=0;k<4;k++){
        int gp = g - 3 + k;
        float term = frombf16(projh[(rbase+gp)*NCC + c]) * conv_w[c*4+k];
        ag += term;
        if (gp >= g0) aw += term;
      }
      xsw[c] = silu_f(aw);
      xsg[c] = silu_f(ag);
    }
    __syncthreads();
    if (tid < 32){
      float yw = 0.f, yg = 0.f;
      #pragma unroll
      for (int h=0;h<NH;h++){ yw += wv[h]*xsw[h*32+tid]; yg += wv[h]*xsg[h*32+tid]; }
      bufw[gi*160 + tid] = yw;
      bufg[gi*160 + tid] = yg;
    } else if (tid < 160){
      bufw[gi*160 + tid] = xsw[768 + tid - 32];
      bufg[gi*160 + tid] = xsg[768 + tid - 32];
    }
    __syncthreads();
  }
  int p0 = (tid >> 5) * 4;
  int n0 = (tid & 31) * 4;
  float acc[4][4] = {};
  #pragma unroll
  for (int gi=0; gi<3; gi++){
    float4 ywv = *(const float4*)&bufw[gi*160 + p0];
    float4 bwv = *(const float4*)&bufw[gi*160 + 32 + n0];
    float4 ygv = *(const float4*)&bufg[gi*160 + p0];
    float4 bgv = *(const float4*)&bufg[gi*160 + 32 + n0];
    float yw[4]={ywv.x,ywv.y,ywv.z,ywv.w}, bw[4]={bwv.x,bwv.y,bwv.z,bwv.w};
    float yg[4]={ygv.x,ygv.y,ygv.z,ygv.w}, bg[4]={bgv.x,bgv.y,bgv.z,bgv.w};
    #pragma unroll
    for (int i=0;i<4;i++)
      #pragma unroll
      for (int j=0;j<4;j++)
        acc[i][j] += yw[i]*bw[j] - yg[i]*bg[j];
  }
  size_t fb = (size_t)(b*TWIN + t)*4096;
  #pragma unroll
  for (int i=0;i<4;i++)
    #pragma unroll
    for (int j=0;j<4;j++)
      feat[fb + (p0+i)*128 + n0+j] += acc[i][j];
}

// out[bt][k] = feat[bt] . cls_w[k] + cls_b[k]; one wave per (bt,k)
__global__ __launch_bounds__(256) void k_classifier(const float* __restrict__ feat,
    const float* __restrict__ cls_w, const float* __restrict__ cls_b,
    float* __restrict__ out){
  int bt = blockIdx.x;
  int wave = threadIdx.x >> 6, lane = threadIdx.x & 63;
  int k = blockIdx.y*4 + wave;
  if (k >= 100) return;
  const float* f  = feat  + (size_t)bt*4096;
  const float* wr = cls_w + (size_t)k*4096;
  float s = 0.f;
  #pragma unroll
  for (int j0 = 0; j0 < 4096; j0 += 256){
    int j = j0 + lane*4;
    float4 fv = *(const float4*)(f + j);
    float4 wv = *(const float4*)(wr + j);
    s += fv.x*wv.x + fv.y*wv.y + fv.z*wv.z + fv.w*wv.w;
  }
  #pragma unroll
  for (int off=32; off>0; off>>=1) s += __shfl_down(s, off, 64);
  if (lane==0) out[bt*100 + k] = s + cls_b[k];
}

extern "C" void kernel_launch(void* const* d_in, const int* in_sizes, int n_in,
                              void* d_out, int out_size, void* d_ws, size_t ws_size,
                              hipStream_t stream){
  const float* inputs    = (const float*)d_in[0];
  const float* in_proj_w = (const float*)d_in[1];
  const float* conv_w    = (const float*)d_in[2];
  const float* conv_b    = (const float*)d_in[3];
  const float* dt_bias   = (const float*)d_in[4];
  const float* A_log     = (const float*)d_in[5];
  const float* cls_w     = (const float*)d_in[6];
  const float* cls_b     = (const float*)d_in[7];
  float* out = (float*)d_out;

  float* xg            = (float*)d_ws;                          // MTOT*192 f32
  unsigned short* projh= (unsigned short*)(xg + (size_t)MTOT*DMODEL); // MTOT*896 bf16
  float* dtraw         = (float*)(projh + (size_t)MTOT*NCC);    // MTOT*24 f32
  float* wbuf          = dtraw + (size_t)MTOT*NH;               // MTOT*24 f32
  unsigned short* xh   = (unsigned short*)(wbuf + (size_t)MTOT*NH); // MTOT*192 bf16
  unsigned short* wh   = xh + (size_t)MTOT*DMODEL;              // NCC*192 bf16
  float* yB            = (float*)(wh + (size_t)NCC*DMODEL);     // MTOT*160 f32
  float* partial       = yB + (size_t)MTOT*160;                 // 256*4096 f32
  float* feat          = partial + (size_t)256*4096;            // 128*4096 f32
  float* ptab          = feat + (size_t)128*4096;               // 8*920 f32
  float* wsum          = ptab + (size_t)8*920;                  // 128*24 f32
  float* cB            = wsum + (size_t)128*NH;                 // 128*160 f32
  size_t need = (size_t)((char*)(cB + (size_t)128*160) - (char*)d_ws);
  if (ws_size < need) return;

  k_build_xg   <<<((NVALID+NCC)*DMODEL + 255)/256, 256, 0, stream>>>(inputs, in_proj_w, xg, xh, wh);
  k_petab      <<<dim3(TWIN, 8), 256, 0, stream>>>(in_proj_w, ptab);
  k_pad        <<<128, 256, 0, stream>>>(ptab, projh, dtraw);
  k_gemm_mfma  <<<dim3(MTOT/256, NCC/128), 256, 0, stream>>>(xh, wh, projh);
  k_gemm_dt    <<<dim3(NVALID/64, 1), 256, 0, stream>>>(xg, in_proj_w, dtraw);
  k_scan_w     <<<dim3(NH, BATCH), 256, 0, stream>>>(dtraw, dt_bias, A_log, wbuf, wsum);
  k_const      <<<dim3(TWIN, BATCH), 256, 0, stream>>>(ptab, conv_w, conv_b, wsum, cB);
  k_fold       <<<dim3(34, BATCH), 256, 0, stream>>>(projh, conv_w, conv_b, wbuf, yB);
  k_partial    <<<dim3(BATCH*TWIN, 2), 256, 0, stream>>>(yB, partial);
  k_suffix     <<<dim3(16, BATCH), 256, 0, stream>>>(partial, cB, feat);
  k_correct    <<<dim3(TWIN-1, BATCH), 256, 0, stream>>>(projh, conv_w, conv_b, wbuf, feat);
  k_classifier <<<dim3(BATCH*TWIN, 25), 256, 0, stream>>>(feat, cls_w, cls_b, out);
}

// Round 12
// 189.187 us; speedup vs baseline: 2.2345x; 1.0941x over previous
//
#include <hip/hip_runtime.h>
#include <math.h>

#define BATCH 16
#define TWIN 8
#define SEQIN 129
#define DMODEL 192
#define GLEN 2048           // TWIN*256
#define NH 24
#define HD 32
#define DS 128
#define NCC 896             // conv channels (x | B); dt handled separately
#define MTOT (BATCH*GLEN)   // 32768
#define NVALID (BATCH*TWIN*128) // 16384 rows with real input (s<128)
#define PADK 40             // GEMM LDS row pitch in bf16

typedef __attribute__((ext_vector_type(8))) short bf16x8;
typedef __attribute__((ext_vector_type(4))) float f32x4;

__device__ __forceinline__ float softplus_f(float x){
  return x > 20.f ? x : log1pf(expf(x));
}
__device__ __forceinline__ float silu_f(float x){
  return x / (1.f + __expf(-x));
}
__device__ __forceinline__ unsigned short tobf16(float f){
  union { float f; unsigned u; } v; v.f = f;
  unsigned r = v.u + 0x7FFF + ((v.u >> 16) & 1);
  return (unsigned short)(r >> 16);
}
__device__ __forceinline__ float frombf16(unsigned short u){
  union { unsigned u; float f; } v; v.u = ((unsigned)u) << 16; return v.f;
}

#define BMAIN 12960   // ((NVALID+NCC)*DMODEL)/256 exactly

// Fused: PE-added input build (real rows, s<128) + bf16 weight copy + ptab.
__global__ __launch_bounds__(256) void k_build(const float* __restrict__ in,
    const float* __restrict__ inw, float* __restrict__ xg,
    unsigned short* __restrict__ xh, unsigned short* __restrict__ wh,
    float* __restrict__ ptab){
  __shared__ float pe[DMODEL];
  int bx = blockIdx.x;
  int tid = threadIdx.x;
  if (bx < BMAIN){
    int idx = bx*256 + tid;
    if (idx < NVALID*DMODEL){
      int d = idx % DMODEL;
      int v = idx / DMODEL;
      int s = v & 127;
      int t = (v >> 7) & 7;
      int b = v >> 10;
      float val = in[((size_t)(b*TWIN + t)*SEQIN + (s+1))*DMODEL + d];
      float div = expf(-(float)(d & ~1) * (logf(10000.f)/(float)DMODEL));
      float ang = (float)t * div;
      val += (d & 1) ? cosf(ang) : sinf(ang);
      size_t row = (size_t)b*GLEN + t*256 + s;
      xg[row*DMODEL + d] = val;
      xh[row*DMODEL + d] = tobf16(val);
    } else {
      int j = idx - NVALID*DMODEL;
      if (j < NCC*DMODEL) wh[j] = tobf16(inw[(size_t)768*DMODEL + j]);
    }
  } else {
    // ptab[t][e] = sum_d PE[t][d]*W[row(e)][d], bf16-rounded inputs
    int pb = bx - BMAIN;          // 0..63
    int t = pb >> 3, eslice = pb & 7;
    if (tid < DMODEL){
      int d = tid;
      float div = expf(-(float)(d & ~1) * (logf(10000.f)/(float)DMODEL));
      float ang = (float)t * div;
      pe[d] = frombf16(tobf16((d & 1) ? cosf(ang) : sinf(ang)));
    }
    __syncthreads();
    int e0 = eslice*115;
    int e1 = min(920, e0 + 115);
    for (int e = e0 + tid; e < e1; e += 256){
      int row = (e < 896) ? (768 + e) : (1792 + (e - 896));
      const float* wr = inw + (size_t)row*DMODEL;
      float s = 0.f;
      #pragma unroll 4
      for (int d = 0; d < DMODEL; d++)
        s += pe[d] * frombf16(tobf16(wr[d]));
      ptab[t*920 + e] = s;
    }
  }
}

// Fused: bf16 MFMA GEMM (896 blocks) + fp32 dt GEMM (256) + pad fill (128).
__global__ __launch_bounds__(256) void k_gemmall(const unsigned short* __restrict__ xh,
    const unsigned short* __restrict__ wh, const float* __restrict__ xg,
    const float* __restrict__ inw, const float* __restrict__ ptab,
    unsigned short* __restrict__ projh, float* __restrict__ dtraw){
  __shared__ char smem[20480];
  int bx = blockIdx.x;
  int tid = threadIdx.x;
  if (bx < 896){
    // MFMA GEMM over real row-tiles: m0 = (bx%128)*256, n0 = (bx/128)*128
    unsigned short* As = (unsigned short*)smem;
    unsigned short* Bs = As + 128*PADK;
    int m0 = (bx & 127)*256, n0 = (bx >> 7)*128;
    int wid = tid >> 6, lane = tid & 63;
    int wm = (wid >> 1)*64, wn = (wid & 1)*64;
    int quad = lane >> 4, lm = lane & 15;
    int sr = tid >> 2, sq = tid & 3;
    f32x4 acc[4][4];
    #pragma unroll
    for (int i=0;i<4;i++)
      #pragma unroll
      for (int j=0;j<4;j++) acc[i][j] = (f32x4){0.f,0.f,0.f,0.f};
    for (int k0 = 0; k0 < DMODEL; k0 += 32){
      #pragma unroll
      for (int half=0; half<2; half++){
        int r = sr + half*64;
        *(bf16x8*)&As[r*PADK + sq*8] =
          *(const bf16x8*)&xh[(size_t)(m0+r)*DMODEL + k0 + sq*8];
        *(bf16x8*)&Bs[r*PADK + sq*8] =
          *(const bf16x8*)&wh[(size_t)(n0+r)*DMODEL + k0 + sq*8];
      }
      __syncthreads();
      bf16x8 aF[4], bF[4];
      #pragma unroll
      for (int i=0;i<4;i++){
        aF[i] = *(const bf16x8*)&As[(wm + i*16 + lm)*PADK + quad*8];
        bF[i] = *(const bf16x8*)&Bs[(wn + i*16 + lm)*PADK + quad*8];
      }
      #pragma unroll
      for (int i=0;i<4;i++)
        #pragma unroll
        for (int j=0;j<4;j++)
          acc[i][j] = __builtin_amdgcn_mfma_f32_16x16x32_bf16(aF[i], bF[j], acc[i][j], 0,0,0);
      __syncthreads();
    }
    #pragma unroll
    for (int i=0;i<4;i++){
      #pragma unroll
      for (int r=0;r<4;r++){
        int m = m0 + wm + i*16 + quad*4 + r;
        unsigned short* dst = projh + (size_t)m*NCC + n0 + wn + lm;
        #pragma unroll
        for (int j=0;j<4;j++)
          dst[j*16] = tobf16(acc[i][j][r]);
      }
    }
  } else if (bx < 1152){
    // fp32 GEMM for 24 dt channels over real row-tiles
    float* As = (float*)smem;          // [16][64]
    float* Bs = As + 16*64;
    int idx = bx - 896;
    int m0 = (idx >> 1)*256 + (idx & 1)*64;
    int ty = tid >> 4, tx = tid & 15;
    int lr = tid >> 2, lq = tid & 3;
    float acc[4][4] = {};
    for (int k0 = 0; k0 < DMODEL; k0 += 16){
      float4 av = *(const float4*)(xg + (size_t)(m0+lr)*DMODEL + k0 + lq*4);
      As[(lq*4+0)*64+lr] = av.x; As[(lq*4+1)*64+lr] = av.y;
      As[(lq*4+2)*64+lr] = av.z; As[(lq*4+3)*64+lr] = av.w;
      float4 bv = make_float4(0.f,0.f,0.f,0.f);
      if (lr < NH) bv = *(const float4*)(inw + (size_t)(1792+lr)*DMODEL + k0 + lq*4);
      Bs[(lq*4+0)*64+lr] = bv.x; Bs[(lq*4+1)*64+lr] = bv.y;
      Bs[(lq*4+2)*64+lr] = bv.z; Bs[(lq*4+3)*64+lr] = bv.w;
      __syncthreads();
      #pragma unroll
      for (int kk = 0; kk < 16; kk++){
        float4 a = *(const float4*)&As[kk*64 + ty*4];
        float4 bq = *(const float4*)&Bs[kk*64 + tx*4];
        float avr[4] = {a.x, a.y, a.z, a.w};
        float bvr[4] = {bq.x, bq.y, bq.z, bq.w};
        #pragma unroll
        for (int i=0;i<4;i++)
          #pragma unroll
          for (int j=0;j<4;j++)
            acc[i][j] += avr[i]*bvr[j];
      }
      __syncthreads();
    }
    #pragma unroll
    for (int i=0;i<4;i++){
      int m = m0 + ty*4 + i;
      #pragma unroll
      for (int j=0;j<4;j++){
        int n = tx*4 + j;
        if (n < NH) dtraw[(size_t)m*NH + n] = acc[i][j];
      }
    }
  } else {
    // pad fill: projh rows s in {128..135, 252..255}; dtraw rows s>=128
    float* pt = (float*)smem;
    int bt = bx - 1152;            // 0..127
    int b = bt >> 3, t = bt & 7;
    for (int e = tid; e < 920; e += 256) pt[e] = ptab[t*920 + e];
    __syncthreads();
    size_t base = (size_t)b*GLEN + t*256;
    for (int i = tid; i < 12*224; i += 256){
      int r = i / 224, c4 = (i - r*224)*4;
      int s = (r < 8) ? (128 + r) : (244 + r);
      ushort4 v;
      v.x = tobf16(pt[c4+0]); v.y = tobf16(pt[c4+1]);
      v.z = tobf16(pt[c4+2]); v.w = tobf16(pt[c4+3]);
      *(ushort4*)&projh[(base + s)*NCC + c4] = v;
    }
    for (int i = tid; i < 128*NH; i += 256){
      int r = i / NH, h = i - r*NH;
      dtraw[(base + 128 + r)*NH + h] = pt[896 + h];
    }
  }
}

// Per (b,h): w[g] = exp(csum_total - csum[g]) * dt[g]; also Wsum (s>=136).
__global__ __launch_bounds__(256) void k_scan_w(const float* __restrict__ dtraw,
    const float* __restrict__ dt_bias, const float* __restrict__ A_log,
    float* __restrict__ wbuf, float* __restrict__ wsum){
  int h = blockIdx.x, b = blockIdx.y;
  int tid = threadIdx.x;
  float dtb = dt_bias[h];
  float negA = -expf(A_log[h]);
  float dtv[8], pre[8];
  float run = 0.f;
  size_t base = (size_t)b*GLEN;
  #pragma unroll
  for (int i=0;i<8;i++){
    int g = tid*8 + i;
    float v = dtraw[(base + g)*NH + h];
    float dt = softplus_f(v + dtb);
    run += dt * negA;
    dtv[i] = dt; pre[i] = run;
  }
  __shared__ float s[256];
  float tot_thread = run;
  s[tid] = run;
  __syncthreads();
  for (int off=1; off<256; off<<=1){
    float v = (tid>=off) ? s[tid-off] : 0.f;
    __syncthreads();
    s[tid] += v;
    __syncthreads();
  }
  float total = s[255];
  float excl = s[tid] - tot_thread;
  float ls = 0.f;
  #pragma unroll
  for (int i=0;i<8;i++){
    int g = tid*8+i;
    float w = expf(total - (excl + pre[i])) * dtv[i];
    wbuf[(base + g)*NH + h] = w;
    ls += w;
  }
  __syncthreads();
  s[tid] = ls;
  __syncthreads();
  int j = tid & 31, tw = tid >> 5;
  if (j == 17){
    float acc = 0.f;
    for (int q = 17; q < 32; q++) acc += s[tw*32 + q];
    wsum[((size_t)b*TWIN + tw)*NH + h] = acc;
  }
}

// Fused: per-strip fold (544 blocks) + const-tail rows (128) + boundary
// correction vectors (112, written to cbuf; applied in k_suffix).
__global__ __launch_bounds__(256) void k_foldall(const unsigned short* __restrict__ projh,
    const float* __restrict__ conv_w, const float* __restrict__ conv_b,
    const float* __restrict__ wbuf, const float* __restrict__ ptab,
    const float* __restrict__ wsum, float* __restrict__ yB,
    float* __restrict__ cB, float* __restrict__ cbuf){
  __shared__ float smem[2800];
  int bx = blockIdx.x;
  int tid = threadIdx.x;
  if (bx < 544){
    // fold: strips of 8 positions, s<136 per window
    int wave = tid >> 6, lane = tid & 63;
    int b = bx / 34;
    int strip = (bx % 34)*4 + wave;     // 0..135
    int tw = strip / 17, k17 = strip - tw*17;
    int g0 = tw*256 + k17*8;
    size_t rbase = (size_t)b*GLEN;
    float cb[7][2], cw[7][2][4];
    #pragma unroll
    for (int k=0;k<7;k++){
      int c = 2*lane + 128*k;
      float2 t = *(const float2*)&conv_b[c];
      cb[k][0]=t.x; cb[k][1]=t.y;
      float4 w0 = *(const float4*)&conv_w[c*4];
      float4 w1 = *(const float4*)&conv_w[(c+1)*4];
      cw[k][0][0]=w0.x; cw[k][0][1]=w0.y; cw[k][0][2]=w0.z; cw[k][0][3]=w0.w;
      cw[k][1][0]=w1.x; cw[k][1][1]=w1.y; cw[k][1][2]=w1.z; cw[k][1][3]=w1.w;
    }
    float h0[7][2], h1[7][2], h2[7][2];
    #pragma unroll
    for (int k=0;k<7;k++){
      h0[k][0]=h0[k][1]=h1[k][0]=h1[k][1]=h2[k][0]=h2[k][1]=0.f;
    }
    if (g0 >= 3){
      #pragma unroll
      for (int k=0;k<7;k++){
        int c = 2*lane + 128*k;
        ushort2 p0 = *(const ushort2*)&projh[(rbase+g0-3)*NCC + c];
        ushort2 p1 = *(const ushort2*)&projh[(rbase+g0-2)*NCC + c];
        ushort2 p2 = *(const ushort2*)&projh[(rbase+g0-1)*NCC + c];
        h0[k][0]=frombf16(p0.x); h0[k][1]=frombf16(p0.y);
        h1[k][0]=frombf16(p1.x); h1[k][1]=frombf16(p1.y);
        h2[k][0]=frombf16(p2.x); h2[k][1]=frombf16(p2.y);
      }
    }
    #pragma unroll
    for (int i=0;i<8;i++){
      size_t row = rbase + g0 + i;
      float wreg = (lane < NH) ? wbuf[row*NH + lane] : 0.f;
      float cur[7][2];
      #pragma unroll
      for (int k=0;k<7;k++){
        int c = 2*lane + 128*k;
        ushort2 pv = *(const ushort2*)&projh[row*NCC + c];
        cur[k][0]=frombf16(pv.x); cur[k][1]=frombf16(pv.y);
      }
      float py0=0.f, py1=0.f, b0v=0.f, b1v=0.f;
      #pragma unroll
      for (int k=0;k<7;k++){
        float a0 = cb[k][0] + h0[k][0]*cw[k][0][0] + h1[k][0]*cw[k][0][1]
                            + h2[k][0]*cw[k][0][2] + cur[k][0]*cw[k][0][3];
        float a1 = cb[k][1] + h0[k][1]*cw[k][1][0] + h1[k][1]*cw[k][1][1]
                            + h2[k][1]*cw[k][1][2] + cur[k][1]*cw[k][1][3];
        float s0 = silu_f(a0), s1 = silu_f(a1);
        if (k < 6){
          float wh_ = __shfl(wreg, (lane>>4) + 4*k, 64);
          py0 += wh_*s0; py1 += wh_*s1;
        } else { b0v = s0; b1v = s1; }
      }
      py0 += __shfl_xor(py0, 16, 64); py0 += __shfl_xor(py0, 32, 64);
      py1 += __shfl_xor(py1, 16, 64); py1 += __shfl_xor(py1, 32, 64);
      float* dst = yB + row*160;
      if (lane < 16) *(float2*)&dst[2*lane] = make_float2(py0, py1);
      *(float2*)&dst[32 + 2*lane] = make_float2(b0v, b1v);
      #pragma unroll
      for (int k=0;k<7;k++){
        h0[k][0]=h1[k][0]; h0[k][1]=h1[k][1];
        h1[k][0]=h2[k][0]; h1[k][1]=h2[k][1];
        h2[k][0]=cur[k][0]; h2[k][1]=cur[k][1];
      }
    }
  } else if (bx < 672){
    // const-tail row per (b,t)
    float* Xc = smem;            // 896
    float* Ws = smem + 896;      // 24
    int idx = bx - 544;
    int t = idx & 7, b = idx >> 3;
    for (int c = tid; c < NCC; c += 256){
      float4 w = *(const float4*)&conv_w[c*4];
      float sw = w.x + w.y + w.z + w.w;
      float a = conv_b[c] + frombf16(tobf16(ptab[t*920 + c])) * sw;
      Xc[c] = silu_f(a);
    }
    if (tid < NH) Ws[tid] = wsum[((size_t)b*TWIN + t)*NH + tid];
    __syncthreads();
    float* dst = cB + ((size_t)(b*TWIN + t))*160;
    if (tid < 32){
      float y = 0.f;
      #pragma unroll
      for (int h=0;h<NH;h++) y += Ws[h]*Xc[h*32 + tid];
      dst[tid] = y;
    } else if (tid < 160){
      dst[tid] = Xc[768 + tid - 32];
    }
  } else {
    // boundary-correction vectors for (b, t>0) -> cbuf[bt*960]
    float* xsw  = smem;          // 896
    float* xsg  = smem + 896;    // 896
    float* wv   = smem + 1792;   // 24
    float* bufw = smem + 1816;   // 480
    float* bufg = smem + 2296;   // 480
    int idx = bx - 672;          // 0..111
    int b = idx / 7, t = idx % 7 + 1;
    size_t rbase = (size_t)b*GLEN;
    int g0 = t*256;
    for (int gi=0; gi<3; gi++){
      int g = g0 + gi;
      if (tid < NH) wv[tid] = wbuf[(rbase+g)*NH + tid];
      for (int c = tid; c < NCC; c += 256){
        float aw = conv_b[c], ag = conv_b[c];
        #pragma unroll
        for (int k=0;k<4;k++){
          int gp = g - 3 + k;
          float term = frombf16(projh[(rbase+gp)*NCC + c]) * conv_w[c*4+k];
          ag += term;
          if (gp >= g0) aw += term;
        }
        xsw[c] = silu_f(aw);
        xsg[c] = silu_f(ag);
      }
      __syncthreads();
      if (tid < 32){
        float yw = 0.f, yg = 0.f;
        #pragma unroll
        for (int h=0;h<NH;h++){ yw += wv[h]*xsw[h*32+tid]; yg += wv[h]*xsg[h*32+tid]; }
        bufw[gi*160 + tid] = yw;
        bufg[gi*160 + tid] = yg;
      } else if (tid < 160){
        bufw[gi*160 + tid] = xsw[768 + tid - 32];
        bufg[gi*160 + tid] = xsg[768 + tid - 32];
      }
      __syncthreads();
    }
    float* dst = cbuf + ((size_t)(b*TWIN + t))*960;
    for (int i = tid; i < 960; i += 256){
      int gi = i / 320, rem = i - gi*320;
      dst[i] = (rem < 160) ? bufw[gi*160 + rem] : bufg[gi*160 + rem - 160];
    }
  }
}

// Chunk partials over the 136 computed positions/window: 2 subs of 68.
__global__ __launch_bounds__(256) void k_partial(const float* __restrict__ yB,
    float* __restrict__ partial){
  int bt = blockIdx.x;            // b*8+t
  int sub = blockIdx.y;           // 0..1
  int b = bt >> 3, t = bt & 7;
  int tid = threadIdx.x;
  __shared__ float buf[8*160];
  int p0 = (tid >> 5) * 4;
  int n0 = (tid & 31) * 4;
  float acc[4][4] = {};
  size_t rbase = (size_t)b*GLEN;
  int gstart = t*256 + sub*68;
  int gend = gstart + 68;
  for (int gb = gstart; gb < gend; gb += 8){
    int cnt = min(8, gend - gb);
    for (int idx = tid; idx < cnt*160; idx += 256)
      buf[idx] = yB[(rbase+gb)*160 + idx];
    __syncthreads();
    for (int gi=0; gi<cnt; gi++){
      float4 yv = *(const float4*)&buf[gi*160 + p0];
      float4 bv = *(const float4*)&buf[gi*160 + 32 + n0];
      float ya[4] = {yv.x,yv.y,yv.z,yv.w};
      float ba[4] = {bv.x,bv.y,bv.z,bv.w};
      #pragma unroll
      for (int i=0;i<4;i++)
        #pragma unroll
        for (int j=0;j<4;j++)
          acc[i][j] += ya[i]*ba[j];
    }
    __syncthreads();
  }
  size_t pb = ((size_t)bt*2 + sub)*4096;
  #pragma unroll
  for (int i=0;i<4;i++)
    #pragma unroll
    for (int j=0;j<4;j++)
      partial[pb + (p0+i)*128 + n0+j] = acc[i][j];
}

// Suffix-sum + const-tail + inline boundary deltas.
__global__ __launch_bounds__(256) void k_suffix(const float* __restrict__ partial,
    const float* __restrict__ cB, const float* __restrict__ cbuf,
    float* __restrict__ feat){
  int b = blockIdx.y;
  int e = blockIdx.x*256 + threadIdx.x;   // 0..4095
  int p = e >> 7, n = e & 127;
  float s = 0.f;
  for (int t = TWIN-1; t >= 0; t--){
    int bt = b*TWIN + t;
    size_t pb = (size_t)bt*2*4096;
    s += partial[pb + e] + partial[pb + 4096 + e];
    const float* cb_ = cB + (size_t)bt*160;
    s += cb_[p] * cb_[32 + n];
    float f = s;
    if (t > 0){
      const float* cw_ = cbuf + (size_t)bt*960;
      #pragma unroll
      for (int gi=0; gi<3; gi++){
        const float* rw = cw_ + gi*320;
        f += rw[p]*rw[32+n] - rw[160+p]*rw[192+n];
      }
    }
    feat[(size_t)bt*4096 + e] = f;
  }
}

// out[bt][k] = feat[bt] . cls_w[k] + cls_b[k]; one wave per (bt,k)
__global__ __launch_bounds__(256) void k_classifier(const float* __restrict__ feat,
    const float* __restrict__ cls_w, const float* __restrict__ cls_b,
    float* __restrict__ out){
  int bt = blockIdx.x;
  int wave = threadIdx.x >> 6, lane = threadIdx.x & 63;
  int k = blockIdx.y*4 + wave;
  if (k >= 100) return;
  const float* f  = feat  + (size_t)bt*4096;
  const float* wr = cls_w + (size_t)k*4096;
  float s = 0.f;
  #pragma unroll
  for (int j0 = 0; j0 < 4096; j0 += 256){
    int j = j0 + lane*4;
    float4 fv = *(const float4*)(f + j);
    float4 wv = *(const float4*)(wr + j);
    s += fv.x*wv.x + fv.y*wv.y + fv.z*wv.z + fv.w*wv.w;
  }
  #pragma unroll
  for (int off=32; off>0; off>>=1) s += __shfl_down(s, off, 64);
  if (lane==0) out[bt*100 + k] = s + cls_b[k];
}

extern "C" void kernel_launch(void* const* d_in, const int* in_sizes, int n_in,
                              void* d_out, int out_size, void* d_ws, size_t ws_size,
                              hipStream_t stream){
  const float* inputs    = (const float*)d_in[0];
  const float* in_proj_w = (const float*)d_in[1];
  const float* conv_w    = (const float*)d_in[2];
  const float* conv_b    = (const float*)d_in[3];
  const float* dt_bias   = (const float*)d_in[4];
  const float* A_log     = (const float*)d_in[5];
  const float* cls_w     = (const float*)d_in[6];
  const float* cls_b     = (const float*)d_in[7];
  float* out = (float*)d_out;

  float* xg            = (float*)d_ws;                          // MTOT*192 f32
  unsigned short* projh= (unsigned short*)(xg + (size_t)MTOT*DMODEL); // MTOT*896 bf16
  float* dtraw         = (float*)(projh + (size_t)MTOT*NCC);    // MTOT*24 f32
  float* wbuf          = dtraw + (size_t)MTOT*NH;               // MTOT*24 f32
  unsigned short* xh   = (unsigned short*)(wbuf + (size_t)MTOT*NH); // MTOT*192 bf16
  unsigned short* wh   = xh + (size_t)MTOT*DMODEL;              // NCC*192 bf16
  float* yB            = (float*)(wh + (size_t)NCC*DMODEL);     // MTOT*160 f32
  float* partial       = yB + (size_t)MTOT*160;                 // 256*4096 f32
  float* feat          = partial + (size_t)256*4096;            // 128*4096 f32
  float* ptab          = feat + (size_t)128*4096;               // 8*920 f32
  float* wsum          = ptab + (size_t)8*920;                  // 128*24 f32
  float* cB            = wsum + (size_t)128*NH;                 // 128*160 f32
  float* cbuf          = cB + (size_t)128*160;                  // 128*960 f32
  size_t need = (size_t)((char*)(cbuf + (size_t)128*960) - (char*)d_ws);
  if (ws_size < need) return;

  k_build      <<<BMAIN + 64, 256, 0, stream>>>(inputs, in_proj_w, xg, xh, wh, ptab);
  k_gemmall    <<<1280, 256, 0, stream>>>(xh, wh, xg, in_proj_w, ptab, projh, dtraw);
  k_scan_w     <<<dim3(NH, BATCH), 256, 0, stream>>>(dtraw, dt_bias, A_log, wbuf, wsum);
  k_foldall    <<<784, 256, 0, stream>>>(projh, conv_w, conv_b, wbuf, ptab, wsum, yB, cB, cbuf);
  k_partial    <<<dim3(BATCH*TWIN, 2), 256, 0, stream>>>(yB, partial);
  k_suffix     <<<dim3(16, BATCH), 256, 0, stream>>>(partial, cB, cbuf, feat);
  k_classifier <<<dim3(BATCH*TWIN, 25), 256, 0, stream>>>(feat, cls_w, cls_b, out);
}

// Round 13
// 188.033 us; speedup vs baseline: 2.2482x; 1.0061x over previous
//
#include <hip/hip_runtime.h>
#include <math.h>

#define BATCH 16
#define TWIN 8
#define SEQIN 129
#define DMODEL 192
#define GLEN 2048           // TWIN*256
#define NH 24
#define HD 32
#define DS 128
#define NCC 896             // conv channels (x | B); dt handled separately
#define MTOT (BATCH*GLEN)   // 32768
#define NVALID (BATCH*TWIN*128) // 16384 rows with real input (s<128)
#define PADK 40             // GEMM LDS row pitch in bf16

typedef __attribute__((ext_vector_type(8))) short bf16x8;
typedef __attribute__((ext_vector_type(4))) float f32x4;

__device__ __forceinline__ float softplus_f(float x){
  return x > 20.f ? x : log1pf(expf(x));
}
__device__ __forceinline__ float silu_f(float x){
  return x / (1.f + __expf(-x));
}
__device__ __forceinline__ unsigned short tobf16(float f){
  union { float f; unsigned u; } v; v.f = f;
  unsigned r = v.u + 0x7FFF + ((v.u >> 16) & 1);
  return (unsigned short)(r >> 16);
}
__device__ __forceinline__ float frombf16(unsigned short u){
  union { unsigned u; float f; } v; v.u = ((unsigned)u) << 16; return v.f;
}

#define BMAIN 12960   // (NVALID*192 + NCC*192)/256 exactly

// Fused: bf16 cast of raw input (compact, real rows only) + bf16 weight copy
// + PE-projection table ptab[t][e] = sum_d PE[t][d]*W[row(e)][d] (fp32).
__global__ __launch_bounds__(256) void k_build(const float* __restrict__ in,
    const float* __restrict__ inw, unsigned short* __restrict__ inh,
    unsigned short* __restrict__ wh, float* __restrict__ ptab){
  __shared__ float pe[DMODEL];
  int bx = blockIdx.x;
  int tid = threadIdx.x;
  if (bx < BMAIN){
    int idx = bx*256 + tid;
    if (idx < NVALID*DMODEL){
      int d = idx % DMODEL;
      int v = idx / DMODEL;          // compact row: b*1024 + t*128 + s
      int bt = v >> 7, s = v & 127;
      inh[idx] = tobf16(in[((size_t)bt*SEQIN + s + 1)*DMODEL + d]);
    } else {
      int j = idx - NVALID*DMODEL;
      wh[j] = tobf16(inw[(size_t)768*DMODEL + j]);
    }
  } else {
    int pb = bx - BMAIN;          // 0..63
    int t = pb >> 3, eslice = pb & 7;
    if (tid < DMODEL){
      int d = tid;
      float div = expf(-(float)(d & ~1) * (logf(10000.f)/(float)DMODEL));
      float ang = (float)t * div;
      pe[d] = (d & 1) ? cosf(ang) : sinf(ang);
    }
    __syncthreads();
    int e0 = eslice*115;
    int e1 = min(920, e0 + 115);
    for (int e = e0 + tid; e < e1; e += 256){
      int row = (e < 896) ? (768 + e) : (1792 + (e - 896));
      const float* wr = inw + (size_t)row*DMODEL;
      float s = 0.f;
      #pragma unroll 4
      for (int d = 0; d < DMODEL; d++)
        s += pe[d] * wr[d];
      ptab[t*920 + e] = s;
    }
  }
}

// Fused: bf16 MFMA GEMM on compact inh (+ptab epilogue) + fp32 dt GEMM on raw
// in (+ptab epilogue) + pad fill of projh/dtraw constant rows.
__global__ __launch_bounds__(256) void k_gemmall(const unsigned short* __restrict__ inh,
    const unsigned short* __restrict__ wh, const float* __restrict__ in,
    const float* __restrict__ inw, const float* __restrict__ ptab,
    unsigned short* __restrict__ projh, float* __restrict__ dtraw){
  __shared__ char smem[20480];
  int bx = blockIdx.x;
  int tid = threadIdx.x;
  if (bx < 896){
    // MFMA GEMM: 128-row compact tile (one (b,t)) x 128 cols
    unsigned short* As = (unsigned short*)smem;
    unsigned short* Bs = As + 128*PADK;
    int mt = bx & 127;              // compact tile = bt index
    int n0 = (bx >> 7)*128;
    int t = mt & 7;
    size_t msrc = (size_t)mt*128;   // compact row base in inh
    size_t mdst = (size_t)(mt >> 3)*GLEN + (size_t)t*256; // projh row base
    int wid = tid >> 6, lane = tid & 63;
    int wm = (wid >> 1)*64, wn = (wid & 1)*64;
    int quad = lane >> 4, lm = lane & 15;
    int sr = tid >> 2, sq = tid & 3;
    f32x4 acc[4][4];
    #pragma unroll
    for (int i=0;i<4;i++)
      #pragma unroll
      for (int j=0;j<4;j++) acc[i][j] = (f32x4){0.f,0.f,0.f,0.f};
    for (int k0 = 0; k0 < DMODEL; k0 += 32){
      #pragma unroll
      for (int half=0; half<2; half++){
        int r = sr + half*64;
        *(bf16x8*)&As[r*PADK + sq*8] =
          *(const bf16x8*)&inh[(msrc + r)*DMODEL + k0 + sq*8];
        *(bf16x8*)&Bs[r*PADK + sq*8] =
          *(const bf16x8*)&wh[(size_t)(n0+r)*DMODEL + k0 + sq*8];
      }
      __syncthreads();
      bf16x8 aF[4], bF[4];
      #pragma unroll
      for (int i=0;i<4;i++){
        aF[i] = *(const bf16x8*)&As[(wm + i*16 + lm)*PADK + quad*8];
        bF[i] = *(const bf16x8*)&Bs[(wn + i*16 + lm)*PADK + quad*8];
      }
      #pragma unroll
      for (int i=0;i<4;i++)
        #pragma unroll
        for (int j=0;j<4;j++)
          acc[i][j] = __builtin_amdgcn_mfma_f32_16x16x32_bf16(aF[i], bF[j], acc[i][j], 0,0,0);
      __syncthreads();
    }
    float ptn[4];
    #pragma unroll
    for (int j=0;j<4;j++) ptn[j] = ptab[t*920 + n0 + wn + lm + j*16];
    // wm covers 0/64 but tile is 128 rows: rows wm+i*16+quad*4+r (0..127)
    #pragma unroll
    for (int i=0;i<4;i++){
      #pragma unroll
      for (int r=0;r<4;r++){
        int m = wm + i*16 + quad*4 + r;
        unsigned short* dst = projh + (mdst + m)*NCC + n0 + wn + lm;
        #pragma unroll
        for (int j=0;j<4;j++)
          dst[j*16] = tobf16(acc[i][j][r] + ptn[j]);
      }
    }
  } else if (bx < 1152){
    // fp32 GEMM for 24 dt channels, reading raw input rows directly
    float* As = (float*)smem;          // [16][64]
    float* Bs = As + 16*64;
    int idx = bx - 896;                // 0..255
    int m0 = idx*64;                   // compact row base
    int bt = m0 >> 7, t = bt & 7, srow = m0 & 127;
    int ty = tid >> 4, tx = tid & 15;
    int lr = tid >> 2, lq = tid & 3;
    float acc[4][4] = {};
    for (int k0 = 0; k0 < DMODEL; k0 += 16){
      float4 av = *(const float4*)(in + ((size_t)bt*SEQIN + srow + 1 + lr)*DMODEL + k0 + lq*4);
      As[(lq*4+0)*64+lr] = av.x; As[(lq*4+1)*64+lr] = av.y;
      As[(lq*4+2)*64+lr] = av.z; As[(lq*4+3)*64+lr] = av.w;
      float4 bv = make_float4(0.f,0.f,0.f,0.f);
      if (lr < NH) bv = *(const float4*)(inw + (size_t)(1792+lr)*DMODEL + k0 + lq*4);
      Bs[(lq*4+0)*64+lr] = bv.x; Bs[(lq*4+1)*64+lr] = bv.y;
      Bs[(lq*4+2)*64+lr] = bv.z; Bs[(lq*4+3)*64+lr] = bv.w;
      __syncthreads();
      #pragma unroll
      for (int kk = 0; kk < 16; kk++){
        float4 a = *(const float4*)&As[kk*64 + ty*4];
        float4 bq = *(const float4*)&Bs[kk*64 + tx*4];
        float avr[4] = {a.x, a.y, a.z, a.w};
        float bvr[4] = {bq.x, bq.y, bq.z, bq.w};
        #pragma unroll
        for (int i=0;i<4;i++)
          #pragma unroll
          for (int j=0;j<4;j++)
            acc[i][j] += avr[i]*bvr[j];
      }
      __syncthreads();
    }
    size_t mdst = (size_t)(bt >> 3)*GLEN + (size_t)t*256 + srow;
    #pragma unroll
    for (int i=0;i<4;i++){
      int m = ty*4 + i;
      #pragma unroll
      for (int j=0;j<4;j++){
        int n = tx*4 + j;
        if (n < NH) dtraw[(mdst + m)*NH + n] = acc[i][j] + ptab[t*920 + 896 + n];
      }
    }
  } else {
    // pad fill: projh rows s in {128..135, 252..255}; dtraw rows s>=128
    float* pt = (float*)smem;
    int bt = bx - 1152;            // 0..127
    int b = bt >> 3, t = bt & 7;
    for (int e = tid; e < 920; e += 256) pt[e] = ptab[t*920 + e];
    __syncthreads();
    size_t base = (size_t)b*GLEN + t*256;
    for (int i = tid; i < 12*224; i += 256){
      int r = i / 224, c4 = (i - r*224)*4;
      int s = (r < 8) ? (128 + r) : (244 + r);
      ushort4 v;
      v.x = tobf16(pt[c4+0]); v.y = tobf16(pt[c4+1]);
      v.z = tobf16(pt[c4+2]); v.w = tobf16(pt[c4+3]);
      *(ushort4*)&projh[(base + s)*NCC + c4] = v;
    }
    for (int i = tid; i < 128*NH; i += 256){
      int r = i / NH, h = i - r*NH;
      dtraw[(base + 128 + r)*NH + h] = pt[896 + h];
    }
  }
}

// Per (b,h): w[g] = exp(csum_total - csum[g]) * dt[g]; also Wsum (s>=136).
__global__ __launch_bounds__(256) void k_scan_w(const float* __restrict__ dtraw,
    const float* __restrict__ dt_bias, const float* __restrict__ A_log,
    float* __restrict__ wbuf, float* __restrict__ wsum){
  int h = blockIdx.x, b = blockIdx.y;
  int tid = threadIdx.x;
  float dtb = dt_bias[h];
  float negA = -expf(A_log[h]);
  float dtv[8], pre[8];
  float run = 0.f;
  size_t base = (size_t)b*GLEN;
  #pragma unroll
  for (int i=0;i<8;i++){
    int g = tid*8 + i;
    float v = dtraw[(base + g)*NH + h];
    float dt = softplus_f(v + dtb);
    run += dt * negA;
    dtv[i] = dt; pre[i] = run;
  }
  __shared__ float s[256];
  float tot_thread = run;
  s[tid] = run;
  __syncthreads();
  for (int off=1; off<256; off<<=1){
    float v = (tid>=off) ? s[tid-off] : 0.f;
    __syncthreads();
    s[tid] += v;
    __syncthreads();
  }
  float total = s[255];
  float excl = s[tid] - tot_thread;
  float ls = 0.f;
  #pragma unroll
  for (int i=0;i<8;i++){
    int g = tid*8+i;
    float w = expf(total - (excl + pre[i])) * dtv[i];
    wbuf[(base + g)*NH + h] = w;
    ls += w;
  }
  __syncthreads();
  s[tid] = ls;
  __syncthreads();
  int j = tid & 31, tw = tid >> 5;
  if (j == 17){
    float acc = 0.f;
    for (int q = 17; q < 32; q++) acc += s[tw*32 + q];
    wsum[((size_t)b*TWIN + tw)*NH + h] = acc;
  }
}

// Fused: per-strip fold (544 blocks) + const-tail rows (128) + boundary
// correction vectors (112, written to cbuf; applied in k_suffix).
__global__ __launch_bounds__(256) void k_foldall(const unsigned short* __restrict__ projh,
    const float* __restrict__ conv_w, const float* __restrict__ conv_b,
    const float* __restrict__ wbuf, const float* __restrict__ ptab,
    const float* __restrict__ wsum, float* __restrict__ yB,
    float* __restrict__ cB, float* __restrict__ cbuf){
  __shared__ float smem[2800];
  int bx = blockIdx.x;
  int tid = threadIdx.x;
  if (bx < 544){
    int wave = tid >> 6, lane = tid & 63;
    int b = bx / 34;
    int strip = (bx % 34)*4 + wave;     // 0..135
    int tw = strip / 17, k17 = strip - tw*17;
    int g0 = tw*256 + k17*8;
    size_t rbase = (size_t)b*GLEN;
    float cb[7][2], cw[7][2][4];
    #pragma unroll
    for (int k=0;k<7;k++){
      int c = 2*lane + 128*k;
      float2 t = *(const float2*)&conv_b[c];
      cb[k][0]=t.x; cb[k][1]=t.y;
      float4 w0 = *(const float4*)&conv_w[c*4];
      float4 w1 = *(const float4*)&conv_w[(c+1)*4];
      cw[k][0][0]=w0.x; cw[k][0][1]=w0.y; cw[k][0][2]=w0.z; cw[k][0][3]=w0.w;
      cw[k][1][0]=w1.x; cw[k][1][1]=w1.y; cw[k][1][2]=w1.z; cw[k][1][3]=w1.w;
    }
    float h0[7][2], h1[7][2], h2[7][2];
    #pragma unroll
    for (int k=0;k<7;k++){
      h0[k][0]=h0[k][1]=h1[k][0]=h1[k][1]=h2[k][0]=h2[k][1]=0.f;
    }
    if (g0 >= 3){
      #pragma unroll
      for (int k=0;k<7;k++){
        int c = 2*lane + 128*k;
        ushort2 p0 = *(const ushort2*)&projh[(rbase+g0-3)*NCC + c];
        ushort2 p1 = *(const ushort2*)&projh[(rbase+g0-2)*NCC + c];
        ushort2 p2 = *(const ushort2*)&projh[(rbase+g0-1)*NCC + c];
        h0[k][0]=frombf16(p0.x); h0[k][1]=frombf16(p0.y);
        h1[k][0]=frombf16(p1.x); h1[k][1]=frombf16(p1.y);
        h2[k][0]=frombf16(p2.x); h2[k][1]=frombf16(p2.y);
      }
    }
    #pragma unroll
    for (int i=0;i<8;i++){
      size_t row = rbase + g0 + i;
      float wreg = (lane < NH) ? wbuf[row*NH + lane] : 0.f;
      float cur[7][2];
      #pragma unroll
      for (int k=0;k<7;k++){
        int c = 2*lane + 128*k;
        ushort2 pv = *(const ushort2*)&projh[row*NCC + c];
        cur[k][0]=frombf16(pv.x); cur[k][1]=frombf16(pv.y);
      }
      float py0=0.f, py1=0.f, b0v=0.f, b1v=0.f;
      #pragma unroll
      for (int k=0;k<7;k++){
        float a0 = cb[k][0] + h0[k][0]*cw[k][0][0] + h1[k][0]*cw[k][0][1]
                            + h2[k][0]*cw[k][0][2] + cur[k][0]*cw[k][0][3];
        float a1 = cb[k][1] + h0[k][1]*cw[k][1][0] + h1[k][1]*cw[k][1][1]
                            + h2[k][1]*cw[k][1][2] + cur[k][1]*cw[k][1][3];
        float s0 = silu_f(a0), s1 = silu_f(a1);
        if (k < 6){
          float wh_ = __shfl(wreg, (lane>>4) + 4*k, 64);
          py0 += wh_*s0; py1 += wh_*s1;
        } else { b0v = s0; b1v = s1; }
      }
      py0 += __shfl_xor(py0, 16, 64); py0 += __shfl_xor(py0, 32, 64);
      py1 += __shfl_xor(py1, 16, 64); py1 += __shfl_xor(py1, 32, 64);
      float* dst = yB + row*160;
      if (lane < 16) *(float2*)&dst[2*lane] = make_float2(py0, py1);
      *(float2*)&dst[32 + 2*lane] = make_float2(b0v, b1v);
      #pragma unroll
      for (int k=0;k<7;k++){
        h0[k][0]=h1[k][0]; h0[k][1]=h1[k][1];
        h1[k][0]=h2[k][0]; h1[k][1]=h2[k][1];
        h2[k][0]=cur[k][0]; h2[k][1]=cur[k][1];
      }
    }
  } else if (bx < 672){
    float* Xc = smem;            // 896
    float* Ws = smem + 896;      // 24
    int idx = bx - 544;
    int t = idx & 7, b = idx >> 3;
    for (int c = tid; c < NCC; c += 256){
      float4 w = *(const float4*)&conv_w[c*4];
      float sw = w.x + w.y + w.z + w.w;
      float a = conv_b[c] + frombf16(tobf16(ptab[t*920 + c])) * sw;
      Xc[c] = silu_f(a);
    }
    if (tid < NH) Ws[tid] = wsum[((size_t)b*TWIN + t)*NH + tid];
    __syncthreads();
    float* dst = cB + ((size_t)(b*TWIN + t))*160;
    if (tid < 32){
      float y = 0.f;
      #pragma unroll
      for (int h=0;h<NH;h++) y += Ws[h]*Xc[h*32 + tid];
      dst[tid] = y;
    } else if (tid < 160){
      dst[tid] = Xc[768 + tid - 32];
    }
  } else {
    float* xsw  = smem;          // 896
    float* xsg  = smem + 896;    // 896
    float* wv   = smem + 1792;   // 24
    float* bufw = smem + 1816;   // 480
    float* bufg = smem + 2296;   // 480
    int idx = bx - 672;          // 0..111
    int b = idx / 7, t = idx % 7 + 1;
    size_t rbase = (size_t)b*GLEN;
    int g0 = t*256;
    for (int gi=0; gi<3; gi++){
      int g = g0 + gi;
      if (tid < NH) wv[tid] = wbuf[(rbase+g)*NH + tid];
      for (int c = tid; c < NCC; c += 256){
        float aw = conv_b[c], ag = conv_b[c];
        #pragma unroll
        for (int k=0;k<4;k++){
          int gp = g - 3 + k;
          float term = frombf16(projh[(rbase+gp)*NCC + c]) * conv_w[c*4+k];
          ag += term;
          if (gp >= g0) aw += term;
        }
        xsw[c] = silu_f(aw);
        xsg[c] = silu_f(ag);
      }
      __syncthreads();
      if (tid < 32){
        float yw = 0.f, yg = 0.f;
        #pragma unroll
        for (int h=0;h<NH;h++){ yw += wv[h]*xsw[h*32+tid]; yg += wv[h]*xsg[h*32+tid]; }
        bufw[gi*160 + tid] = yw;
        bufg[gi*160 + tid] = yg;
      } else if (tid < 160){
        bufw[gi*160 + tid] = xsw[768 + tid - 32];
        bufg[gi*160 + tid] = xsg[768 + tid - 32];
      }
      __syncthreads();
    }
    float* dst = cbuf + ((size_t)(b*TWIN + t))*960;
    for (int i = tid; i < 960; i += 256){
      int gi = i / 320, rem = i - gi*320;
      dst[i] = (rem < 160) ? bufw[gi*160 + rem] : bufg[gi*160 + rem - 160];
    }
  }
}

// Chunk partials over the 136 computed positions/window: 2 subs of 68.
__global__ __launch_bounds__(256) void k_partial(const float* __restrict__ yB,
    float* __restrict__ partial){
  int bt = blockIdx.x;            // b*8+t
  int sub = blockIdx.y;           // 0..1
  int b = bt >> 3, t = bt & 7;
  int tid = threadIdx.x;
  __shared__ float buf[8*160];
  int p0 = (tid >> 5) * 4;
  int n0 = (tid & 31) * 4;
  float acc[4][4] = {};
  size_t rbase = (size_t)b*GLEN;
  int gstart = t*256 + sub*68;
  int gend = gstart + 68;
  for (int gb = gstart; gb < gend; gb += 8){
    int cnt = min(8, gend - gb);
    for (int idx = tid; idx < cnt*160; idx += 256)
      buf[idx] = yB[(rbase+gb)*160 + idx];
    __syncthreads();
    for (int gi=0; gi<cnt; gi++){
      float4 yv = *(const float4*)&buf[gi*160 + p0];
      float4 bv = *(const float4*)&buf[gi*160 + 32 + n0];
      float ya[4] = {yv.x,yv.y,yv.z,yv.w};
      float ba[4] = {bv.x,bv.y,bv.z,bv.w};
      #pragma unroll
      for (int i=0;i<4;i++)
        #pragma unroll
        for (int j=0;j<4;j++)
          acc[i][j] += ya[i]*ba[j];
    }
    __syncthreads();
  }
  size_t pb = ((size_t)bt*2 + sub)*4096;
  #pragma unroll
  for (int i=0;i<4;i++)
    #pragma unroll
    for (int j=0;j<4;j++)
      partial[pb + (p0+i)*128 + n0+j] = acc[i][j];
}

// Suffix-sum + const-tail + inline boundary deltas.
__global__ __launch_bounds__(256) void k_suffix(const float* __restrict__ partial,
    const float* __restrict__ cB, const float* __restrict__ cbuf,
    float* __restrict__ feat){
  int b = blockIdx.y;
  int e = blockIdx.x*256 + threadIdx.x;   // 0..4095
  int p = e >> 7, n = e & 127;
  float s = 0.f;
  for (int t = TWIN-1; t >= 0; t--){
    int bt = b*TWIN + t;
    size_t pb = (size_t)bt*2*4096;
    s += partial[pb + e] + partial[pb + 4096 + e];
    const float* cb_ = cB + (size_t)bt*160;
    s += cb_[p] * cb_[32 + n];
    float f = s;
    if (t > 0){
      const float* cw_ = cbuf + (size_t)bt*960;
      #pragma unroll
      for (int gi=0; gi<3; gi++){
        const float* rw = cw_ + gi*320;
        f += rw[p]*rw[32+n] - rw[160+p]*rw[192+n];
      }
    }
    feat[(size_t)bt*4096 + e] = f;
  }
}

// out[bt][k] = feat[bt] . cls_w[k] + cls_b[k]; one wave per (bt,k)
__global__ __launch_bounds__(256) void k_classifier(const float* __restrict__ feat,
    const float* __restrict__ cls_w, const float* __restrict__ cls_b,
    float* __restrict__ out){
  int bt = blockIdx.x;
  int wave = threadIdx.x >> 6, lane = threadIdx.x & 63;
  int k = blockIdx.y*4 + wave;
  if (k >= 100) return;
  const float* f  = feat  + (size_t)bt*4096;
  const float* wr = cls_w + (size_t)k*4096;
  float s = 0.f;
  #pragma unroll
  for (int j0 = 0; j0 < 4096; j0 += 256){
    int j = j0 + lane*4;
    float4 fv = *(const float4*)(f + j);
    float4 wv = *(const float4*)(wr + j);
    s += fv.x*wv.x + fv.y*wv.y + fv.z*wv.z + fv.w*wv.w;
  }
  #pragma unroll
  for (int off=32; off>0; off>>=1) s += __shfl_down(s, off, 64);
  if (lane==0) out[bt*100 + k] = s + cls_b[k];
}

extern "C" void kernel_launch(void* const* d_in, const int* in_sizes, int n_in,
                              void* d_out, int out_size, void* d_ws, size_t ws_size,
                              hipStream_t stream){
  const float* inputs    = (const float*)d_in[0];
  const float* in_proj_w = (const float*)d_in[1];
  const float* conv_w    = (const float*)d_in[2];
  const float* conv_b    = (const float*)d_in[3];
  const float* dt_bias   = (const float*)d_in[4];
  const float* A_log     = (const float*)d_in[5];
  const float* cls_w     = (const float*)d_in[6];
  const float* cls_b     = (const float*)d_in[7];
  float* out = (float*)d_out;

  unsigned short* projh= (unsigned short*)d_ws;                 // MTOT*896 bf16
  float* dtraw         = (float*)(projh + (size_t)MTOT*NCC);    // MTOT*24 f32
  float* wbuf          = dtraw + (size_t)MTOT*NH;               // MTOT*24 f32
  unsigned short* inh  = (unsigned short*)(wbuf + (size_t)MTOT*NH); // NVALID*192 bf16
  unsigned short* wh   = inh + (size_t)NVALID*DMODEL;           // NCC*192 bf16
  float* yB            = (float*)(wh + (size_t)NCC*DMODEL);     // MTOT*160 f32
  float* partial       = yB + (size_t)MTOT*160;                 // 256*4096 f32
  float* feat          = partial + (size_t)256*4096;            // 128*4096 f32
  float* ptab          = feat + (size_t)128*4096;               // 8*920 f32
  float* wsum          = ptab + (size_t)8*920;                  // 128*24 f32
  float* cB            = wsum + (size_t)128*NH;                 // 128*160 f32
  float* cbuf          = cB + (size_t)128*160;                  // 128*960 f32
  size_t need = (size_t)((char*)(cbuf + (size_t)128*960) - (char*)d_ws);
  if (ws_size < need) return;

  k_build      <<<BMAIN + 64, 256, 0, stream>>>(inputs, in_proj_w, inh, wh, ptab);
  k_gemmall    <<<1280, 256, 0, stream>>>(inh, wh, inputs, in_proj_w, ptab, projh, dtraw);
  k_scan_w     <<<dim3(NH, BATCH), 256, 0, stream>>>(dtraw, dt_bias, A_log, wbuf, wsum);
  k_foldall    <<<784, 256, 0, stream>>>(projh, conv_w, conv_b, wbuf, ptab, wsum, yB, cB, cbuf);
  k_partial    <<<dim3(BATCH*TWIN, 2), 256, 0, stream>>>(yB, partial);
  k_suffix     <<<dim3(16, BATCH), 256, 0, stream>>>(partial, cB, cbuf, feat);
  k_classifier <<<dim3(BATCH*TWIN, 25), 256, 0, stream>>>(feat, cls_w, cls_b, out);
}

// Round 14
// 180.185 us; speedup vs baseline: 2.3462x; 1.0436x over previous
//
#include <hip/hip_runtime.h>
#include <math.h>

#define BATCH 16
#define TWIN 8
#define SEQIN 129
#define DMODEL 192
#define GLEN 2048           // TWIN*256
#define NH 24
#define HD 32
#define DS 128
#define NCC 896             // conv channels (x | B); dt handled separately
#define MTOT (BATCH*GLEN)   // 32768
#define NVALID (BATCH*TWIN*128) // 16384 rows with real input (s<128)
#define PADK 40             // GEMM LDS row pitch in bf16

typedef __attribute__((ext_vector_type(8))) short bf16x8;
typedef __attribute__((ext_vector_type(4))) float f32x4;

__device__ __forceinline__ float softplus_f(float x){
  return x > 20.f ? x : log1pf(expf(x));
}
__device__ __forceinline__ float silu_f(float x){
  return x / (1.f + __expf(-x));
}
__device__ __forceinline__ unsigned short tobf16(float f){
  union { float f; unsigned u; } v; v.f = f;
  unsigned r = v.u + 0x7FFF + ((v.u >> 16) & 1);
  return (unsigned short)(r >> 16);
}
__device__ __forceinline__ float frombf16(unsigned short u){
  union { unsigned u; float f; } v; v.u = ((unsigned)u) << 16; return v.f;
}

#define BMAIN 12960   // (NVALID*192 + NCC*192)/256 exactly

// Fused: bf16 cast of raw input + bf16 weight copy + ptab + compact dt GEMM.
__global__ __launch_bounds__(256) void k_build(const float* __restrict__ in,
    const float* __restrict__ inw, unsigned short* __restrict__ inh,
    unsigned short* __restrict__ wh, float* __restrict__ ptab,
    float* __restrict__ dtraw){
  __shared__ float smem[2048];
  int bx = blockIdx.x;
  int tid = threadIdx.x;
  if (bx < BMAIN){
    int idx = bx*256 + tid;
    if (idx < NVALID*DMODEL){
      int d = idx % DMODEL;
      int v = idx / DMODEL;          // compact row: bt*128 + s
      int bt = v >> 7, s = v & 127;
      inh[idx] = tobf16(in[((size_t)bt*SEQIN + s + 1)*DMODEL + d]);
    } else {
      int j = idx - NVALID*DMODEL;
      wh[j] = tobf16(inw[(size_t)768*DMODEL + j]);
    }
  } else if (bx < BMAIN + 64){
    // ptab[t][e] = sum_d PE[t][d]*W[row(e)][d]  (fp32)
    float* pe = smem;
    int pb = bx - BMAIN;          // 0..63
    int t = pb >> 3, eslice = pb & 7;
    if (tid < DMODEL){
      int d = tid;
      float div = expf(-(float)(d & ~1) * (logf(10000.f)/(float)DMODEL));
      float ang = (float)t * div;
      pe[d] = (d & 1) ? cosf(ang) : sinf(ang);
    }
    __syncthreads();
    int e0 = eslice*115;
    int e1 = min(920, e0 + 115);
    for (int e = e0 + tid; e < e1; e += 256){
      int row = (e < 896) ? (768 + e) : (1792 + (e - 896));
      const float* wr = inw + (size_t)row*DMODEL;
      float s = 0.f;
      #pragma unroll 4
      for (int d = 0; d < DMODEL; d++)
        s += pe[d] * wr[d];
      ptab[t*920 + e] = s;
    }
  } else {
    // fp32 GEMM for 24 dt channels, compact rows, NO ptab epilogue
    float* As = smem;          // [16][64]
    float* Bs = smem + 1024;
    int idx = bx - (BMAIN + 64);       // 0..255
    int m0 = idx*64;                   // compact row base
    int bt = m0 >> 7, srow = m0 & 127;
    int ty = tid >> 4, tx = tid & 15;
    int lr = tid >> 2, lq = tid & 3;
    float acc[4][4] = {};
    for (int k0 = 0; k0 < DMODEL; k0 += 16){
      float4 av = *(const float4*)(in + ((size_t)bt*SEQIN + srow + 1 + lr)*DMODEL + k0 + lq*4);
      As[(lq*4+0)*64+lr] = av.x; As[(lq*4+1)*64+lr] = av.y;
      As[(lq*4+2)*64+lr] = av.z; As[(lq*4+3)*64+lr] = av.w;
      float4 bv = make_float4(0.f,0.f,0.f,0.f);
      if (lr < NH) bv = *(const float4*)(inw + (size_t)(1792+lr)*DMODEL + k0 + lq*4);
      Bs[(lq*4+0)*64+lr] = bv.x; Bs[(lq*4+1)*64+lr] = bv.y;
      Bs[(lq*4+2)*64+lr] = bv.z; Bs[(lq*4+3)*64+lr] = bv.w;
      __syncthreads();
      #pragma unroll
      for (int kk = 0; kk < 16; kk++){
        float4 a = *(const float4*)&As[kk*64 + ty*4];
        float4 bq = *(const float4*)&Bs[kk*64 + tx*4];
        float avr[4] = {a.x, a.y, a.z, a.w};
        float bvr[4] = {bq.x, bq.y, bq.z, bq.w};
        #pragma unroll
        for (int i=0;i<4;i++)
          #pragma unroll
          for (int j=0;j<4;j++)
            acc[i][j] += avr[i]*bvr[j];
      }
      __syncthreads();
    }
    #pragma unroll
    for (int i=0;i<4;i++){
      int m = m0 + ty*4 + i;
      #pragma unroll
      for (int j=0;j<4;j++){
        int n = tx*4 + j;
        if (n < NH) dtraw[(size_t)m*NH + n] = acc[i][j];
      }
    }
  }
}

// Fused: bf16 MFMA GEMM on compact inh (+ptab epilogue) + projh pad fill.
__global__ __launch_bounds__(256) void k_gemmall(const unsigned short* __restrict__ inh,
    const unsigned short* __restrict__ wh, const float* __restrict__ ptab,
    unsigned short* __restrict__ projh){
  __shared__ char smem[20480];
  int bx = blockIdx.x;
  int tid = threadIdx.x;
  if (bx < 896){
    unsigned short* As = (unsigned short*)smem;
    unsigned short* Bs = As + 128*PADK;
    int mt = bx & 127;              // compact tile = bt index
    int n0 = (bx >> 7)*128;
    int t = mt & 7;
    size_t msrc = (size_t)mt*128;
    size_t mdst = (size_t)(mt >> 3)*GLEN + (size_t)t*256;
    int wid = tid >> 6, lane = tid & 63;
    int wm = (wid >> 1)*64, wn = (wid & 1)*64;
    int quad = lane >> 4, lm = lane & 15;
    int sr = tid >> 2, sq = tid & 3;
    f32x4 acc[4][4];
    #pragma unroll
    for (int i=0;i<4;i++)
      #pragma unroll
      for (int j=0;j<4;j++) acc[i][j] = (f32x4){0.f,0.f,0.f,0.f};
    for (int k0 = 0; k0 < DMODEL; k0 += 32){
      #pragma unroll
      for (int half=0; half<2; half++){
        int r = sr + half*64;
        *(bf16x8*)&As[r*PADK + sq*8] =
          *(const bf16x8*)&inh[(msrc + r)*DMODEL + k0 + sq*8];
        *(bf16x8*)&Bs[r*PADK + sq*8] =
          *(const bf16x8*)&wh[(size_t)(n0+r)*DMODEL + k0 + sq*8];
      }
      __syncthreads();
      bf16x8 aF[4], bF[4];
      #pragma unroll
      for (int i=0;i<4;i++){
        aF[i] = *(const bf16x8*)&As[(wm + i*16 + lm)*PADK + quad*8];
        bF[i] = *(const bf16x8*)&Bs[(wn + i*16 + lm)*PADK + quad*8];
      }
      #pragma unroll
      for (int i=0;i<4;i++)
        #pragma unroll
        for (int j=0;j<4;j++)
          acc[i][j] = __builtin_amdgcn_mfma_f32_16x16x32_bf16(aF[i], bF[j], acc[i][j], 0,0,0);
      __syncthreads();
    }
    float ptn[4];
    #pragma unroll
    for (int j=0;j<4;j++) ptn[j] = ptab[t*920 + n0 + wn + lm + j*16];
    #pragma unroll
    for (int i=0;i<4;i++){
      #pragma unroll
      for (int r=0;r<4;r++){
        int m = wm + i*16 + quad*4 + r;
        unsigned short* dst = projh + (mdst + m)*NCC + n0 + wn + lm;
        #pragma unroll
        for (int j=0;j<4;j++)
          dst[j*16] = tobf16(acc[i][j][r] + ptn[j]);
      }
    }
  } else {
    // pad fill: projh rows s in {128..135, 252..255}
    float* pt = (float*)smem;
    int bt = bx - 896;             // 0..127
    int b = bt >> 3, t = bt & 7;
    for (int e = tid; e < NCC; e += 256) pt[e] = ptab[t*920 + e];
    __syncthreads();
    size_t base = (size_t)b*GLEN + t*256;
    for (int i = tid; i < 12*224; i += 256){
      int r = i / 224, c4 = (i - r*224)*4;
      int s = (r < 8) ? (128 + r) : (244 + r);
      ushort4 v;
      v.x = tobf16(pt[c4+0]); v.y = tobf16(pt[c4+1]);
      v.z = tobf16(pt[c4+2]); v.w = tobf16(pt[c4+3]);
      *(ushort4*)&projh[(base + s)*NCC + c4] = v;
    }
  }
}

// Per (b,h): w[g] = exp(csum_total - csum[g]) * dt[g]; Wsum over s>=136.
// shfl-based scan; const dt (from ptab) for s>=128; wbuf written only s<136.
__global__ __launch_bounds__(256) void k_scan_w(const float* __restrict__ dtraw,
    const float* __restrict__ ptab, const float* __restrict__ dt_bias,
    const float* __restrict__ A_log, float* __restrict__ wbuf,
    float* __restrict__ wsum){
  int h = blockIdx.x, b = blockIdx.y;
  int tid = threadIdx.x;
  int lane = tid & 63, wid = tid >> 6;
  int tw = tid >> 5, q = tid & 31;
  float dtb = dt_bias[h];
  float negA = -expf(A_log[h]);
  float off = ptab[tw*920 + 896 + h] + dtb;  // const dt_raw + bias for this t
  float dtv[8], pre[8];
  float run = 0.f;
  if (q < 16){
    size_t rb = ((size_t)(b*TWIN + tw)*128 + q*8)*NH + h;
    #pragma unroll
    for (int i=0;i<8;i++){
      float dt = softplus_f(dtraw[rb + (size_t)i*NH] + off);
      run += dt * negA;
      dtv[i] = dt; pre[i] = run;
    }
  } else {
    float dt = softplus_f(off);
    #pragma unroll
    for (int i=0;i<8;i++){
      run += dt * negA;
      dtv[i] = dt; pre[i] = run;
    }
  }
  // wave-level inclusive scan of run
  float v = run;
  #pragma unroll
  for (int o=1; o<64; o<<=1){
    float u = __shfl_up(v, o, 64);
    if (lane >= o) v += u;
  }
  __shared__ float wtot[4];
  __shared__ float sred[256];
  if (lane == 63) wtot[wid] = v;
  __syncthreads();
  float base = 0.f, total = 0.f;
  #pragma unroll
  for (int w2=0; w2<4; w2++){
    float tv = wtot[w2];
    if (w2 < wid) base += tv;
    total += tv;
  }
  float excl = base + v - run;
  float ls = 0.f;
  size_t gb = (size_t)b*GLEN + tw*256 + q*8;
  #pragma unroll
  for (int i=0;i<8;i++){
    float w = expf(total - (excl + pre[i])) * dtv[i];
    if (q < 17) wbuf[(gb + i)*NH + h] = w;   // s<136: read by fold/correct
    else ls += w;                             // s>=136: const-tail sum
  }
  sred[tid] = ls;
  __syncthreads();
  if (q == 17){
    float acc = ls;
    for (int r = 18; r < 32; r++) acc += sred[tw*32 + r];
    wsum[((size_t)b*TWIN + tw)*NH + h] = acc;
  }
}

// Fused: per-strip fold (544 blocks) + const-tail rows (128) + boundary
// correction vectors (112, written to cbuf; applied in k_suffix).
__global__ __launch_bounds__(256) void k_foldall(const unsigned short* __restrict__ projh,
    const float* __restrict__ conv_w, const float* __restrict__ conv_b,
    const float* __restrict__ wbuf, const float* __restrict__ ptab,
    const float* __restrict__ wsum, float* __restrict__ yB,
    float* __restrict__ cB, float* __restrict__ cbuf){
  __shared__ float smem[2800];
  int bx = blockIdx.x;
  int tid = threadIdx.x;
  if (bx < 544){
    int wave = tid >> 6, lane = tid & 63;
    int b = bx / 34;
    int strip = (bx % 34)*4 + wave;     // 0..135
    int tw = strip / 17, k17 = strip - tw*17;
    int g0 = tw*256 + k17*8;
    size_t rbase = (size_t)b*GLEN;
    float cb[7][2], cw[7][2][4];
    #pragma unroll
    for (int k=0;k<7;k++){
      int c = 2*lane + 128*k;
      float2 t = *(const float2*)&conv_b[c];
      cb[k][0]=t.x; cb[k][1]=t.y;
      float4 w0 = *(const float4*)&conv_w[c*4];
      float4 w1 = *(const float4*)&conv_w[(c+1)*4];
      cw[k][0][0]=w0.x; cw[k][0][1]=w0.y; cw[k][0][2]=w0.z; cw[k][0][3]=w0.w;
      cw[k][1][0]=w1.x; cw[k][1][1]=w1.y; cw[k][1][2]=w1.z; cw[k][1][3]=w1.w;
    }
    float h0[7][2], h1[7][2], h2[7][2];
    #pragma unroll
    for (int k=0;k<7;k++){
      h0[k][0]=h0[k][1]=h1[k][0]=h1[k][1]=h2[k][0]=h2[k][1]=0.f;
    }
    if (g0 >= 3){
      #pragma unroll
      for (int k=0;k<7;k++){
        int c = 2*lane + 128*k;
        ushort2 p0 = *(const ushort2*)&projh[(rbase+g0-3)*NCC + c];
        ushort2 p1 = *(const ushort2*)&projh[(rbase+g0-2)*NCC + c];
        ushort2 p2 = *(const ushort2*)&projh[(rbase+g0-1)*NCC + c];
        h0[k][0]=frombf16(p0.x); h0[k][1]=frombf16(p0.y);
        h1[k][0]=frombf16(p1.x); h1[k][1]=frombf16(p1.y);
        h2[k][0]=frombf16(p2.x); h2[k][1]=frombf16(p2.y);
      }
    }
    #pragma unroll
    for (int i=0;i<8;i++){
      size_t row = rbase + g0 + i;
      float wreg = (lane < NH) ? wbuf[row*NH + lane] : 0.f;
      float cur[7][2];
      #pragma unroll
      for (int k=0;k<7;k++){
        int c = 2*lane + 128*k;
        ushort2 pv = *(const ushort2*)&projh[row*NCC + c];
        cur[k][0]=frombf16(pv.x); cur[k][1]=frombf16(pv.y);
      }
      float py0=0.f, py1=0.f, b0v=0.f, b1v=0.f;
      #pragma unroll
      for (int k=0;k<7;k++){
        float a0 = cb[k][0] + h0[k][0]*cw[k][0][0] + h1[k][0]*cw[k][0][1]
                            + h2[k][0]*cw[k][0][2] + cur[k][0]*cw[k][0][3];
        float a1 = cb[k][1] + h0[k][1]*cw[k][1][0] + h1[k][1]*cw[k][1][1]
                            + h2[k][1]*cw[k][1][2] + cur[k][1]*cw[k][1][3];
        float s0 = silu_f(a0), s1 = silu_f(a1);
        if (k < 6){
          float wh_ = __shfl(wreg, (lane>>4) + 4*k, 64);
          py0 += wh_*s0; py1 += wh_*s1;
        } else { b0v = s0; b1v = s1; }
      }
      py0 += __shfl_xor(py0, 16, 64); py0 += __shfl_xor(py0, 32, 64);
      py1 += __shfl_xor(py1, 16, 64); py1 += __shfl_xor(py1, 32, 64);
      float* dst = yB + row*160;
      if (lane < 16) *(float2*)&dst[2*lane] = make_float2(py0, py1);
      *(float2*)&dst[32 + 2*lane] = make_float2(b0v, b1v);
      #pragma unroll
      for (int k=0;k<7;k++){
        h0[k][0]=h1[k][0]; h0[k][1]=h1[k][1];
        h1[k][0]=h2[k][0]; h1[k][1]=h2[k][1];
        h2[k][0]=cur[k][0]; h2[k][1]=cur[k][1];
      }
    }
  } else if (bx < 672){
    float* Xc = smem;            // 896
    float* Ws = smem + 896;      // 24
    int idx = bx - 544;
    int t = idx & 7, b = idx >> 3;
    for (int c = tid; c < NCC; c += 256){
      float4 w = *(const float4*)&conv_w[c*4];
      float sw = w.x + w.y + w.z + w.w;
      float a = conv_b[c] + frombf16(tobf16(ptab[t*920 + c])) * sw;
      Xc[c] = silu_f(a);
    }
    if (tid < NH) Ws[tid] = wsum[((size_t)b*TWIN + t)*NH + tid];
    __syncthreads();
    float* dst = cB + ((size_t)(b*TWIN + t))*160;
    if (tid < 32){
      float y = 0.f;
      #pragma unroll
      for (int h=0;h<NH;h++) y += Ws[h]*Xc[h*32 + tid];
      dst[tid] = y;
    } else if (tid < 160){
      dst[tid] = Xc[768 + tid - 32];
    }
  } else {
    float* xsw  = smem;          // 896
    float* xsg  = smem + 896;    // 896
    float* wv   = smem + 1792;   // 24
    float* bufw = smem + 1816;   // 480
    float* bufg = smem + 2296;   // 480
    int idx = bx - 672;          // 0..111
    int b = idx / 7, t = idx % 7 + 1;
    size_t rbase = (size_t)b*GLEN;
    int g0 = t*256;
    for (int gi=0; gi<3; gi++){
      int g = g0 + gi;
      if (tid < NH) wv[tid] = wbuf[(rbase+g)*NH + tid];
      for (int c = tid; c < NCC; c += 256){
        float aw = conv_b[c], ag = conv_b[c];
        #pragma unroll
        for (int k=0;k<4;k++){
          int gp = g - 3 + k;
          float term = frombf16(projh[(rbase+gp)*NCC + c]) * conv_w[c*4+k];
          ag += term;
          if (gp >= g0) aw += term;
        }
        xsw[c] = silu_f(aw);
        xsg[c] = silu_f(ag);
      }
      __syncthreads();
      if (tid < 32){
        float yw = 0.f, yg = 0.f;
        #pragma unroll
        for (int h=0;h<NH;h++){ yw += wv[h]*xsw[h*32+tid]; yg += wv[h]*xsg[h*32+tid]; }
        bufw[gi*160 + tid] = yw;
        bufg[gi*160 + tid] = yg;
      } else if (tid < 160){
        bufw[gi*160 + tid] = xsw[768 + tid - 32];
        bufg[gi*160 + tid] = xsg[768 + tid - 32];
      }
      __syncthreads();
    }
    float* dst = cbuf + ((size_t)(b*TWIN + t))*960;
    for (int i = tid; i < 960; i += 256){
      int gi = i / 320, rem = i - gi*320;
      dst[i] = (rem < 160) ? bufw[gi*160 + rem] : bufg[gi*160 + rem - 160];
    }
  }
}

// Chunk partials over the 136 computed positions/window: 2 subs of 68.
__global__ __launch_bounds__(256) void k_partial(const float* __restrict__ yB,
    float* __restrict__ partial){
  int bt = blockIdx.x;            // b*8+t
  int sub = blockIdx.y;           // 0..1
  int b = bt >> 3, t = bt & 7;
  int tid = threadIdx.x;
  __shared__ float buf[8*160];
  int p0 = (tid >> 5) * 4;
  int n0 = (tid & 31) * 4;
  float acc[4][4] = {};
  size_t rbase = (size_t)b*GLEN;
  int gstart = t*256 + sub*68;
  int gend = gstart + 68;
  for (int gb = gstart; gb < gend; gb += 8){
    int cnt = min(8, gend - gb);
    for (int idx = tid; idx < cnt*160; idx += 256)
      buf[idx] = yB[(rbase+gb)*160 + idx];
    __syncthreads();
    for (int gi=0; gi<cnt; gi++){
      float4 yv = *(const float4*)&buf[gi*160 + p0];
      float4 bv = *(const float4*)&buf[gi*160 + 32 + n0];
      float ya[4] = {yv.x,yv.y,yv.z,yv.w};
      float ba[4] = {bv.x,bv.y,bv.z,bv.w};
      #pragma unroll
      for (int i=0;i<4;i++)
        #pragma unroll
        for (int j=0;j<4;j++)
          acc[i][j] += ya[i]*ba[j];
    }
    __syncthreads();
  }
  size_t pb = ((size_t)bt*2 + sub)*4096;
  #pragma unroll
  for (int i=0;i<4;i++)
    #pragma unroll
    for (int j=0;j<4;j++)
      partial[pb + (p0+i)*128 + n0+j] = acc[i][j];
}

// Suffix-sum + const-tail + inline boundary deltas.
__global__ __launch_bounds__(256) void k_suffix(const float* __restrict__ partial,
    const float* __restrict__ cB, const float* __restrict__ cbuf,
    float* __restrict__ feat){
  int b = blockIdx.y;
  int e = blockIdx.x*256 + threadIdx.x;   // 0..4095
  int p = e >> 7, n = e & 127;
  float s = 0.f;
  for (int t = TWIN-1; t >= 0; t--){
    int bt = b*TWIN + t;
    size_t pb = (size_t)bt*2*4096;
    s += partial[pb + e] + partial[pb + 4096 + e];
    const float* cb_ = cB + (size_t)bt*160;
    s += cb_[p] * cb_[32 + n];
    float f = s;
    if (t > 0){
      const float* cw_ = cbuf + (size_t)bt*960;
      #pragma unroll
      for (int gi=0; gi<3; gi++){
        const float* rw = cw_ + gi*320;
        f += rw[p]*rw[32+n] - rw[160+p]*rw[192+n];
      }
    }
    feat[(size_t)bt*4096 + e] = f;
  }
}

// Classifier: 4x4 register-tiled, grid (32 bt-quads, 25 k-quads).
__global__ __launch_bounds__(256) void k_classifier(const float* __restrict__ feat,
    const float* __restrict__ cls_w, const float* __restrict__ cls_b,
    float* __restrict__ out){
  int bt0 = blockIdx.x*4;
  int k0  = blockIdx.y*4;
  int tid = threadIdx.x, wid = tid >> 6, lane = tid & 63;
  float acc[4][4] = {};
  int j0 = wid*1024;
  #pragma unroll
  for (int it = 0; it < 4; it++){
    int j = j0 + it*256 + lane*4;
    float4 f4[4], w4[4];
    #pragma unroll
    for (int i=0;i<4;i++) f4[i] = *(const float4*)(feat + (size_t)(bt0+i)*4096 + j);
    #pragma unroll
    for (int k=0;k<4;k++) w4[k] = *(const float4*)(cls_w + (size_t)(k0+k)*4096 + j);
    #pragma unroll
    for (int i=0;i<4;i++)
      #pragma unroll
      for (int k=0;k<4;k++)
        acc[i][k] += f4[i].x*w4[k].x + f4[i].y*w4[k].y
                   + f4[i].z*w4[k].z + f4[i].w*w4[k].w;
  }
  #pragma unroll
  for (int i=0;i<4;i++)
    #pragma unroll
    for (int k=0;k<4;k++)
      #pragma unroll
      for (int o=32; o>0; o>>=1)
        acc[i][k] += __shfl_down(acc[i][k], o, 64);
  __shared__ float part[4][16];
  if (lane == 0){
    #pragma unroll
    for (int i=0;i<4;i++)
      #pragma unroll
      for (int k=0;k<4;k++)
        part[wid][i*4+k] = acc[i][k];
  }
  __syncthreads();
  if (tid < 16){
    int i = tid >> 2, k = tid & 3;
    float s = part[0][tid] + part[1][tid] + part[2][tid] + part[3][tid];
    out[(size_t)(bt0+i)*100 + k0 + k] = s + cls_b[k0+k];
  }
}

extern "C" void kernel_launch(void* const* d_in, const int* in_sizes, int n_in,
                              void* d_out, int out_size, void* d_ws, size_t ws_size,
                              hipStream_t stream){
  const float* inputs    = (const float*)d_in[0];
  const float* in_proj_w = (const float*)d_in[1];
  const float* conv_w    = (const float*)d_in[2];
  const float* conv_b    = (const float*)d_in[3];
  const float* dt_bias   = (const float*)d_in[4];
  const float* A_log     = (const float*)d_in[5];
  const float* cls_w     = (const float*)d_in[6];
  const float* cls_b     = (const float*)d_in[7];
  float* out = (float*)d_out;

  unsigned short* projh= (unsigned short*)d_ws;                 // MTOT*896 bf16
  float* dtraw         = (float*)(projh + (size_t)MTOT*NCC);    // NVALID*24 f32 (compact)
  float* wbuf          = dtraw + (size_t)NVALID*NH;             // MTOT*24 f32
  unsigned short* inh  = (unsigned short*)(wbuf + (size_t)MTOT*NH); // NVALID*192 bf16
  unsigned short* wh   = inh + (size_t)NVALID*DMODEL;           // NCC*192 bf16
  float* yB            = (float*)(wh + (size_t)NCC*DMODEL);     // MTOT*160 f32
  float* partial       = yB + (size_t)MTOT*160;                 // 256*4096 f32
  float* feat          = partial + (size_t)256*4096;            // 128*4096 f32
  float* ptab          = feat + (size_t)128*4096;               // 8*920 f32
  float* wsum          = ptab + (size_t)8*920;                  // 128*24 f32
  float* cB            = wsum + (size_t)128*NH;                 // 128*160 f32
  float* cbuf          = cB + (size_t)128*160;                  // 128*960 f32
  size_t need = (size_t)((char*)(cbuf + (size_t)128*960) - (char*)d_ws);
  if (ws_size < need) return;

  k_build      <<<BMAIN + 64 + 256, 256, 0, stream>>>(inputs, in_proj_w, inh, wh, ptab, dtraw);
  k_gemmall    <<<1024, 256, 0, stream>>>(inh, wh, ptab, projh);
  k_scan_w     <<<dim3(NH, BATCH), 256, 0, stream>>>(dtraw, ptab, dt_bias, A_log, wbuf, wsum);
  k_foldall    <<<784, 256, 0, stream>>>(projh, conv_w, conv_b, wbuf, ptab, wsum, yB, cB, cbuf);
  k_partial    <<<dim3(BATCH*TWIN, 2), 256, 0, stream>>>(yB, partial);
  k_suffix     <<<dim3(16, BATCH), 256, 0, stream>>>(partial, cB, cbuf, feat);
  k_classifier <<<dim3(32, 25), 256, 0, stream>>>(feat, cls_w, cls_b, out);
}

// Round 15
// 165.817 us; speedup vs baseline: 2.5495x; 1.0866x over previous
//
#include <hip/hip_runtime.h>
#include <math.h>

#define BATCH 16
#define TWIN 8
#define SEQIN 129
#define DMODEL 192
#define GLEN 2048           // TWIN*256
#define NH 24
#define HD 32
#define DS 128
#define NCC 896             // conv channels (x | B); dt handled separately
#define MTOT (BATCH*GLEN)   // 32768
#define NVALID (BATCH*TWIN*128) // 16384 rows with real input (s<128)
#define PADK 40             // GEMM LDS row pitch in bf16

typedef __attribute__((ext_vector_type(8))) short bf16x8;
typedef __attribute__((ext_vector_type(4))) float f32x4;

__device__ __forceinline__ float softplus_f(float x){
  return x > 20.f ? x : log1pf(expf(x));
}
__device__ __forceinline__ float silu_f(float x){
  return x / (1.f + __expf(-x));
}
__device__ __forceinline__ unsigned short tobf16(float f){
  union { float f; unsigned u; } v; v.f = f;
  unsigned r = v.u + 0x7FFF + ((v.u >> 16) & 1);
  return (unsigned short)(r >> 16);
}
__device__ __forceinline__ float frombf16(unsigned short u){
  union { unsigned u; float f; } v; v.u = ((unsigned)u) << 16; return v.f;
}
__device__ __forceinline__ bf16x8 pack8(float4 a, float4 b){
  bf16x8 r;
  r[0]=(short)tobf16(a.x); r[1]=(short)tobf16(a.y);
  r[2]=(short)tobf16(a.z); r[3]=(short)tobf16(a.w);
  r[4]=(short)tobf16(b.x); r[5]=(short)tobf16(b.y);
  r[6]=(short)tobf16(b.z); r[7]=(short)tobf16(b.w);
  return r;
}

// k_build: bf16 weight copy (84 blocks, 8 elems/thread) + ptab (64) + dt GEMM (256).
__global__ __launch_bounds__(256) void k_build(const float* __restrict__ in,
    const float* __restrict__ inw, unsigned short* __restrict__ wh,
    float* __restrict__ ptab, float* __restrict__ dtraw){
  __shared__ float smem[2048];
  int bx = blockIdx.x;
  int tid = threadIdx.x;
  if (bx < 84){
    int idx = (bx*256 + tid)*8;        // < NCC*DMODEL = 172032 exactly
    const float* src = inw + (size_t)768*DMODEL + idx;
    float4 a = *(const float4*)src;
    float4 b = *(const float4*)(src+4);
    *(bf16x8*)&wh[idx] = pack8(a, b);
  } else if (bx < 148){
    // ptab[t][e] = sum_d PE[t][d]*W[row(e)][d]  (fp32)
    float* pe = smem;
    int pb = bx - 84;             // 0..63
    int t = pb >> 3, eslice = pb & 7;
    if (tid < DMODEL){
      int d = tid;
      float div = expf(-(float)(d & ~1) * (logf(10000.f)/(float)DMODEL));
      float ang = (float)t * div;
      pe[d] = (d & 1) ? cosf(ang) : sinf(ang);
    }
    __syncthreads();
    int e0 = eslice*115;
    int e1 = min(920, e0 + 115);
    for (int e = e0 + tid; e < e1; e += 256){
      int row = (e < 896) ? (768 + e) : (1792 + (e - 896));
      const float* wr = inw + (size_t)row*DMODEL;
      float s = 0.f;
      #pragma unroll 4
      for (int d = 0; d < DMODEL; d++)
        s += pe[d] * wr[d];
      ptab[t*920 + e] = s;
    }
  } else {
    // fp32 GEMM for 24 dt channels, compact rows, NO ptab epilogue
    float* As = smem;          // [16][64]
    float* Bs = smem + 1024;
    int idx = bx - 148;                // 0..255
    int m0 = idx*64;                   // compact row base
    int bt = m0 >> 7, srow = m0 & 127;
    int ty = tid >> 4, tx = tid & 15;
    int lr = tid >> 2, lq = tid & 3;
    float acc[4][4] = {};
    for (int k0 = 0; k0 < DMODEL; k0 += 16){
      float4 av = *(const float4*)(in + ((size_t)bt*SEQIN + srow + 1 + lr)*DMODEL + k0 + lq*4);
      As[(lq*4+0)*64+lr] = av.x; As[(lq*4+1)*64+lr] = av.y;
      As[(lq*4+2)*64+lr] = av.z; As[(lq*4+3)*64+lr] = av.w;
      float4 bv = make_float4(0.f,0.f,0.f,0.f);
      if (lr < NH) bv = *(const float4*)(inw + (size_t)(1792+lr)*DMODEL + k0 + lq*4);
      Bs[(lq*4+0)*64+lr] = bv.x; Bs[(lq*4+1)*64+lr] = bv.y;
      Bs[(lq*4+2)*64+lr] = bv.z; Bs[(lq*4+3)*64+lr] = bv.w;
      __syncthreads();
      #pragma unroll
      for (int kk = 0; kk < 16; kk++){
        float4 a = *(const float4*)&As[kk*64 + ty*4];
        float4 bq = *(const float4*)&Bs[kk*64 + tx*4];
        float avr[4] = {a.x, a.y, a.z, a.w};
        float bvr[4] = {bq.x, bq.y, bq.z, bq.w};
        #pragma unroll
        for (int i=0;i<4;i++)
          #pragma unroll
          for (int j=0;j<4;j++)
            acc[i][j] += avr[i]*bvr[j];
      }
      __syncthreads();
    }
    #pragma unroll
    for (int i=0;i<4;i++){
      int m = m0 + ty*4 + i;
      #pragma unroll
      for (int j=0;j<4;j++){
        int n = tx*4 + j;
        if (n < NH) dtraw[(size_t)m*NH + n] = acc[i][j];
      }
    }
  }
}

// Fused: bf16 MFMA GEMM reading fp32 input directly (convert during staging,
// +ptab epilogue) + projh pad fill.
__global__ __launch_bounds__(256) void k_gemmall(const float* __restrict__ in,
    const unsigned short* __restrict__ wh, const float* __restrict__ ptab,
    unsigned short* __restrict__ projh){
  __shared__ char smem[20480];
  int bx = blockIdx.x;
  int tid = threadIdx.x;
  if (bx < 896){
    unsigned short* As = (unsigned short*)smem;
    unsigned short* Bs = As + 128*PADK;
    int mt = bx & 127;              // compact tile = bt index
    int n0 = (bx >> 7)*128;
    int t = mt & 7;
    size_t mdst = (size_t)(mt >> 3)*GLEN + (size_t)t*256;
    int wid = tid >> 6, lane = tid & 63;
    int wm = (wid >> 1)*64, wn = (wid & 1)*64;
    int quad = lane >> 4, lm = lane & 15;
    int sr = tid >> 2, sq = tid & 3;
    f32x4 acc[4][4];
    #pragma unroll
    for (int i=0;i<4;i++)
      #pragma unroll
      for (int j=0;j<4;j++) acc[i][j] = (f32x4){0.f,0.f,0.f,0.f};
    for (int k0 = 0; k0 < DMODEL; k0 += 32){
      #pragma unroll
      for (int half=0; half<2; half++){
        int r = sr + half*64;
        const float* srcA = in + ((size_t)mt*SEQIN + r + 1)*DMODEL + k0 + sq*8;
        float4 a0 = *(const float4*)srcA;
        float4 a1 = *(const float4*)(srcA + 4);
        *(bf16x8*)&As[r*PADK + sq*8] = pack8(a0, a1);
        *(bf16x8*)&Bs[r*PADK + sq*8] =
          *(const bf16x8*)&wh[(size_t)(n0+r)*DMODEL + k0 + sq*8];
      }
      __syncthreads();
      bf16x8 aF[4], bF[4];
      #pragma unroll
      for (int i=0;i<4;i++){
        aF[i] = *(const bf16x8*)&As[(wm + i*16 + lm)*PADK + quad*8];
        bF[i] = *(const bf16x8*)&Bs[(wn + i*16 + lm)*PADK + quad*8];
      }
      #pragma unroll
      for (int i=0;i<4;i++)
        #pragma unroll
        for (int j=0;j<4;j++)
          acc[i][j] = __builtin_amdgcn_mfma_f32_16x16x32_bf16(aF[i], bF[j], acc[i][j], 0,0,0);
      __syncthreads();
    }
    float ptn[4];
    #pragma unroll
    for (int j=0;j<4;j++) ptn[j] = ptab[t*920 + n0 + wn + lm + j*16];
    #pragma unroll
    for (int i=0;i<4;i++){
      #pragma unroll
      for (int r=0;r<4;r++){
        int m = wm + i*16 + quad*4 + r;
        unsigned short* dst = projh + (mdst + m)*NCC + n0 + wn + lm;
        #pragma unroll
        for (int j=0;j<4;j++)
          dst[j*16] = tobf16(acc[i][j][r] + ptn[j]);
      }
    }
  } else {
    // pad fill: projh rows s in {128..135, 252..255}
    float* pt = (float*)smem;
    int bt = bx - 896;             // 0..127
    int b = bt >> 3, t = bt & 7;
    for (int e = tid; e < NCC; e += 256) pt[e] = ptab[t*920 + e];
    __syncthreads();
    size_t base = (size_t)b*GLEN + t*256;
    for (int i = tid; i < 12*224; i += 256){
      int r = i / 224, c4 = (i - r*224)*4;
      int s = (r < 8) ? (128 + r) : (244 + r);
      ushort4 v;
      v.x = tobf16(pt[c4+0]); v.y = tobf16(pt[c4+1]);
      v.z = tobf16(pt[c4+2]); v.w = tobf16(pt[c4+3]);
      *(ushort4*)&projh[(base + s)*NCC + c4] = v;
    }
  }
}

// Per (b,h): w[g] = exp(csum_total - csum[g]) * dt[g]; Wsum over s>=136.
__global__ __launch_bounds__(256) void k_scan_w(const float* __restrict__ dtraw,
    const float* __restrict__ ptab, const float* __restrict__ dt_bias,
    const float* __restrict__ A_log, float* __restrict__ wbuf,
    float* __restrict__ wsum){
  int h = blockIdx.x, b = blockIdx.y;
  int tid = threadIdx.x;
  int lane = tid & 63, wid = tid >> 6;
  int tw = tid >> 5, q = tid & 31;
  float dtb = dt_bias[h];
  float negA = -expf(A_log[h]);
  float off = ptab[tw*920 + 896 + h] + dtb;
  float dtv[8], pre[8];
  float run = 0.f;
  if (q < 16){
    size_t rb = ((size_t)(b*TWIN + tw)*128 + q*8)*NH + h;
    #pragma unroll
    for (int i=0;i<8;i++){
      float dt = softplus_f(dtraw[rb + (size_t)i*NH] + off);
      run += dt * negA;
      dtv[i] = dt; pre[i] = run;
    }
  } else {
    float dt = softplus_f(off);
    #pragma unroll
    for (int i=0;i<8;i++){
      run += dt * negA;
      dtv[i] = dt; pre[i] = run;
    }
  }
  float v = run;
  #pragma unroll
  for (int o=1; o<64; o<<=1){
    float u = __shfl_up(v, o, 64);
    if (lane >= o) v += u;
  }
  __shared__ float wtot[4];
  __shared__ float sred[256];
  if (lane == 63) wtot[wid] = v;
  __syncthreads();
  float base = 0.f, total = 0.f;
  #pragma unroll
  for (int w2=0; w2<4; w2++){
    float tv = wtot[w2];
    if (w2 < wid) base += tv;
    total += tv;
  }
  float excl = base + v - run;
  float ls = 0.f;
  size_t gb = (size_t)b*GLEN + tw*256 + q*8;
  #pragma unroll
  for (int i=0;i<8;i++){
    float w = expf(total - (excl + pre[i])) * dtv[i];
    if (q < 17) wbuf[(gb + i)*NH + h] = w;
    else ls += w;
  }
  sred[tid] = ls;
  __syncthreads();
  if (q == 17){
    float acc = ls;
    for (int r = 18; r < 32; r++) acc += sred[tw*32 + r];
    wsum[((size_t)b*TWIN + tw)*NH + h] = acc;
  }
}

// Fused: per-strip fold (544) + const-tail rows (128) + boundary vectors (112).
__global__ __launch_bounds__(256) void k_foldall(const unsigned short* __restrict__ projh,
    const float* __restrict__ conv_w, const float* __restrict__ conv_b,
    const float* __restrict__ wbuf, const float* __restrict__ ptab,
    const float* __restrict__ wsum, float* __restrict__ yB,
    float* __restrict__ cB, float* __restrict__ cbuf){
  __shared__ float smem[2800];
  int bx = blockIdx.x;
  int tid = threadIdx.x;
  if (bx < 544){
    int wave = tid >> 6, lane = tid & 63;
    int b = bx / 34;
    int strip = (bx % 34)*4 + wave;     // 0..135
    int tw = strip / 17, k17 = strip - tw*17;
    int g0 = tw*256 + k17*8;
    size_t rbase = (size_t)b*GLEN;
    float cb[7][2], cw[7][2][4];
    #pragma unroll
    for (int k=0;k<7;k++){
      int c = 2*lane + 128*k;
      float2 t = *(const float2*)&conv_b[c];
      cb[k][0]=t.x; cb[k][1]=t.y;
      float4 w0 = *(const float4*)&conv_w[c*4];
      float4 w1 = *(const float4*)&conv_w[(c+1)*4];
      cw[k][0][0]=w0.x; cw[k][0][1]=w0.y; cw[k][0][2]=w0.z; cw[k][0][3]=w0.w;
      cw[k][1][0]=w1.x; cw[k][1][1]=w1.y; cw[k][1][2]=w1.z; cw[k][1][3]=w1.w;
    }
    float h0[7][2], h1[7][2], h2[7][2];
    #pragma unroll
    for (int k=0;k<7;k++){
      h0[k][0]=h0[k][1]=h1[k][0]=h1[k][1]=h2[k][0]=h2[k][1]=0.f;
    }
    if (g0 >= 3){
      #pragma unroll
      for (int k=0;k<7;k++){
        int c = 2*lane + 128*k;
        ushort2 p0 = *(const ushort2*)&projh[(rbase+g0-3)*NCC + c];
        ushort2 p1 = *(const ushort2*)&projh[(rbase+g0-2)*NCC + c];
        ushort2 p2 = *(const ushort2*)&projh[(rbase+g0-1)*NCC + c];
        h0[k][0]=frombf16(p0.x); h0[k][1]=frombf16(p0.y);
        h1[k][0]=frombf16(p1.x); h1[k][1]=frombf16(p1.y);
        h2[k][0]=frombf16(p2.x); h2[k][1]=frombf16(p2.y);
      }
    }
    #pragma unroll
    for (int i=0;i<8;i++){
      size_t row = rbase + g0 + i;
      float wreg = (lane < NH) ? wbuf[row*NH + lane] : 0.f;
      float cur[7][2];
      #pragma unroll
      for (int k=0;k<7;k++){
        int c = 2*lane + 128*k;
        ushort2 pv = *(const ushort2*)&projh[row*NCC + c];
        cur[k][0]=frombf16(pv.x); cur[k][1]=frombf16(pv.y);
      }
      float py0=0.f, py1=0.f, b0v=0.f, b1v=0.f;
      #pragma unroll
      for (int k=0;k<7;k++){
        float a0 = cb[k][0] + h0[k][0]*cw[k][0][0] + h1[k][0]*cw[k][0][1]
                            + h2[k][0]*cw[k][0][2] + cur[k][0]*cw[k][0][3];
        float a1 = cb[k][1] + h0[k][1]*cw[k][1][0] + h1[k][1]*cw[k][1][1]
                            + h2[k][1]*cw[k][1][2] + cur[k][1]*cw[k][1][3];
        float s0 = silu_f(a0), s1 = silu_f(a1);
        if (k < 6){
          float wh_ = __shfl(wreg, (lane>>4) + 4*k, 64);
          py0 += wh_*s0; py1 += wh_*s1;
        } else { b0v = s0; b1v = s1; }
      }
      py0 += __shfl_xor(py0, 16, 64); py0 += __shfl_xor(py0, 32, 64);
      py1 += __shfl_xor(py1, 16, 64); py1 += __shfl_xor(py1, 32, 64);
      float* dst = yB + row*160;
      if (lane < 16) *(float2*)&dst[2*lane] = make_float2(py0, py1);
      *(float2*)&dst[32 + 2*lane] = make_float2(b0v, b1v);
      #pragma unroll
      for (int k=0;k<7;k++){
        h0[k][0]=h1[k][0]; h0[k][1]=h1[k][1];
        h1[k][0]=h2[k][0]; h1[k][1]=h2[k][1];
        h2[k][0]=cur[k][0]; h2[k][1]=cur[k][1];
      }
    }
  } else if (bx < 672){
    float* Xc = smem;            // 896
    float* Ws = smem + 896;      // 24
    int idx = bx - 544;
    int t = idx & 7, b = idx >> 3;
    for (int c = tid; c < NCC; c += 256){
      float4 w = *(const float4*)&conv_w[c*4];
      float sw = w.x + w.y + w.z + w.w;
      float a = conv_b[c] + frombf16(tobf16(ptab[t*920 + c])) * sw;
      Xc[c] = silu_f(a);
    }
    if (tid < NH) Ws[tid] = wsum[((size_t)b*TWIN + t)*NH + tid];
    __syncthreads();
    float* dst = cB + ((size_t)(b*TWIN + t))*160;
    if (tid < 32){
      float y = 0.f;
      #pragma unroll
      for (int h=0;h<NH;h++) y += Ws[h]*Xc[h*32 + tid];
      dst[tid] = y;
    } else if (tid < 160){
      dst[tid] = Xc[768 + tid - 32];
    }
  } else {
    float* xsw  = smem;          // 896
    float* xsg  = smem + 896;    // 896
    float* wv   = smem + 1792;   // 24
    float* bufw = smem + 1816;   // 480
    float* bufg = smem + 2296;   // 480
    int idx = bx - 672;          // 0..111
    int b = idx / 7, t = idx % 7 + 1;
    size_t rbase = (size_t)b*GLEN;
    int g0 = t*256;
    for (int gi=0; gi<3; gi++){
      int g = g0 + gi;
      if (tid < NH) wv[tid] = wbuf[(rbase+g)*NH + tid];
      for (int c = tid; c < NCC; c += 256){
        float aw = conv_b[c], ag = conv_b[c];
        #pragma unroll
        for (int k=0;k<4;k++){
          int gp = g - 3 + k;
          float term = frombf16(projh[(rbase+gp)*NCC + c]) * conv_w[c*4+k];
          ag += term;
          if (gp >= g0) aw += term;
        }
        xsw[c] = silu_f(aw);
        xsg[c] = silu_f(ag);
      }
      __syncthreads();
      if (tid < 32){
        float yw = 0.f, yg = 0.f;
        #pragma unroll
        for (int h=0;h<NH;h++){ yw += wv[h]*xsw[h*32+tid]; yg += wv[h]*xsg[h*32+tid]; }
        bufw[gi*160 + tid] = yw;
        bufg[gi*160 + tid] = yg;
      } else if (tid < 160){
        bufw[gi*160 + tid] = xsw[768 + tid - 32];
        bufg[gi*160 + tid] = xsg[768 + tid - 32];
      }
      __syncthreads();
    }
    float* dst = cbuf + ((size_t)(b*TWIN + t))*960;
    for (int i = tid; i < 960; i += 256){
      int gi = i / 320, rem = i - gi*320;
      dst[i] = (rem < 160) ? bufw[gi*160 + rem] : bufg[gi*160 + rem - 160];
    }
  }
}

// Chunk partials over the 136 computed positions/window: 2 subs of 68.
__global__ __launch_bounds__(256) void k_partial(const float* __restrict__ yB,
    float* __restrict__ partial){
  int bt = blockIdx.x;            // b*8+t
  int sub = blockIdx.y;           // 0..1
  int b = bt >> 3, t = bt & 7;
  int tid = threadIdx.x;
  __shared__ float buf[8*160];
  int p0 = (tid >> 5) * 4;
  int n0 = (tid & 31) * 4;
  float acc[4][4] = {};
  size_t rbase = (size_t)b*GLEN;
  int gstart = t*256 + sub*68;
  int gend = gstart + 68;
  for (int gb = gstart; gb < gend; gb += 8){
    int cnt = min(8, gend - gb);
    for (int idx = tid; idx < cnt*160; idx += 256)
      buf[idx] = yB[(rbase+gb)*160 + idx];
    __syncthreads();
    for (int gi=0; gi<cnt; gi++){
      float4 yv = *(const float4*)&buf[gi*160 + p0];
      float4 bv = *(const float4*)&buf[gi*160 + 32 + n0];
      float ya[4] = {yv.x,yv.y,yv.z,yv.w};
      float ba[4] = {bv.x,bv.y,bv.z,bv.w};
      #pragma unroll
      for (int i=0;i<4;i++)
        #pragma unroll
        for (int j=0;j<4;j++)
          acc[i][j] += ya[i]*ba[j];
    }
    __syncthreads();
  }
  size_t pb = ((size_t)bt*2 + sub)*4096;
  #pragma unroll
  for (int i=0;i<4;i++)
    #pragma unroll
    for (int j=0;j<4;j++)
      partial[pb + (p0+i)*128 + n0+j] = acc[i][j];
}

// Suffix-sum + const-tail + inline boundary deltas.
__global__ __launch_bounds__(256) void k_suffix(const float* __restrict__ partial,
    const float* __restrict__ cB, const float* __restrict__ cbuf,
    float* __restrict__ feat){
  int b = blockIdx.y;
  int e = blockIdx.x*256 + threadIdx.x;   // 0..4095
  int p = e >> 7, n = e & 127;
  float s = 0.f;
  for (int t = TWIN-1; t >= 0; t--){
    int bt = b*TWIN + t;
    size_t pb = (size_t)bt*2*4096;
    s += partial[pb + e] + partial[pb + 4096 + e];
    const float* cb_ = cB + (size_t)bt*160;
    s += cb_[p] * cb_[32 + n];
    float f = s;
    if (t > 0){
      const float* cw_ = cbuf + (size_t)bt*960;
      #pragma unroll
      for (int gi=0; gi<3; gi++){
        const float* rw = cw_ + gi*320;
        f += rw[p]*rw[32+n] - rw[160+p]*rw[192+n];
      }
    }
    feat[(size_t)bt*4096 + e] = f;
  }
}

// Classifier: 4x4 register-tiled, grid (32 bt-quads, 25 k-quads).
__global__ __launch_bounds__(256) void k_classifier(const float* __restrict__ feat,
    const float* __restrict__ cls_w, const float* __restrict__ cls_b,
    float* __restrict__ out){
  int bt0 = blockIdx.x*4;
  int k0  = blockIdx.y*4;
  int tid = threadIdx.x, wid = tid >> 6, lane = tid & 63;
  float acc[4][4] = {};
  int j0 = wid*1024;
  #pragma unroll
  for (int it = 0; it < 4; it++){
    int j = j0 + it*256 + lane*4;
    float4 f4[4], w4[4];
    #pragma unroll
    for (int i=0;i<4;i++) f4[i] = *(const float4*)(feat + (size_t)(bt0+i)*4096 + j);
    #pragma unroll
    for (int k=0;k<4;k++) w4[k] = *(const float4*)(cls_w + (size_t)(k0+k)*4096 + j);
    #pragma unroll
    for (int i=0;i<4;i++)
      #pragma unroll
      for (int k=0;k<4;k++)
        acc[i][k] += f4[i].x*w4[k].x + f4[i].y*w4[k].y
                   + f4[i].z*w4[k].z + f4[i].w*w4[k].w;
  }
  #pragma unroll
  for (int i=0;i<4;i++)
    #pragma unroll
    for (int k=0;k<4;k++)
      #pragma unroll
      for (int o=32; o>0; o>>=1)
        acc[i][k] += __shfl_down(acc[i][k], o, 64);
  __shared__ float part[4][16];
  if (lane == 0){
    #pragma unroll
    for (int i=0;i<4;i++)
      #pragma unroll
      for (int k=0;k<4;k++)
        part[wid][i*4+k] = acc[i][k];
  }
  __syncthreads();
  if (tid < 16){
    int i = tid >> 2, k = tid & 3;
    float s = part[0][tid] + part[1][tid] + part[2][tid] + part[3][tid];
    out[(size_t)(bt0+i)*100 + k0 + k] = s + cls_b[k0+k];
  }
}

extern "C" void kernel_launch(void* const* d_in, const int* in_sizes, int n_in,
                              void* d_out, int out_size, void* d_ws, size_t ws_size,
                              hipStream_t stream){
  const float* inputs    = (const float*)d_in[0];
  const float* in_proj_w = (const float*)d_in[1];
  const float* conv_w    = (const float*)d_in[2];
  const float* conv_b    = (const float*)d_in[3];
  const float* dt_bias   = (const float*)d_in[4];
  const float* A_log     = (const float*)d_in[5];
  const float* cls_w     = (const float*)d_in[6];
  const float* cls_b     = (const float*)d_in[7];
  float* out = (float*)d_out;

  unsigned short* projh= (unsigned short*)d_ws;                 // MTOT*896 bf16
  float* dtraw         = (float*)(projh + (size_t)MTOT*NCC);    // NVALID*24 f32 (compact)
  float* wbuf          = dtraw + (size_t)NVALID*NH;             // MTOT*24 f32
  unsigned short* wh   = (unsigned short*)(wbuf + (size_t)MTOT*NH); // NCC*192 bf16
  float* yB            = (float*)(wh + (size_t)NCC*DMODEL);     // MTOT*160 f32
  float* partial       = yB + (size_t)MTOT*160;                 // 256*4096 f32
  float* feat          = partial + (size_t)256*4096;            // 128*4096 f32
  float* ptab          = feat + (size_t)128*4096;               // 8*920 f32
  float* wsum          = ptab + (size_t)8*920;                  // 128*24 f32
  float* cB            = wsum + (size_t)128*NH;                 // 128*160 f32
  float* cbuf          = cB + (size_t)128*160;                  // 128*960 f32
  size_t need = (size_t)((char*)(cbuf + (size_t)128*960) - (char*)d_ws);
  if (ws_size < need) return;

  k_build      <<<404, 256, 0, stream>>>(inputs, in_proj_w, wh, ptab, dtraw);
  k_gemmall    <<<1024, 256, 0, stream>>>(inputs, wh, ptab, projh);
  k_scan_w     <<<dim3(NH, BATCH), 256, 0, stream>>>(dtraw, ptab, dt_bias, A_log, wbuf, wsum);
  k_foldall    <<<784, 256, 0, stream>>>(projh, conv_w, conv_b, wbuf, ptab, wsum, yB, cB, cbuf);
  k_partial    <<<dim3(BATCH*TWIN, 2), 256, 0, stream>>>(yB, partial);
  k_suffix     <<<dim3(16, BATCH), 256, 0, stream>>>(partial, cB, cbuf, feat);
  k_classifier <<<dim3(32, 25), 256, 0, stream>>>(feat, cls_w, cls_b, out);
}

// Round 16
// 160.948 us; speedup vs baseline: 2.6266x; 1.0303x over previous
//
#include <hip/hip_runtime.h>
#include <math.h>

#define BATCH 16
#define TWIN 8
#define SEQIN 129
#define DMODEL 192
#define GLEN 2048           // TWIN*256
#define NH 24
#define HD 32
#define DS 128
#define NCC 896             // conv channels (x | B); dt handled separately
#define MTOT (BATCH*GLEN)   // 32768
#define NVALID (BATCH*TWIN*128) // 16384 rows with real input (s<128)
#define PADK 40             // GEMM LDS row pitch in bf16

typedef __attribute__((ext_vector_type(8))) short bf16x8;
typedef __attribute__((ext_vector_type(4))) float f32x4;

__device__ __forceinline__ float softplus_f(float x){
  return x > 20.f ? x : log1pf(expf(x));
}
__device__ __forceinline__ float silu_f(float x){
  return x / (1.f + __expf(-x));
}
__device__ __forceinline__ unsigned short tobf16(float f){
  union { float f; unsigned u; } v; v.f = f;
  unsigned r = v.u + 0x7FFF + ((v.u >> 16) & 1);
  return (unsigned short)(r >> 16);
}
__device__ __forceinline__ float frombf16(unsigned short u){
  union { unsigned u; float f; } v; v.u = ((unsigned)u) << 16; return v.f;
}
__device__ __forceinline__ bf16x8 pack8(float4 a, float4 b){
  bf16x8 r;
  r[0]=(short)tobf16(a.x); r[1]=(short)tobf16(a.y);
  r[2]=(short)tobf16(a.z); r[3]=(short)tobf16(a.w);
  r[4]=(short)tobf16(b.x); r[5]=(short)tobf16(b.y);
  r[6]=(short)tobf16(b.z); r[7]=(short)tobf16(b.w);
  return r;
}

// k_build: vectorized input cast (768 blocks, 16 elems/thread) + bf16 weight
// copy (84) + ptab (64) + compact dt GEMM (256). 1172 blocks total.
__global__ __launch_bounds__(256) void k_build(const float* __restrict__ in,
    const float* __restrict__ inw, unsigned short* __restrict__ inh,
    unsigned short* __restrict__ wh, float* __restrict__ ptab,
    float* __restrict__ dtraw){
  __shared__ float smem[2048];
  int bx = blockIdx.x;
  int tid = threadIdx.x;
  if (bx < 768){
    // compact bf16 cast: idx multiple of 16; 192%16==0 so chunk stays in-row
    int idx = (bx*256 + tid)*16;      // < NVALID*DMODEL = 3145728 exactly
    int v = idx / DMODEL;             // compact row: bt*128 + s
    int d = idx - v*DMODEL;
    int bt = v >> 7, s = v & 127;
    const float* src = in + ((size_t)bt*SEQIN + s + 1)*DMODEL + d;
    float4 a0 = *(const float4*)src;
    float4 a1 = *(const float4*)(src+4);
    float4 a2 = *(const float4*)(src+8);
    float4 a3 = *(const float4*)(src+12);
    *(bf16x8*)&inh[idx]   = pack8(a0, a1);
    *(bf16x8*)&inh[idx+8] = pack8(a2, a3);
  } else if (bx < 852){
    int idx = ((bx-768)*256 + tid)*8;  // < NCC*DMODEL = 172032 exactly
    const float* src = inw + (size_t)768*DMODEL + idx;
    float4 a = *(const float4*)src;
    float4 b = *(const float4*)(src+4);
    *(bf16x8*)&wh[idx] = pack8(a, b);
  } else if (bx < 916){
    // ptab[t][e] = sum_d PE[t][d]*W[row(e)][d]  (fp32)
    float* pe = smem;
    int pb = bx - 852;            // 0..63
    int t = pb >> 3, eslice = pb & 7;
    if (tid < DMODEL){
      int d = tid;
      float div = expf(-(float)(d & ~1) * (logf(10000.f)/(float)DMODEL));
      float ang = (float)t * div;
      pe[d] = (d & 1) ? cosf(ang) : sinf(ang);
    }
    __syncthreads();
    int e0 = eslice*115;
    int e1 = min(920, e0 + 115);
    for (int e = e0 + tid; e < e1; e += 256){
      int row = (e < 896) ? (768 + e) : (1792 + (e - 896));
      const float* wr = inw + (size_t)row*DMODEL;
      float s = 0.f;
      #pragma unroll 4
      for (int d = 0; d < DMODEL; d++)
        s += pe[d] * wr[d];
      ptab[t*920 + e] = s;
    }
  } else {
    // fp32 GEMM for 24 dt channels, compact rows, NO ptab epilogue
    float* As = smem;          // [16][64]
    float* Bs = smem + 1024;
    int idx = bx - 916;                // 0..255
    int m0 = idx*64;                   // compact row base
    int bt = m0 >> 7, srow = m0 & 127;
    int ty = tid >> 4, tx = tid & 15;
    int lr = tid >> 2, lq = tid & 3;
    float acc[4][4] = {};
    for (int k0 = 0; k0 < DMODEL; k0 += 16){
      float4 av = *(const float4*)(in + ((size_t)bt*SEQIN + srow + 1 + lr)*DMODEL + k0 + lq*4);
      As[(lq*4+0)*64+lr] = av.x; As[(lq*4+1)*64+lr] = av.y;
      As[(lq*4+2)*64+lr] = av.z; As[(lq*4+3)*64+lr] = av.w;
      float4 bv = make_float4(0.f,0.f,0.f,0.f);
      if (lr < NH) bv = *(const float4*)(inw + (size_t)(1792+lr)*DMODEL + k0 + lq*4);
      Bs[(lq*4+0)*64+lr] = bv.x; Bs[(lq*4+1)*64+lr] = bv.y;
      Bs[(lq*4+2)*64+lr] = bv.z; Bs[(lq*4+3)*64+lr] = bv.w;
      __syncthreads();
      #pragma unroll
      for (int kk = 0; kk < 16; kk++){
        float4 a = *(const float4*)&As[kk*64 + ty*4];
        float4 bq = *(const float4*)&Bs[kk*64 + tx*4];
        float avr[4] = {a.x, a.y, a.z, a.w};
        float bvr[4] = {bq.x, bq.y, bq.z, bq.w};
        #pragma unroll
        for (int i=0;i<4;i++)
          #pragma unroll
          for (int j=0;j<4;j++)
            acc[i][j] += avr[i]*bvr[j];
      }
      __syncthreads();
    }
    #pragma unroll
    for (int i=0;i<4;i++){
      int m = m0 + ty*4 + i;
      #pragma unroll
      for (int j=0;j<4;j++){
        int n = tx*4 + j;
        if (n < NH) dtraw[(size_t)m*NH + n] = acc[i][j];
      }
    }
  }
}

// Fused: bf16 MFMA GEMM on compact inh (+ptab epilogue) + projh pad fill
// + scan_w (independent of GEMM blocks; depends only on k_build outputs).
__global__ __launch_bounds__(256) void k_gemmall(const unsigned short* __restrict__ inh,
    const unsigned short* __restrict__ wh, const float* __restrict__ ptab,
    const float* __restrict__ dtraw, const float* __restrict__ dt_bias,
    const float* __restrict__ A_log, unsigned short* __restrict__ projh,
    float* __restrict__ wbuf, float* __restrict__ wsum){
  __shared__ char smem[20480];
  int bx = blockIdx.x;
  int tid = threadIdx.x;
  if (bx < 896){
    unsigned short* As = (unsigned short*)smem;
    unsigned short* Bs = As + 128*PADK;
    int mt = bx & 127;              // compact tile = bt index
    int n0 = (bx >> 7)*128;
    int t = mt & 7;
    size_t msrc = (size_t)mt*128;
    size_t mdst = (size_t)(mt >> 3)*GLEN + (size_t)t*256;
    int wid = tid >> 6, lane = tid & 63;
    int wm = (wid >> 1)*64, wn = (wid & 1)*64;
    int quad = lane >> 4, lm = lane & 15;
    int sr = tid >> 2, sq = tid & 3;
    f32x4 acc[4][4];
    #pragma unroll
    for (int i=0;i<4;i++)
      #pragma unroll
      for (int j=0;j<4;j++) acc[i][j] = (f32x4){0.f,0.f,0.f,0.f};
    for (int k0 = 0; k0 < DMODEL; k0 += 32){
      #pragma unroll
      for (int half=0; half<2; half++){
        int r = sr + half*64;
        *(bf16x8*)&As[r*PADK + sq*8] =
          *(const bf16x8*)&inh[(msrc + r)*DMODEL + k0 + sq*8];
        *(bf16x8*)&Bs[r*PADK + sq*8] =
          *(const bf16x8*)&wh[(size_t)(n0+r)*DMODEL + k0 + sq*8];
      }
      __syncthreads();
      bf16x8 aF[4], bF[4];
      #pragma unroll
      for (int i=0;i<4;i++){
        aF[i] = *(const bf16x8*)&As[(wm + i*16 + lm)*PADK + quad*8];
        bF[i] = *(const bf16x8*)&Bs[(wn + i*16 + lm)*PADK + quad*8];
      }
      #pragma unroll
      for (int i=0;i<4;i++)
        #pragma unroll
        for (int j=0;j<4;j++)
          acc[i][j] = __builtin_amdgcn_mfma_f32_16x16x32_bf16(aF[i], bF[j], acc[i][j], 0,0,0);
      __syncthreads();
    }
    float ptn[4];
    #pragma unroll
    for (int j=0;j<4;j++) ptn[j] = ptab[t*920 + n0 + wn + lm + j*16];
    #pragma unroll
    for (int i=0;i<4;i++){
      #pragma unroll
      for (int r=0;r<4;r++){
        int m = wm + i*16 + quad*4 + r;
        unsigned short* dst = projh + (mdst + m)*NCC + n0 + wn + lm;
        #pragma unroll
        for (int j=0;j<4;j++)
          dst[j*16] = tobf16(acc[i][j][r] + ptn[j]);
      }
    }
  } else if (bx < 1024){
    // pad fill: projh rows s in {128..135, 252..255}
    float* pt = (float*)smem;
    int bt = bx - 896;             // 0..127
    int b = bt >> 3, t = bt & 7;
    for (int e = tid; e < NCC; e += 256) pt[e] = ptab[t*920 + e];
    __syncthreads();
    size_t base = (size_t)b*GLEN + t*256;
    for (int i = tid; i < 12*224; i += 256){
      int r = i / 224, c4 = (i - r*224)*4;
      int s = (r < 8) ? (128 + r) : (244 + r);
      ushort4 v;
      v.x = tobf16(pt[c4+0]); v.y = tobf16(pt[c4+1]);
      v.z = tobf16(pt[c4+2]); v.w = tobf16(pt[c4+3]);
      *(ushort4*)&projh[(base + s)*NCC + c4] = v;
    }
  } else {
    // scan_w: per (b,h) decay weights + const-tail sums
    float* wtot = (float*)smem;        // 4
    float* sred = (float*)smem + 4;    // 256
    int idx = bx - 1024;               // 0..383
    int h = idx % NH, b = idx / NH;
    int lane = tid & 63, wid = tid >> 6;
    int tw = tid >> 5, q = tid & 31;
    float dtb = dt_bias[h];
    float negA = -expf(A_log[h]);
    float off = ptab[tw*920 + 896 + h] + dtb;
    float dtv[8], pre[8];
    float run = 0.f;
    if (q < 16){
      size_t rb = ((size_t)(b*TWIN + tw)*128 + q*8)*NH + h;
      #pragma unroll
      for (int i=0;i<8;i++){
        float dt = softplus_f(dtraw[rb + (size_t)i*NH] + off);
        run += dt * negA;
        dtv[i] = dt; pre[i] = run;
      }
    } else {
      float dt = softplus_f(off);
      #pragma unroll
      for (int i=0;i<8;i++){
        run += dt * negA;
        dtv[i] = dt; pre[i] = run;
      }
    }
    float v = run;
    #pragma unroll
    for (int o=1; o<64; o<<=1){
      float u = __shfl_up(v, o, 64);
      if (lane >= o) v += u;
    }
    if (lane == 63) wtot[wid] = v;
    __syncthreads();
    float base = 0.f, total = 0.f;
    #pragma unroll
    for (int w2=0; w2<4; w2++){
      float tv = wtot[w2];
      if (w2 < wid) base += tv;
      total += tv;
    }
    float excl = base + v - run;
    float ls = 0.f;
    size_t gb = (size_t)b*GLEN + tw*256 + q*8;
    #pragma unroll
    for (int i=0;i<8;i++){
      float w = expf(total - (excl + pre[i])) * dtv[i];
      if (q < 17) wbuf[(gb + i)*NH + h] = w;
      else ls += w;
    }
    sred[tid] = ls;
    __syncthreads();
    if (q == 17){
      float acc = ls;
      for (int r = 18; r < 32; r++) acc += sred[tw*32 + r];
      wsum[((size_t)b*TWIN + tw)*NH + h] = acc;
    }
  }
}

// Fused: per-strip fold (544) + const-tail rows (128) + boundary vectors (112).
__global__ __launch_bounds__(256) void k_foldall(const unsigned short* __restrict__ projh,
    const float* __restrict__ conv_w, const float* __restrict__ conv_b,
    const float* __restrict__ wbuf, const float* __restrict__ ptab,
    const float* __restrict__ wsum, float* __restrict__ yB,
    float* __restrict__ cB, float* __restrict__ cbuf){
  __shared__ float smem[2800];
  int bx = blockIdx.x;
  int tid = threadIdx.x;
  if (bx < 544){
    int wave = tid >> 6, lane = tid & 63;
    int b = bx / 34;
    int strip = (bx % 34)*4 + wave;     // 0..135
    int tw = strip / 17, k17 = strip - tw*17;
    int g0 = tw*256 + k17*8;
    size_t rbase = (size_t)b*GLEN;
    float cb[7][2], cw[7][2][4];
    #pragma unroll
    for (int k=0;k<7;k++){
      int c = 2*lane + 128*k;
      float2 t = *(const float2*)&conv_b[c];
      cb[k][0]=t.x; cb[k][1]=t.y;
      float4 w0 = *(const float4*)&conv_w[c*4];
      float4 w1 = *(const float4*)&conv_w[(c+1)*4];
      cw[k][0][0]=w0.x; cw[k][0][1]=w0.y; cw[k][0][2]=w0.z; cw[k][0][3]=w0.w;
      cw[k][1][0]=w1.x; cw[k][1][1]=w1.y; cw[k][1][2]=w1.z; cw[k][1][3]=w1.w;
    }
    float h0[7][2], h1[7][2], h2[7][2];
    #pragma unroll
    for (int k=0;k<7;k++){
      h0[k][0]=h0[k][1]=h1[k][0]=h1[k][1]=h2[k][0]=h2[k][1]=0.f;
    }
    if (g0 >= 3){
      #pragma unroll
      for (int k=0;k<7;k++){
        int c = 2*lane + 128*k;
        ushort2 p0 = *(const ushort2*)&projh[(rbase+g0-3)*NCC + c];
        ushort2 p1 = *(const ushort2*)&projh[(rbase+g0-2)*NCC + c];
        ushort2 p2 = *(const ushort2*)&projh[(rbase+g0-1)*NCC + c];
        h0[k][0]=frombf16(p0.x); h0[k][1]=frombf16(p0.y);
        h1[k][0]=frombf16(p1.x); h1[k][1]=frombf16(p1.y);
        h2[k][0]=frombf16(p2.x); h2[k][1]=frombf16(p2.y);
      }
    }
    #pragma unroll
    for (int i=0;i<8;i++){
      size_t row = rbase + g0 + i;
      float wreg = (lane < NH) ? wbuf[row*NH + lane] : 0.f;
      float cur[7][2];
      #pragma unroll
      for (int k=0;k<7;k++){
        int c = 2*lane + 128*k;
        ushort2 pv = *(const ushort2*)&projh[row*NCC + c];
        cur[k][0]=frombf16(pv.x); cur[k][1]=frombf16(pv.y);
      }
      float py0=0.f, py1=0.f, b0v=0.f, b1v=0.f;
      #pragma unroll
      for (int k=0;k<7;k++){
        float a0 = cb[k][0] + h0[k][0]*cw[k][0][0] + h1[k][0]*cw[k][0][1]
                            + h2[k][0]*cw[k][0][2] + cur[k][0]*cw[k][0][3];
        float a1 = cb[k][1] + h0[k][1]*cw[k][1][0] + h1[k][1]*cw[k][1][1]
                            + h2[k][1]*cw[k][1][2] + cur[k][1]*cw[k][1][3];
        float s0 = silu_f(a0), s1 = silu_f(a1);
        if (k < 6){
          float wh_ = __shfl(wreg, (lane>>4) + 4*k, 64);
          py0 += wh_*s0; py1 += wh_*s1;
        } else { b0v = s0; b1v = s1; }
      }
      py0 += __shfl_xor(py0, 16, 64); py0 += __shfl_xor(py0, 32, 64);
      py1 += __shfl_xor(py1, 16, 64); py1 += __shfl_xor(py1, 32, 64);
      float* dst = yB + row*160;
      if (lane < 16) *(float2*)&dst[2*lane] = make_float2(py0, py1);
      *(float2*)&dst[32 + 2*lane] = make_float2(b0v, b1v);
      #pragma unroll
      for (int k=0;k<7;k++){
        h0[k][0]=h1[k][0]; h0[k][1]=h1[k][1];
        h1[k][0]=h2[k][0]; h1[k][1]=h2[k][1];
        h2[k][0]=cur[k][0]; h2[k][1]=cur[k][1];
      }
    }
  } else if (bx < 672){
    float* Xc = smem;            // 896
    float* Ws = smem + 896;      // 24
    int idx = bx - 544;
    int t = idx & 7, b = idx >> 3;
    for (int c = tid; c < NCC; c += 256){
      float4 w = *(const float4*)&conv_w[c*4];
      float sw = w.x + w.y + w.z + w.w;
      float a = conv_b[c] + frombf16(tobf16(ptab[t*920 + c])) * sw;
      Xc[c] = silu_f(a);
    }
    if (tid < NH) Ws[tid] = wsum[((size_t)b*TWIN + t)*NH + tid];
    __syncthreads();
    float* dst = cB + ((size_t)(b*TWIN + t))*160;
    if (tid < 32){
      float y = 0.f;
      #pragma unroll
      for (int h=0;h<NH;h++) y += Ws[h]*Xc[h*32 + tid];
      dst[tid] = y;
    } else if (tid < 160){
      dst[tid] = Xc[768 + tid - 32];
    }
  } else {
    float* xsw  = smem;          // 896
    float* xsg  = smem + 896;    // 896
    float* wv   = smem + 1792;   // 24
    float* bufw = smem + 1816;   // 480
    float* bufg = smem + 2296;   // 480
    int idx = bx - 672;          // 0..111
    int b = idx / 7, t = idx % 7 + 1;
    size_t rbase = (size_t)b*GLEN;
    int g0 = t*256;
    for (int gi=0; gi<3; gi++){
      int g = g0 + gi;
      if (tid < NH) wv[tid] = wbuf[(rbase+g)*NH + tid];
      for (int c = tid; c < NCC; c += 256){
        float aw = conv_b[c], ag = conv_b[c];
        #pragma unroll
        for (int k=0;k<4;k++){
          int gp = g - 3 + k;
          float term = frombf16(projh[(rbase+gp)*NCC + c]) * conv_w[c*4+k];
          ag += term;
          if (gp >= g0) aw += term;
        }
        xsw[c] = silu_f(aw);
        xsg[c] = silu_f(ag);
      }
      __syncthreads();
      if (tid < 32){
        float yw = 0.f, yg = 0.f;
        #pragma unroll
        for (int h=0;h<NH;h++){ yw += wv[h]*xsw[h*32+tid]; yg += wv[h]*xsg[h*32+tid]; }
        bufw[gi*160 + tid] = yw;
        bufg[gi*160 + tid] = yg;
      } else if (tid < 160){
        bufw[gi*160 + tid] = xsw[768 + tid - 32];
        bufg[gi*160 + tid] = xsg[768 + tid - 32];
      }
      __syncthreads();
    }
    float* dst = cbuf + ((size_t)(b*TWIN + t))*960;
    for (int i = tid; i < 960; i += 256){
      int gi = i / 320, rem = i - gi*320;
      dst[i] = (rem < 160) ? bufw[gi*160 + rem] : bufg[gi*160 + rem - 160];
    }
  }
}

// Chunk partials over the 136 computed positions/window: 2 subs of 68.
__global__ __launch_bounds__(256) void k_partial(const float* __restrict__ yB,
    float* __restrict__ partial){
  int bt = blockIdx.x;            // b*8+t
  int sub = blockIdx.y;           // 0..1
  int b = bt >> 3, t = bt & 7;
  int tid = threadIdx.x;
  __shared__ float buf[8*160];
  int p0 = (tid >> 5) * 4;
  int n0 = (tid & 31) * 4;
  float acc[4][4] = {};
  size_t rbase = (size_t)b*GLEN;
  int gstart = t*256 + sub*68;
  int gend = gstart + 68;
  for (int gb = gstart; gb < gend; gb += 8){
    int cnt = min(8, gend - gb);
    for (int idx = tid; idx < cnt*160; idx += 256)
      buf[idx] = yB[(rbase+gb)*160 + idx];
    __syncthreads();
    for (int gi=0; gi<cnt; gi++){
      float4 yv = *(const float4*)&buf[gi*160 + p0];
      float4 bv = *(const float4*)&buf[gi*160 + 32 + n0];
      float ya[4] = {yv.x,yv.y,yv.z,yv.w};
      float ba[4] = {bv.x,bv.y,bv.z,bv.w};
      #pragma unroll
      for (int i=0;i<4;i++)
        #pragma unroll
        for (int j=0;j<4;j++)
          acc[i][j] += ya[i]*ba[j];
    }
    __syncthreads();
  }
  size_t pb = ((size_t)bt*2 + sub)*4096;
  #pragma unroll
  for (int i=0;i<4;i++)
    #pragma unroll
    for (int j=0;j<4;j++)
      partial[pb + (p0+i)*128 + n0+j] = acc[i][j];
}

// Suffix-sum + const-tail + inline boundary deltas.
__global__ __launch_bounds__(256) void k_suffix(const float* __restrict__ partial,
    const float* __restrict__ cB, const float* __restrict__ cbuf,
    float* __restrict__ feat){
  int b = blockIdx.y;
  int e = blockIdx.x*256 + threadIdx.x;   // 0..4095
  int p = e >> 7, n = e & 127;
  float s = 0.f;
  for (int t = TWIN-1; t >= 0; t--){
    int bt = b*TWIN + t;
    size_t pb = (size_t)bt*2*4096;
    s += partial[pb + e] + partial[pb + 4096 + e];
    const float* cb_ = cB + (size_t)bt*160;
    s += cb_[p] * cb_[32 + n];
    float f = s;
    if (t > 0){
      const float* cw_ = cbuf + (size_t)bt*960;
      #pragma unroll
      for (int gi=0; gi<3; gi++){
        const float* rw = cw_ + gi*320;
        f += rw[p]*rw[32+n] - rw[160+p]*rw[192+n];
      }
    }
    feat[(size_t)bt*4096 + e] = f;
  }
}

// Classifier: 4x4 register-tiled, grid (32 bt-quads, 25 k-quads).
__global__ __launch_bounds__(256) void k_classifier(const float* __restrict__ feat,
    const float* __restrict__ cls_w, const float* __restrict__ cls_b,
    float* __restrict__ out){
  int bt0 = blockIdx.x*4;
  int k0  = blockIdx.y*4;
  int tid = threadIdx.x, wid = tid >> 6, lane = tid & 63;
  float acc[4][4] = {};
  int j0 = wid*1024;
  #pragma unroll
  for (int it = 0; it < 4; it++){
    int j = j0 + it*256 + lane*4;
    float4 f4[4], w4[4];
    #pragma unroll
    for (int i=0;i<4;i++) f4[i] = *(const float4*)(feat + (size_t)(bt0+i)*4096 + j);
    #pragma unroll
    for (int k=0;k<4;k++) w4[k] = *(const float4*)(cls_w + (size_t)(k0+k)*4096 + j);
    #pragma unroll
    for (int i=0;i<4;i++)
      #pragma unroll
      for (int k=0;k<4;k++)
        acc[i][k] += f4[i].x*w4[k].x + f4[i].y*w4[k].y
                   + f4[i].z*w4[k].z + f4[i].w*w4[k].w;
  }
  #pragma unroll
  for (int i=0;i<4;i++)
    #pragma unroll
    for (int k=0;k<4;k++)
      #pragma unroll
      for (int o=32; o>0; o>>=1)
        acc[i][k] += __shfl_down(acc[i][k], o, 64);
  __shared__ float part[4][16];
  if (lane == 0){
    #pragma unroll
    for (int i=0;i<4;i++)
      #pragma unroll
      for (int k=0;k<4;k++)
        part[wid][i*4+k] = acc[i][k];
  }
  __syncthreads();
  if (tid < 16){
    int i = tid >> 2, k = tid & 3;
    float s = part[0][tid] + part[1][tid] + part[2][tid] + part[3][tid];
    out[(size_t)(bt0+i)*100 + k0 + k] = s + cls_b[k0+k];
  }
}

extern "C" void kernel_launch(void* const* d_in, const int* in_sizes, int n_in,
                              void* d_out, int out_size, void* d_ws, size_t ws_size,
                              hipStream_t stream){
  const float* inputs    = (const float*)d_in[0];
  const float* in_proj_w = (const float*)d_in[1];
  const float* conv_w    = (const float*)d_in[2];
  const float* conv_b    = (const float*)d_in[3];
  const float* dt_bias   = (const float*)d_in[4];
  const float* A_log     = (const float*)d_in[5];
  const float* cls_w     = (const float*)d_in[6];
  const float* cls_b     = (const float*)d_in[7];
  float* out = (float*)d_out;

  unsigned short* projh= (unsigned short*)d_ws;                 // MTOT*896 bf16
  float* dtraw         = (float*)(projh + (size_t)MTOT*NCC);    // NVALID*24 f32 (compact)
  float* wbuf          = dtraw + (size_t)NVALID*NH;             // MTOT*24 f32
  unsigned short* inh  = (unsigned short*)(wbuf + (size_t)MTOT*NH); // NVALID*192 bf16
  unsigned short* wh   = inh + (size_t)NVALID*DMODEL;           // NCC*192 bf16
  float* yB            = (float*)(wh + (size_t)NCC*DMODEL);     // MTOT*160 f32
  float* partial       = yB + (size_t)MTOT*160;                 // 256*4096 f32
  float* feat          = partial + (size_t)256*4096;            // 128*4096 f32
  float* ptab          = feat + (size_t)128*4096;               // 8*920 f32
  float* wsum          = ptab + (size_t)8*920;                  // 128*24 f32
  float* cB            = wsum + (size_t)128*NH;                 // 128*160 f32
  float* cbuf          = cB + (size_t)128*160;                  // 128*960 f32
  size_t need = (size_t)((char*)(cbuf + (size_t)128*960) - (char*)d_ws);
  if (ws_size < need) return;

  k_build      <<<1172, 256, 0, stream>>>(inputs, in_proj_w, inh, wh, ptab, dtraw);
  k_gemmall    <<<1408, 256, 0, stream>>>(inh, wh, ptab, dtraw, dt_bias, A_log,
                                          projh, wbuf, wsum);
  k_foldall    <<<784, 256, 0, stream>>>(projh, conv_w, conv_b, wbuf, ptab, wsum, yB, cB, cbuf);
  k_partial    <<<dim3(BATCH*TWIN, 2), 256, 0, stream>>>(yB, partial);
  k_suffix     <<<dim3(16, BATCH), 256, 0, stream>>>(partial, cB, cbuf, feat);
  k_classifier <<<dim3(32, 25), 256, 0, stream>>>(feat, cls_w, cls_b, out);
}

// Round 17
// 153.063 us; speedup vs baseline: 2.7619x; 1.0515x over previous
//
#include <hip/hip_runtime.h>
#include <math.h>

#define BATCH 16
#define TWIN 8
#define SEQIN 129
#define DMODEL 192
#define GLEN 2048           // TWIN*256
#define NH 24
#define HD 32
#define DS 128
#define NCC 896             // conv channels (x | B); dt handled separately
#define MTOT (BATCH*GLEN)   // 32768
#define NVALID (BATCH*TWIN*128) // 16384 rows with real input (s<128)
#define PADK 40             // GEMM LDS row pitch in bf16

typedef __attribute__((ext_vector_type(8))) short bf16x8;
typedef __attribute__((ext_vector_type(4))) float f32x4;

__device__ __forceinline__ float softplus_f(float x){
  return x > 20.f ? x : log1pf(expf(x));
}
__device__ __forceinline__ float silu_f(float x){
  return x / (1.f + __expf(-x));
}
__device__ __forceinline__ unsigned short tobf16(float f){
  union { float f; unsigned u; } v; v.f = f;
  unsigned r = v.u + 0x7FFF + ((v.u >> 16) & 1);
  return (unsigned short)(r >> 16);
}
__device__ __forceinline__ float frombf16(unsigned short u){
  union { unsigned u; float f; } v; v.u = ((unsigned)u) << 16; return v.f;
}
__device__ __forceinline__ bf16x8 pack8(float4 a, float4 b){
  bf16x8 r;
  r[0]=(short)tobf16(a.x); r[1]=(short)tobf16(a.y);
  r[2]=(short)tobf16(a.z); r[3]=(short)tobf16(a.w);
  r[4]=(short)tobf16(b.x); r[5]=(short)tobf16(b.y);
  r[6]=(short)tobf16(b.z); r[7]=(short)tobf16(b.w);
  return r;
}

// k_build: vectorized input cast (768 blocks, 16 elems/thread) + bf16 weight
// copy (84) + ptab (64) + compact dt GEMM (256). 1172 blocks total.
__global__ __launch_bounds__(256) void k_build(const float* __restrict__ in,
    const float* __restrict__ inw, unsigned short* __restrict__ inh,
    unsigned short* __restrict__ wh, float* __restrict__ ptab,
    float* __restrict__ dtraw){
  __shared__ float smem[2048];
  int bx = blockIdx.x;
  int tid = threadIdx.x;
  if (bx < 768){
    // compact bf16 cast: idx multiple of 16; 192%16==0 so chunk stays in-row
    int idx = (bx*256 + tid)*16;      // < NVALID*DMODEL = 3145728 exactly
    int v = idx / DMODEL;             // compact row: bt*128 + s
    int d = idx - v*DMODEL;
    int bt = v >> 7, s = v & 127;
    const float* src = in + ((size_t)bt*SEQIN + s + 1)*DMODEL + d;
    float4 a0 = *(const float4*)src;
    float4 a1 = *(const float4*)(src+4);
    float4 a2 = *(const float4*)(src+8);
    float4 a3 = *(const float4*)(src+12);
    *(bf16x8*)&inh[idx]   = pack8(a0, a1);
    *(bf16x8*)&inh[idx+8] = pack8(a2, a3);
  } else if (bx < 852){
    int idx = ((bx-768)*256 + tid)*8;  // < NCC*DMODEL = 172032 exactly
    const float* src = inw + (size_t)768*DMODEL + idx;
    float4 a = *(const float4*)src;
    float4 b = *(const float4*)(src+4);
    *(bf16x8*)&wh[idx] = pack8(a, b);
  } else if (bx < 916){
    // ptab[t][e] = sum_d PE[t][d]*W[row(e)][d]  (fp32)
    float* pe = smem;
    int pb = bx - 852;            // 0..63
    int t = pb >> 3, eslice = pb & 7;
    if (tid < DMODEL){
      int d = tid;
      float div = expf(-(float)(d & ~1) * (logf(10000.f)/(float)DMODEL));
      float ang = (float)t * div;
      pe[d] = (d & 1) ? cosf(ang) : sinf(ang);
    }
    __syncthreads();
    int e0 = eslice*115;
    int e1 = min(920, e0 + 115);
    for (int e = e0 + tid; e < e1; e += 256){
      int row = (e < 896) ? (768 + e) : (1792 + (e - 896));
      const float* wr = inw + (size_t)row*DMODEL;
      float s = 0.f;
      #pragma unroll 4
      for (int d = 0; d < DMODEL; d++)
        s += pe[d] * wr[d];
      ptab[t*920 + e] = s;
    }
  } else {
    // fp32 GEMM for 24 dt channels, compact rows, NO ptab epilogue
    float* As = smem;          // [16][64]
    float* Bs = smem + 1024;
    int idx = bx - 916;                // 0..255
    int m0 = idx*64;                   // compact row base
    int bt = m0 >> 7, srow = m0 & 127;
    int ty = tid >> 4, tx = tid & 15;
    int lr = tid >> 2, lq = tid & 3;
    float acc[4][4] = {};
    for (int k0 = 0; k0 < DMODEL; k0 += 16){
      float4 av = *(const float4*)(in + ((size_t)bt*SEQIN + srow + 1 + lr)*DMODEL + k0 + lq*4);
      As[(lq*4+0)*64+lr] = av.x; As[(lq*4+1)*64+lr] = av.y;
      As[(lq*4+2)*64+lr] = av.z; As[(lq*4+3)*64+lr] = av.w;
      float4 bv = make_float4(0.f,0.f,0.f,0.f);
      if (lr < NH) bv = *(const float4*)(inw + (size_t)(1792+lr)*DMODEL + k0 + lq*4);
      Bs[(lq*4+0)*64+lr] = bv.x; Bs[(lq*4+1)*64+lr] = bv.y;
      Bs[(lq*4+2)*64+lr] = bv.z; Bs[(lq*4+3)*64+lr] = bv.w;
      __syncthreads();
      #pragma unroll
      for (int kk = 0; kk < 16; kk++){
        float4 a = *(const float4*)&As[kk*64 + ty*4];
        float4 bq = *(const float4*)&Bs[kk*64 + tx*4];
        float avr[4] = {a.x, a.y, a.z, a.w};
        float bvr[4] = {bq.x, bq.y, bq.z, bq.w};
        #pragma unroll
        for (int i=0;i<4;i++)
          #pragma unroll
          for (int j=0;j<4;j++)
            acc[i][j] += avr[i]*bvr[j];
      }
      __syncthreads();
    }
    #pragma unroll
    for (int i=0;i<4;i++){
      int m = m0 + ty*4 + i;
      #pragma unroll
      for (int j=0;j<4;j++){
        int n = tx*4 + j;
        if (n < NH) dtraw[(size_t)m*NH + n] = acc[i][j];
      }
    }
  }
}

// Fused: bf16 MFMA GEMM on compact inh (+ptab epilogue) + projh pad fill
// + scan_w (independent of GEMM blocks; depends only on k_build outputs).
__global__ __launch_bounds__(256) void k_gemmall(const unsigned short* __restrict__ inh,
    const unsigned short* __restrict__ wh, const float* __restrict__ ptab,
    const float* __restrict__ dtraw, const float* __restrict__ dt_bias,
    const float* __restrict__ A_log, unsigned short* __restrict__ projh,
    float* __restrict__ wbuf, float* __restrict__ wsum){
  __shared__ char smem[20480];
  int bx = blockIdx.x;
  int tid = threadIdx.x;
  if (bx < 896){
    unsigned short* As = (unsigned short*)smem;
    unsigned short* Bs = As + 128*PADK;
    int mt = bx & 127;              // compact tile = bt index
    int n0 = (bx >> 7)*128;
    int t = mt & 7;
    size_t msrc = (size_t)mt*128;
    size_t mdst = (size_t)(mt >> 3)*GLEN + (size_t)t*256;
    int wid = tid >> 6, lane = tid & 63;
    int wm = (wid >> 1)*64, wn = (wid & 1)*64;
    int quad = lane >> 4, lm = lane & 15;
    int sr = tid >> 2, sq = tid & 3;
    f32x4 acc[4][4];
    #pragma unroll
    for (int i=0;i<4;i++)
      #pragma unroll
      for (int j=0;j<4;j++) acc[i][j] = (f32x4){0.f,0.f,0.f,0.f};
    for (int k0 = 0; k0 < DMODEL; k0 += 32){
      #pragma unroll
      for (int half=0; half<2; half++){
        int r = sr + half*64;
        *(bf16x8*)&As[r*PADK + sq*8] =
          *(const bf16x8*)&inh[(msrc + r)*DMODEL + k0 + sq*8];
        *(bf16x8*)&Bs[r*PADK + sq*8] =
          *(const bf16x8*)&wh[(size_t)(n0+r)*DMODEL + k0 + sq*8];
      }
      __syncthreads();
      bf16x8 aF[4], bF[4];
      #pragma unroll
      for (int i=0;i<4;i++){
        aF[i] = *(const bf16x8*)&As[(wm + i*16 + lm)*PADK + quad*8];
        bF[i] = *(const bf16x8*)&Bs[(wn + i*16 + lm)*PADK + quad*8];
      }
      #pragma unroll
      for (int i=0;i<4;i++)
        #pragma unroll
        for (int j=0;j<4;j++)
          acc[i][j] = __builtin_amdgcn_mfma_f32_16x16x32_bf16(aF[i], bF[j], acc[i][j], 0,0,0);
      __syncthreads();
    }
    float ptn[4];
    #pragma unroll
    for (int j=0;j<4;j++) ptn[j] = ptab[t*920 + n0 + wn + lm + j*16];
    #pragma unroll
    for (int i=0;i<4;i++){
      #pragma unroll
      for (int r=0;r<4;r++){
        int m = wm + i*16 + quad*4 + r;
        unsigned short* dst = projh + (mdst + m)*NCC + n0 + wn + lm;
        #pragma unroll
        for (int j=0;j<4;j++)
          dst[j*16] = tobf16(acc[i][j][r] + ptn[j]);
      }
    }
  } else if (bx < 1024){
    // pad fill: projh rows s in {128..135, 252..255}
    float* pt = (float*)smem;
    int bt = bx - 896;             // 0..127
    int b = bt >> 3, t = bt & 7;
    for (int e = tid; e < NCC; e += 256) pt[e] = ptab[t*920 + e];
    __syncthreads();
    size_t base = (size_t)b*GLEN + t*256;
    for (int i = tid; i < 12*224; i += 256){
      int r = i / 224, c4 = (i - r*224)*4;
      int s = (r < 8) ? (128 + r) : (244 + r);
      ushort4 v;
      v.x = tobf16(pt[c4+0]); v.y = tobf16(pt[c4+1]);
      v.z = tobf16(pt[c4+2]); v.w = tobf16(pt[c4+3]);
      *(ushort4*)&projh[(base + s)*NCC + c4] = v;
    }
  } else {
    // scan_w: per (b,h) decay weights + const-tail sums
    float* wtot = (float*)smem;        // 4
    float* sred = (float*)smem + 4;    // 256
    int idx = bx - 1024;               // 0..383
    int h = idx % NH, b = idx / NH;
    int lane = tid & 63, wid = tid >> 6;
    int tw = tid >> 5, q = tid & 31;
    float dtb = dt_bias[h];
    float negA = -expf(A_log[h]);
    float off = ptab[tw*920 + 896 + h] + dtb;
    float dtv[8], pre[8];
    float run = 0.f;
    if (q < 16){
      size_t rb = ((size_t)(b*TWIN + tw)*128 + q*8)*NH + h;
      #pragma unroll
      for (int i=0;i<8;i++){
        float dt = softplus_f(dtraw[rb + (size_t)i*NH] + off);
        run += dt * negA;
        dtv[i] = dt; pre[i] = run;
      }
    } else {
      float dt = softplus_f(off);
      #pragma unroll
      for (int i=0;i<8;i++){
        run += dt * negA;
        dtv[i] = dt; pre[i] = run;
      }
    }
    float v = run;
    #pragma unroll
    for (int o=1; o<64; o<<=1){
      float u = __shfl_up(v, o, 64);
      if (lane >= o) v += u;
    }
    if (lane == 63) wtot[wid] = v;
    __syncthreads();
    float base = 0.f, total = 0.f;
    #pragma unroll
    for (int w2=0; w2<4; w2++){
      float tv = wtot[w2];
      if (w2 < wid) base += tv;
      total += tv;
    }
    float excl = base + v - run;
    float ls = 0.f;
    size_t gb = (size_t)b*GLEN + tw*256 + q*8;
    #pragma unroll
    for (int i=0;i<8;i++){
      float w = expf(total - (excl + pre[i])) * dtv[i];
      if (q < 17) wbuf[(gb + i)*NH + h] = w;
      else ls += w;
    }
    sred[tid] = ls;
    __syncthreads();
    if (q == 17){
      float acc = ls;
      for (int r = 18; r < 32; r++) acc += sred[tw*32 + r];
      wsum[((size_t)b*TWIN + tw)*NH + h] = acc;
    }
  }
}

// Fused: per-strip fold (544) + const-tail rows (128) + boundary vectors (112).
__global__ __launch_bounds__(256) void k_foldall(const unsigned short* __restrict__ projh,
    const float* __restrict__ conv_w, const float* __restrict__ conv_b,
    const float* __restrict__ wbuf, const float* __restrict__ ptab,
    const float* __restrict__ wsum, float* __restrict__ yB,
    float* __restrict__ cB, float* __restrict__ cbuf){
  __shared__ float smem[2800];
  int bx = blockIdx.x;
  int tid = threadIdx.x;
  if (bx < 544){
    int wave = tid >> 6, lane = tid & 63;
    int b = bx / 34;
    int strip = (bx % 34)*4 + wave;     // 0..135
    int tw = strip / 17, k17 = strip - tw*17;
    int g0 = tw*256 + k17*8;
    size_t rbase = (size_t)b*GLEN;
    float cb[7][2], cw[7][2][4];
    #pragma unroll
    for (int k=0;k<7;k++){
      int c = 2*lane + 128*k;
      float2 t = *(const float2*)&conv_b[c];
      cb[k][0]=t.x; cb[k][1]=t.y;
      float4 w0 = *(const float4*)&conv_w[c*4];
      float4 w1 = *(const float4*)&conv_w[(c+1)*4];
      cw[k][0][0]=w0.x; cw[k][0][1]=w0.y; cw[k][0][2]=w0.z; cw[k][0][3]=w0.w;
      cw[k][1][0]=w1.x; cw[k][1][1]=w1.y; cw[k][1][2]=w1.z; cw[k][1][3]=w1.w;
    }
    float h0[7][2], h1[7][2], h2[7][2];
    #pragma unroll
    for (int k=0;k<7;k++){
      h0[k][0]=h0[k][1]=h1[k][0]=h1[k][1]=h2[k][0]=h2[k][1]=0.f;
    }
    if (g0 >= 3){
      #pragma unroll
      for (int k=0;k<7;k++){
        int c = 2*lane + 128*k;
        ushort2 p0 = *(const ushort2*)&projh[(rbase+g0-3)*NCC + c];
        ushort2 p1 = *(const ushort2*)&projh[(rbase+g0-2)*NCC + c];
        ushort2 p2 = *(const ushort2*)&projh[(rbase+g0-1)*NCC + c];
        h0[k][0]=frombf16(p0.x); h0[k][1]=frombf16(p0.y);
        h1[k][0]=frombf16(p1.x); h1[k][1]=frombf16(p1.y);
        h2[k][0]=frombf16(p2.x); h2[k][1]=frombf16(p2.y);
      }
    }
    #pragma unroll
    for (int i=0;i<8;i++){
      size_t row = rbase + g0 + i;
      float wreg = (lane < NH) ? wbuf[row*NH + lane] : 0.f;
      float cur[7][2];
      #pragma unroll
      for (int k=0;k<7;k++){
        int c = 2*lane + 128*k;
        ushort2 pv = *(const ushort2*)&projh[row*NCC + c];
        cur[k][0]=frombf16(pv.x); cur[k][1]=frombf16(pv.y);
      }
      float py0=0.f, py1=0.f, b0v=0.f, b1v=0.f;
      #pragma unroll
      for (int k=0;k<7;k++){
        float a0 = cb[k][0] + h0[k][0]*cw[k][0][0] + h1[k][0]*cw[k][0][1]
                            + h2[k][0]*cw[k][0][2] + cur[k][0]*cw[k][0][3];
        float a1 = cb[k][1] + h0[k][1]*cw[k][1][0] + h1[k][1]*cw[k][1][1]
                            + h2[k][1]*cw[k][1][2] + cur[k][1]*cw[k][1][3];
        float s0 = silu_f(a0), s1 = silu_f(a1);
        if (k < 6){
          float wh_ = __shfl(wreg, (lane>>4) + 4*k, 64);
          py0 += wh_*s0; py1 += wh_*s1;
        } else { b0v = s0; b1v = s1; }
      }
      py0 += __shfl_xor(py0, 16, 64); py0 += __shfl_xor(py0, 32, 64);
      py1 += __shfl_xor(py1, 16, 64); py1 += __shfl_xor(py1, 32, 64);
      float* dst = yB + row*160;
      if (lane < 16) *(float2*)&dst[2*lane] = make_float2(py0, py1);
      *(float2*)&dst[32 + 2*lane] = make_float2(b0v, b1v);
      #pragma unroll
      for (int k=0;k<7;k++){
        h0[k][0]=h1[k][0]; h0[k][1]=h1[k][1];
        h1[k][0]=h2[k][0]; h1[k][1]=h2[k][1];
        h2[k][0]=cur[k][0]; h2[k][1]=cur[k][1];
      }
    }
  } else if (bx < 672){
    float* Xc = smem;            // 896
    float* Ws = smem + 896;      // 24
    int idx = bx - 544;
    int t = idx & 7, b = idx >> 3;
    for (int c = tid; c < NCC; c += 256){
      float4 w = *(const float4*)&conv_w[c*4];
      float sw = w.x + w.y + w.z + w.w;
      float a = conv_b[c] + frombf16(tobf16(ptab[t*920 + c])) * sw;
      Xc[c] = silu_f(a);
    }
    if (tid < NH) Ws[tid] = wsum[((size_t)b*TWIN + t)*NH + tid];
    __syncthreads();
    float* dst = cB + ((size_t)(b*TWIN + t))*160;
    if (tid < 32){
      float y = 0.f;
      #pragma unroll
      for (int h=0;h<NH;h++) y += Ws[h]*Xc[h*32 + tid];
      dst[tid] = y;
    } else if (tid < 160){
      dst[tid] = Xc[768 + tid - 32];
    }
  } else {
    float* xsw  = smem;          // 896
    float* xsg  = smem + 896;    // 896
    float* wv   = smem + 1792;   // 24
    float* bufw = smem + 1816;   // 480
    float* bufg = smem + 2296;   // 480
    int idx = bx - 672;          // 0..111
    int b = idx / 7, t = idx % 7 + 1;
    size_t rbase = (size_t)b*GLEN;
    int g0 = t*256;
    for (int gi=0; gi<3; gi++){
      int g = g0 + gi;
      if (tid < NH) wv[tid] = wbuf[(rbase+g)*NH + tid];
      for (int c = tid; c < NCC; c += 256){
        float aw = conv_b[c], ag = conv_b[c];
        #pragma unroll
        for (int k=0;k<4;k++){
          int gp = g - 3 + k;
          float term = frombf16(projh[(rbase+gp)*NCC + c]) * conv_w[c*4+k];
          ag += term;
          if (gp >= g0) aw += term;
        }
        xsw[c] = silu_f(aw);
        xsg[c] = silu_f(ag);
      }
      __syncthreads();
      if (tid < 32){
        float yw = 0.f, yg = 0.f;
        #pragma unroll
        for (int h=0;h<NH;h++){ yw += wv[h]*xsw[h*32+tid]; yg += wv[h]*xsg[h*32+tid]; }
        bufw[gi*160 + tid] = yw;
        bufg[gi*160 + tid] = yg;
      } else if (tid < 160){
        bufw[gi*160 + tid] = xsw[768 + tid - 32];
        bufg[gi*160 + tid] = xsg[768 + tid - 32];
      }
      __syncthreads();
    }
    float* dst = cbuf + ((size_t)(b*TWIN + t))*960;
    for (int i = tid; i < 960; i += 256){
      int gi = i / 320, rem = i - gi*320;
      dst[i] = (rem < 160) ? bufw[gi*160 + rem] : bufg[gi*160 + rem - 160];
    }
  }
}

// Chunk partials, barrier-free: direct global loads (yv broadcasts within a
// 32-lane group; bv rows are coalesced). 4 subs of 17 positions per window.
__global__ __launch_bounds__(256) void k_partial(const float* __restrict__ yB,
    float* __restrict__ partial){
  int bt = blockIdx.x;            // b*8+t
  int sub = blockIdx.y;           // 0..3
  int b = bt >> 3, t = bt & 7;
  int tid = threadIdx.x;
  int p0 = (tid >> 5) * 4;
  int n0 = (tid & 31) * 4;
  float acc[4][4] = {};
  size_t rbase = (size_t)b*GLEN;
  int gstart = t*256 + sub*17;
  #pragma unroll 4
  for (int gi = 0; gi < 17; gi++){
    const float* row = yB + (rbase + gstart + gi)*160;
    float4 yv = *(const float4*)(row + p0);
    float4 bv = *(const float4*)(row + 32 + n0);
    float ya[4] = {yv.x,yv.y,yv.z,yv.w};
    float ba[4] = {bv.x,bv.y,bv.z,bv.w};
    #pragma unroll
    for (int i=0;i<4;i++)
      #pragma unroll
      for (int j=0;j<4;j++)
        acc[i][j] += ya[i]*ba[j];
  }
  size_t pb = ((size_t)bt*4 + sub)*4096;
  #pragma unroll
  for (int i=0;i<4;i++)
    #pragma unroll
    for (int j=0;j<4;j++)
      partial[pb + (p0+i)*128 + n0+j] = acc[i][j];
}

// Suffix-sum + const-tail + inline boundary deltas.
__global__ __launch_bounds__(256) void k_suffix(const float* __restrict__ partial,
    const float* __restrict__ cB, const float* __restrict__ cbuf,
    float* __restrict__ feat){
  int b = blockIdx.y;
  int e = blockIdx.x*256 + threadIdx.x;   // 0..4095
  int p = e >> 7, n = e & 127;
  float s = 0.f;
  for (int t = TWIN-1; t >= 0; t--){
    int bt = b*TWIN + t;
    size_t pb = (size_t)bt*4*4096;
    s += partial[pb + e] + partial[pb + 4096 + e]
       + partial[pb + 2*4096 + e] + partial[pb + 3*4096 + e];
    const float* cb_ = cB + (size_t)bt*160;
    s += cb_[p] * cb_[32 + n];
    float f = s;
    if (t > 0){
      const float* cw_ = cbuf + (size_t)bt*960;
      #pragma unroll
      for (int gi=0; gi<3; gi++){
        const float* rw = cw_ + gi*320;
        f += rw[p]*rw[32+n] - rw[160+p]*rw[192+n];
      }
    }
    feat[(size_t)bt*4096 + e] = f;
  }
}

// Classifier: 4x4 register-tiled, grid (32 bt-quads, 25 k-quads).
__global__ __launch_bounds__(256) void k_classifier(const float* __restrict__ feat,
    const float* __restrict__ cls_w, const float* __restrict__ cls_b,
    float* __restrict__ out){
  int bt0 = blockIdx.x*4;
  int k0  = blockIdx.y*4;
  int tid = threadIdx.x, wid = tid >> 6, lane = tid & 63;
  float acc[4][4] = {};
  int j0 = wid*1024;
  #pragma unroll
  for (int it = 0; it < 4; it++){
    int j = j0 + it*256 + lane*4;
    float4 f4[4], w4[4];
    #pragma unroll
    for (int i=0;i<4;i++) f4[i] = *(const float4*)(feat + (size_t)(bt0+i)*4096 + j);
    #pragma unroll
    for (int k=0;k<4;k++) w4[k] = *(const float4*)(cls_w + (size_t)(k0+k)*4096 + j);
    #pragma unroll
    for (int i=0;i<4;i++)
      #pragma unroll
      for (int k=0;k<4;k++)
        acc[i][k] += f4[i].x*w4[k].x + f4[i].y*w4[k].y
                   + f4[i].z*w4[k].z + f4[i].w*w4[k].w;
  }
  #pragma unroll
  for (int i=0;i<4;i++)
    #pragma unroll
    for (int k=0;k<4;k++)
      #pragma unroll
      for (int o=32; o>0; o>>=1)
        acc[i][k] += __shfl_down(acc[i][k], o, 64);
  __shared__ float part[4][16];
  if (lane == 0){
    #pragma unroll
    for (int i=0;i<4;i++)
      #pragma unroll
      for (int k=0;k<4;k++)
        part[wid][i*4+k] = acc[i][k];
  }
  __syncthreads();
  if (tid < 16){
    int i = tid >> 2, k = tid & 3;
    float s = part[0][tid] + part[1][tid] + part[2][tid] + part[3][tid];
    out[(size_t)(bt0+i)*100 + k0 + k] = s + cls_b[k0+k];
  }
}

extern "C" void kernel_launch(void* const* d_in, const int* in_sizes, int n_in,
                              void* d_out, int out_size, void* d_ws, size_t ws_size,
                              hipStream_t stream){
  const float* inputs    = (const float*)d_in[0];
  const float* in_proj_w = (const float*)d_in[1];
  const float* conv_w    = (const float*)d_in[2];
  const float* conv_b    = (const float*)d_in[3];
  const float* dt_bias   = (const float*)d_in[4];
  const float* A_log     = (const float*)d_in[5];
  const float* cls_w     = (const float*)d_in[6];
  const float* cls_b     = (const float*)d_in[7];
  float* out = (float*)d_out;

  unsigned short* projh= (unsigned short*)d_ws;                 // MTOT*896 bf16
  float* dtraw         = (float*)(projh + (size_t)MTOT*NCC);    // NVALID*24 f32 (compact)
  float* wbuf          = dtraw + (size_t)NVALID*NH;             // MTOT*24 f32
  unsigned short* inh  = (unsigned short*)(wbuf + (size_t)MTOT*NH); // NVALID*192 bf16
  unsigned short* wh   = inh + (size_t)NVALID*DMODEL;           // NCC*192 bf16
  float* yB            = (float*)(wh + (size_t)NCC*DMODEL);     // MTOT*160 f32
  float* partial       = yB + (size_t)MTOT*160;                 // 512*4096 f32
  float* feat          = partial + (size_t)512*4096;            // 128*4096 f32
  float* ptab          = feat + (size_t)128*4096;               // 8*920 f32
  float* wsum          = ptab + (size_t)8*920;                  // 128*24 f32
  float* cB            = wsum + (size_t)128*NH;                 // 128*160 f32
  float* cbuf          = cB + (size_t)128*160;                  // 128*960 f32
  size_t need = (size_t)((char*)(cbuf + (size_t)128*960) - (char*)d_ws);
  if (ws_size < need) return;

  k_build      <<<1172, 256, 0, stream>>>(inputs, in_proj_w, inh, wh, ptab, dtraw);
  k_gemmall    <<<1408, 256, 0, stream>>>(inh, wh, ptab, dtraw, dt_bias, A_log,
                                          projh, wbuf, wsum);
  k_foldall    <<<784, 256, 0, stream>>>(projh, conv_w, conv_b, wbuf, ptab, wsum, yB, cB, cbuf);
  k_partial    <<<dim3(BATCH*TWIN, 4), 256, 0, stream>>>(yB, partial);
  k_suffix     <<<dim3(16, BATCH), 256, 0, stream>>>(partial, cB, cbuf, feat);
  k_classifier <<<dim3(32, 25), 256, 0, stream>>>(feat, cls_w, cls_b, out);
}

// Round 18
// 152.967 us; speedup vs baseline: 2.7636x; 1.0006x over previous
//
#include <hip/hip_runtime.h>
#include <math.h>

#define BATCH 16
#define TWIN 8
#define SEQIN 129
#define DMODEL 192
#define GLEN 2048           // TWIN*256
#define NH 24
#define HD 32
#define DS 128
#define NCC 896             // conv channels (x | B); dt handled separately
#define MTOT (BATCH*GLEN)   // 32768
#define NVALID (BATCH*TWIN*128) // 16384 rows with real input (s<128)
#define PADK 40             // GEMM LDS row pitch in bf16

typedef __attribute__((ext_vector_type(8))) short bf16x8;
typedef __attribute__((ext_vector_type(4))) float f32x4;

__device__ __forceinline__ float softplus_f(float x){
  return x > 20.f ? x : log1pf(expf(x));
}
__device__ __forceinline__ float silu_f(float x){
  return x / (1.f + __expf(-x));
}
__device__ __forceinline__ unsigned short tobf16(float f){
  union { float f; unsigned u; } v; v.f = f;
  unsigned r = v.u + 0x7FFF + ((v.u >> 16) & 1);
  return (unsigned short)(r >> 16);
}
__device__ __forceinline__ float frombf16(unsigned short u){
  union { unsigned u; float f; } v; v.u = ((unsigned)u) << 16; return v.f;
}
__device__ __forceinline__ bf16x8 pack8(float4 a, float4 b){
  bf16x8 r;
  r[0]=(short)tobf16(a.x); r[1]=(short)tobf16(a.y);
  r[2]=(short)tobf16(a.z); r[3]=(short)tobf16(a.w);
  r[4]=(short)tobf16(b.x); r[5]=(short)tobf16(b.y);
  r[6]=(short)tobf16(b.z); r[7]=(short)tobf16(b.w);
  return r;
}

// k_build: vectorized input cast (768) + bf16 weight copy (84) + ptab (64)
// + compact dt GEMM (256). 1172 blocks total.
__global__ __launch_bounds__(256) void k_build(const float* __restrict__ in,
    const float* __restrict__ inw, unsigned short* __restrict__ inh,
    unsigned short* __restrict__ wh, float* __restrict__ ptab,
    float* __restrict__ dtraw){
  __shared__ float smem[2048];
  int bx = blockIdx.x;
  int tid = threadIdx.x;
  if (bx < 768){
    int idx = (bx*256 + tid)*16;      // < NVALID*DMODEL exactly
    int v = idx / DMODEL;             // compact row: bt*128 + s
    int d = idx - v*DMODEL;
    int bt = v >> 7, s = v & 127;
    const float* src = in + ((size_t)bt*SEQIN + s + 1)*DMODEL + d;
    float4 a0 = *(const float4*)src;
    float4 a1 = *(const float4*)(src+4);
    float4 a2 = *(const float4*)(src+8);
    float4 a3 = *(const float4*)(src+12);
    *(bf16x8*)&inh[idx]   = pack8(a0, a1);
    *(bf16x8*)&inh[idx+8] = pack8(a2, a3);
  } else if (bx < 852){
    int idx = ((bx-768)*256 + tid)*8;  // < NCC*DMODEL exactly
    const float* src = inw + (size_t)768*DMODEL + idx;
    float4 a = *(const float4*)src;
    float4 b = *(const float4*)(src+4);
    *(bf16x8*)&wh[idx] = pack8(a, b);
  } else if (bx < 916){
    // ptab[t][e] = sum_d PE[t][d]*W[row(e)][d]  (fp32)
    float* pe = smem;
    int pb = bx - 852;            // 0..63
    int t = pb >> 3, eslice = pb & 7;
    if (tid < DMODEL){
      int d = tid;
      float div = expf(-(float)(d & ~1) * (logf(10000.f)/(float)DMODEL));
      float ang = (float)t * div;
      pe[d] = (d & 1) ? cosf(ang) : sinf(ang);
    }
    __syncthreads();
    int e0 = eslice*115;
    int e1 = min(920, e0 + 115);
    for (int e = e0 + tid; e < e1; e += 256){
      int row = (e < 896) ? (768 + e) : (1792 + (e - 896));
      const float* wr = inw + (size_t)row*DMODEL;
      float s = 0.f;
      #pragma unroll 4
      for (int d = 0; d < DMODEL; d++)
        s += pe[d] * wr[d];
      ptab[t*920 + e] = s;
    }
  } else {
    // fp32 GEMM for 24 dt channels, compact rows
    float* As = smem;          // [16][64]
    float* Bs = smem + 1024;
    int idx = bx - 916;                // 0..255
    int m0 = idx*64;
    int bt = m0 >> 7, srow = m0 & 127;
    int ty = tid >> 4, tx = tid & 15;
    int lr = tid >> 2, lq = tid & 3;
    float acc[4][4] = {};
    for (int k0 = 0; k0 < DMODEL; k0 += 16){
      float4 av = *(const float4*)(in + ((size_t)bt*SEQIN + srow + 1 + lr)*DMODEL + k0 + lq*4);
      As[(lq*4+0)*64+lr] = av.x; As[(lq*4+1)*64+lr] = av.y;
      As[(lq*4+2)*64+lr] = av.z; As[(lq*4+3)*64+lr] = av.w;
      float4 bv = make_float4(0.f,0.f,0.f,0.f);
      if (lr < NH) bv = *(const float4*)(inw + (size_t)(1792+lr)*DMODEL + k0 + lq*4);
      Bs[(lq*4+0)*64+lr] = bv.x; Bs[(lq*4+1)*64+lr] = bv.y;
      Bs[(lq*4+2)*64+lr] = bv.z; Bs[(lq*4+3)*64+lr] = bv.w;
      __syncthreads();
      #pragma unroll
      for (int kk = 0; kk < 16; kk++){
        float4 a = *(const float4*)&As[kk*64 + ty*4];
        float4 bq = *(const float4*)&Bs[kk*64 + tx*4];
        float avr[4] = {a.x, a.y, a.z, a.w};
        float bvr[4] = {bq.x, bq.y, bq.z, bq.w};
        #pragma unroll
        for (int i=0;i<4;i++)
          #pragma unroll
          for (int j=0;j<4;j++)
            acc[i][j] += avr[i]*bvr[j];
      }
      __syncthreads();
    }
    #pragma unroll
    for (int i=0;i<4;i++){
      int m = m0 + ty*4 + i;
      #pragma unroll
      for (int j=0;j<4;j++){
        int n = tx*4 + j;
        if (n < NH) dtraw[(size_t)m*NH + n] = acc[i][j];
      }
    }
  }
}

// Fused: bf16 MFMA GEMM on compact inh (+ptab epilogue) + projh pad fill + scan_w.
__global__ __launch_bounds__(256) void k_gemmall(const unsigned short* __restrict__ inh,
    const unsigned short* __restrict__ wh, const float* __restrict__ ptab,
    const float* __restrict__ dtraw, const float* __restrict__ dt_bias,
    const float* __restrict__ A_log, unsigned short* __restrict__ projh,
    float* __restrict__ wbuf, float* __restrict__ wsum){
  __shared__ char smem[20480];
  int bx = blockIdx.x;
  int tid = threadIdx.x;
  if (bx < 896){
    unsigned short* As = (unsigned short*)smem;
    unsigned short* Bs = As + 128*PADK;
    int mt = bx & 127;              // compact tile = bt index
    int n0 = (bx >> 7)*128;
    int t = mt & 7;
    size_t msrc = (size_t)mt*128;
    size_t mdst = (size_t)(mt >> 3)*GLEN + (size_t)t*256;
    int wid = tid >> 6, lane = tid & 63;
    int wm = (wid >> 1)*64, wn = (wid & 1)*64;
    int quad = lane >> 4, lm = lane & 15;
    int sr = tid >> 2, sq = tid & 3;
    f32x4 acc[4][4];
    #pragma unroll
    for (int i=0;i<4;i++)
      #pragma unroll
      for (int j=0;j<4;j++) acc[i][j] = (f32x4){0.f,0.f,0.f,0.f};
    for (int k0 = 0; k0 < DMODEL; k0 += 32){
      #pragma unroll
      for (int half=0; half<2; half++){
        int r = sr + half*64;
        *(bf16x8*)&As[r*PADK + sq*8] =
          *(const bf16x8*)&inh[(msrc + r)*DMODEL + k0 + sq*8];
        *(bf16x8*)&Bs[r*PADK + sq*8] =
          *(const bf16x8*)&wh[(size_t)(n0+r)*DMODEL + k0 + sq*8];
      }
      __syncthreads();
      bf16x8 aF[4], bF[4];
      #pragma unroll
      for (int i=0;i<4;i++){
        aF[i] = *(const bf16x8*)&As[(wm + i*16 + lm)*PADK + quad*8];
        bF[i] = *(const bf16x8*)&Bs[(wn + i*16 + lm)*PADK + quad*8];
      }
      #pragma unroll
      for (int i=0;i<4;i++)
        #pragma unroll
        for (int j=0;j<4;j++)
          acc[i][j] = __builtin_amdgcn_mfma_f32_16x16x32_bf16(aF[i], bF[j], acc[i][j], 0,0,0);
      __syncthreads();
    }
    float ptn[4];
    #pragma unroll
    for (int j=0;j<4;j++) ptn[j] = ptab[t*920 + n0 + wn + lm + j*16];
    #pragma unroll
    for (int i=0;i<4;i++){
      #pragma unroll
      for (int r=0;r<4;r++){
        int m = wm + i*16 + quad*4 + r;
        unsigned short* dst = projh + (mdst + m)*NCC + n0 + wn + lm;
        #pragma unroll
        for (int j=0;j<4;j++)
          dst[j*16] = tobf16(acc[i][j][r] + ptn[j]);
      }
    }
  } else if (bx < 1024){
    // pad fill: projh rows s in {128..135, 252..255}
    float* pt = (float*)smem;
    int bt = bx - 896;             // 0..127
    int b = bt >> 3, t = bt & 7;
    for (int e = tid; e < NCC; e += 256) pt[e] = ptab[t*920 + e];
    __syncthreads();
    size_t base = (size_t)b*GLEN + t*256;
    for (int i = tid; i < 12*224; i += 256){
      int r = i / 224, c4 = (i - r*224)*4;
      int s = (r < 8) ? (128 + r) : (244 + r);
      ushort4 v;
      v.x = tobf16(pt[c4+0]); v.y = tobf16(pt[c4+1]);
      v.z = tobf16(pt[c4+2]); v.w = tobf16(pt[c4+3]);
      *(ushort4*)&projh[(base + s)*NCC + c4] = v;
    }
  } else {
    // scan_w: per (b,h) decay weights + const-tail sums
    float* wtot = (float*)smem;        // 4
    float* sred = (float*)smem + 4;    // 256
    int idx = bx - 1024;               // 0..383
    int h = idx % NH, b = idx / NH;
    int lane = tid & 63, wid = tid >> 6;
    int tw = tid >> 5, q = tid & 31;
    float dtb = dt_bias[h];
    float negA = -expf(A_log[h]);
    float off = ptab[tw*920 + 896 + h] + dtb;
    float dtv[8], pre[8];
    float run = 0.f;
    if (q < 16){
      size_t rb = ((size_t)(b*TWIN + tw)*128 + q*8)*NH + h;
      #pragma unroll
      for (int i=0;i<8;i++){
        float dt = softplus_f(dtraw[rb + (size_t)i*NH] + off);
        run += dt * negA;
        dtv[i] = dt; pre[i] = run;
      }
    } else {
      float dt = softplus_f(off);
      #pragma unroll
      for (int i=0;i<8;i++){
        run += dt * negA;
        dtv[i] = dt; pre[i] = run;
      }
    }
    float v = run;
    #pragma unroll
    for (int o=1; o<64; o<<=1){
      float u = __shfl_up(v, o, 64);
      if (lane >= o) v += u;
    }
    if (lane == 63) wtot[wid] = v;
    __syncthreads();
    float base = 0.f, total = 0.f;
    #pragma unroll
    for (int w2=0; w2<4; w2++){
      float tv = wtot[w2];
      if (w2 < wid) base += tv;
      total += tv;
    }
    float excl = base + v - run;
    float ls = 0.f;
    size_t gb = (size_t)b*GLEN + tw*256 + q*8;
    #pragma unroll
    for (int i=0;i<8;i++){
      float w = expf(total - (excl + pre[i])) * dtv[i];
      if (q < 17) wbuf[(gb + i)*NH + h] = w;
      else ls += w;
    }
    sred[tid] = ls;
    __syncthreads();
    if (q == 17){
      float acc = ls;
      for (int r = 18; r < 32; r++) acc += sred[tw*32 + r];
      wsum[((size_t)b*TWIN + tw)*NH + h] = acc;
    }
  }
}

// Fused: fold+partial (512 blocks: (bt,sub), 34 positions each, full 136
// coverage) + const-tail rows (128) + boundary vectors (112). 752 blocks.
__global__ __launch_bounds__(256) void k_foldall(const unsigned short* __restrict__ projh,
    const float* __restrict__ conv_w, const float* __restrict__ conv_b,
    const float* __restrict__ wbuf, const float* __restrict__ ptab,
    const float* __restrict__ wsum, float* __restrict__ partial,
    float* __restrict__ cB, float* __restrict__ cbuf){
  __shared__ float smem[5440];   // 34*160 ybuf (branch A) / 2800 (B,C)
  int bx = blockIdx.x;
  int tid = threadIdx.x;
  if (bx < 512){
    // fold+partial: block = (bt, sub); waves fold 9 positions each at starts
    // {0,9,17,25} (position 25 duplicated with identical data — benign).
    int bt = bx >> 2, sub = bx & 3;
    int b = bt >> 3, t = bt & 7;
    int wave = tid >> 6, lane = tid & 63;
    int g0 = t*256 + sub*34;
    int wstart = wave*8 + (wave > 0 ? 1 : 0);   // 0,9,17,25
    int gw = g0 + wstart;
    size_t rbase = (size_t)b*GLEN;
    float* ybuf = smem;
    float cb[7][2], cw[7][2][4];
    #pragma unroll
    for (int k=0;k<7;k++){
      int c = 2*lane + 128*k;
      float2 tb = *(const float2*)&conv_b[c];
      cb[k][0]=tb.x; cb[k][1]=tb.y;
      float4 w0 = *(const float4*)&conv_w[c*4];
      float4 w1 = *(const float4*)&conv_w[(c+1)*4];
      cw[k][0][0]=w0.x; cw[k][0][1]=w0.y; cw[k][0][2]=w0.z; cw[k][0][3]=w0.w;
      cw[k][1][0]=w1.x; cw[k][1][1]=w1.y; cw[k][1][2]=w1.z; cw[k][1][3]=w1.w;
    }
    float h0[7][2], h1[7][2], h2[7][2];
    #pragma unroll
    for (int k=0;k<7;k++){
      h0[k][0]=h0[k][1]=h1[k][0]=h1[k][1]=h2[k][0]=h2[k][1]=0.f;
    }
    if (gw >= 3){
      #pragma unroll
      for (int k=0;k<7;k++){
        int c = 2*lane + 128*k;
        ushort2 p0 = *(const ushort2*)&projh[(rbase+gw-3)*NCC + c];
        ushort2 p1 = *(const ushort2*)&projh[(rbase+gw-2)*NCC + c];
        ushort2 p2 = *(const ushort2*)&projh[(rbase+gw-1)*NCC + c];
        h0[k][0]=frombf16(p0.x); h0[k][1]=frombf16(p0.y);
        h1[k][0]=frombf16(p1.x); h1[k][1]=frombf16(p1.y);
        h2[k][0]=frombf16(p2.x); h2[k][1]=frombf16(p2.y);
      }
    }
    #pragma unroll
    for (int i=0;i<9;i++){
      size_t row = rbase + gw + i;
      float wreg = (lane < NH) ? wbuf[row*NH + lane] : 0.f;
      float cur[7][2];
      #pragma unroll
      for (int k=0;k<7;k++){
        int c = 2*lane + 128*k;
        ushort2 pv = *(const ushort2*)&projh[row*NCC + c];
        cur[k][0]=frombf16(pv.x); cur[k][1]=frombf16(pv.y);
      }
      float py0=0.f, py1=0.f, b0v=0.f, b1v=0.f;
      #pragma unroll
      for (int k=0;k<7;k++){
        float a0 = cb[k][0] + h0[k][0]*cw[k][0][0] + h1[k][0]*cw[k][0][1]
                            + h2[k][0]*cw[k][0][2] + cur[k][0]*cw[k][0][3];
        float a1 = cb[k][1] + h0[k][1]*cw[k][1][0] + h1[k][1]*cw[k][1][1]
                            + h2[k][1]*cw[k][1][2] + cur[k][1]*cw[k][1][3];
        float s0 = silu_f(a0), s1 = silu_f(a1);
        if (k < 6){
          float wh_ = __shfl(wreg, (lane>>4) + 4*k, 64);
          py0 += wh_*s0; py1 += wh_*s1;
        } else { b0v = s0; b1v = s1; }
      }
      py0 += __shfl_xor(py0, 16, 64); py0 += __shfl_xor(py0, 32, 64);
      py1 += __shfl_xor(py1, 16, 64); py1 += __shfl_xor(py1, 32, 64);
      float* dst = ybuf + (wstart + i)*160;
      if (lane < 16) *(float2*)&dst[2*lane] = make_float2(py0, py1);
      *(float2*)&dst[32 + 2*lane] = make_float2(b0v, b1v);
      #pragma unroll
      for (int k=0;k<7;k++){
        h0[k][0]=h1[k][0]; h0[k][1]=h1[k][1];
        h1[k][0]=h2[k][0]; h1[k][1]=h2[k][1];
        h2[k][0]=cur[k][0]; h2[k][1]=cur[k][1];
      }
    }
    __syncthreads();
    int p0 = (tid >> 5)*4, n0 = (tid & 31)*4;
    float acc[4][4] = {};
    #pragma unroll 2
    for (int gi = 0; gi < 34; gi++){
      float4 yv = *(const float4*)&ybuf[gi*160 + p0];
      float4 bv = *(const float4*)&ybuf[gi*160 + 32 + n0];
      float ya[4] = {yv.x,yv.y,yv.z,yv.w};
      float ba[4] = {bv.x,bv.y,bv.z,bv.w};
      #pragma unroll
      for (int i=0;i<4;i++)
        #pragma unroll
        for (int j=0;j<4;j++)
          acc[i][j] += ya[i]*ba[j];
    }
    size_t pb = ((size_t)bt*4 + sub)*4096;
    #pragma unroll
    for (int i=0;i<4;i++)
      #pragma unroll
      for (int j=0;j<4;j++)
        partial[pb + (p0+i)*128 + n0+j] = acc[i][j];
  } else if (bx < 640){
    float* Xc = smem;            // 896
    float* Ws = smem + 896;      // 24
    int idx = bx - 512;
    int t = idx & 7, b = idx >> 3;
    for (int c = tid; c < NCC; c += 256){
      float4 w = *(const float4*)&conv_w[c*4];
      float sw = w.x + w.y + w.z + w.w;
      float a = conv_b[c] + frombf16(tobf16(ptab[t*920 + c])) * sw;
      Xc[c] = silu_f(a);
    }
    if (tid < NH) Ws[tid] = wsum[((size_t)b*TWIN + t)*NH + tid];
    __syncthreads();
    float* dst = cB + ((size_t)(b*TWIN + t))*160;
    if (tid < 32){
      float y = 0.f;
      #pragma unroll
      for (int h=0;h<NH;h++) y += Ws[h]*Xc[h*32 + tid];
      dst[tid] = y;
    } else if (tid < 160){
      dst[tid] = Xc[768 + tid - 32];
    }
  } else {
    float* xsw  = smem;          // 896
    float* xsg  = smem + 896;    // 896
    float* wv   = smem + 1792;   // 24
    float* bufw = smem + 1816;   // 480
    float* bufg = smem + 2296;   // 480
    int idx = bx - 640;          // 0..111
    int b = idx / 7, t = idx % 7 + 1;
    size_t rbase = (size_t)b*GLEN;
    int g0 = t*256;
    for (int gi=0; gi<3; gi++){
      int g = g0 + gi;
      if (tid < NH) wv[tid] = wbuf[(rbase+g)*NH + tid];
      for (int c = tid; c < NCC; c += 256){
        float aw = conv_b[c], ag = conv_b[c];
        #pragma unroll
        for (int k=0;k<4;k++){
          int gp = g - 3 + k;
          float term = frombf16(projh[(rbase+gp)*NCC + c]) * conv_w[c*4+k];
          ag += term;
          if (gp >= g0) aw += term;
        }
        xsw[c] = silu_f(aw);
        xsg[c] = silu_f(ag);
      }
      __syncthreads();
      if (tid < 32){
        float yw = 0.f, yg = 0.f;
        #pragma unroll
        for (int h=0;h<NH;h++){ yw += wv[h]*xsw[h*32+tid]; yg += wv[h]*xsg[h*32+tid]; }
        bufw[gi*160 + tid] = yw;
        bufg[gi*160 + tid] = yg;
      } else if (tid < 160){
        bufw[gi*160 + tid] = xsw[768 + tid - 32];
        bufg[gi*160 + tid] = xsg[768 + tid - 32];
      }
      __syncthreads();
    }
    float* dst = cbuf + ((size_t)(b*TWIN + t))*960;
    for (int i = tid; i < 960; i += 256){
      int gi = i / 320, rem = i - gi*320;
      dst[i] = (rem < 160) ? bufw[gi*160 + rem] : bufg[gi*160 + rem - 160];
    }
  }
}

// Suffix-sum + const-tail + inline boundary deltas.
__global__ __launch_bounds__(256) void k_suffix(const float* __restrict__ partial,
    const float* __restrict__ cB, const float* __restrict__ cbuf,
    float* __restrict__ feat){
  int b = blockIdx.y;
  int e = blockIdx.x*256 + threadIdx.x;   // 0..4095
  int p = e >> 7, n = e & 127;
  float s = 0.f;
  for (int t = TWIN-1; t >= 0; t--){
    int bt = b*TWIN + t;
    size_t pb = (size_t)bt*4*4096;
    s += partial[pb + e] + partial[pb + 4096 + e]
       + partial[pb + 2*4096 + e] + partial[pb + 3*4096 + e];
    const float* cb_ = cB + (size_t)bt*160;
    s += cb_[p] * cb_[32 + n];
    float f = s;
    if (t > 0){
      const float* cw_ = cbuf + (size_t)bt*960;
      #pragma unroll
      for (int gi=0; gi<3; gi++){
        const float* rw = cw_ + gi*320;
        f += rw[p]*rw[32+n] - rw[160+p]*rw[192+n];
      }
    }
    feat[(size_t)bt*4096 + e] = f;
  }
}

// Classifier: 4x4 register-tiled, grid (32 bt-quads, 25 k-quads).
__global__ __launch_bounds__(256) void k_classifier(const float* __restrict__ feat,
    const float* __restrict__ cls_w, const float* __restrict__ cls_b,
    float* __restrict__ out){
  int bt0 = blockIdx.x*4;
  int k0  = blockIdx.y*4;
  int tid = threadIdx.x, wid = tid >> 6, lane = tid & 63;
  float acc[4][4] = {};
  int j0 = wid*1024;
  #pragma unroll
  for (int it = 0; it < 4; it++){
    int j = j0 + it*256 + lane*4;
    float4 f4[4], w4[4];
    #pragma unroll
    for (int i=0;i<4;i++) f4[i] = *(const float4*)(feat + (size_t)(bt0+i)*4096 + j);
    #pragma unroll
    for (int k=0;k<4;k++) w4[k] = *(const float4*)(cls_w + (size_t)(k0+k)*4096 + j);
    #pragma unroll
    for (int i=0;i<4;i++)
      #pragma unroll
      for (int k=0;k<4;k++)
        acc[i][k] += f4[i].x*w4[k].x + f4[i].y*w4[k].y
                   + f4[i].z*w4[k].z + f4[i].w*w4[k].w;
  }
  #pragma unroll
  for (int i=0;i<4;i++)
    #pragma unroll
    for (int k=0;k<4;k++)
      #pragma unroll
      for (int o=32; o>0; o>>=1)
        acc[i][k] += __shfl_down(acc[i][k], o, 64);
  __shared__ float part[4][16];
  if (lane == 0){
    #pragma unroll
    for (int i=0;i<4;i++)
      #pragma unroll
      for (int k=0;k<4;k++)
        part[wid][i*4+k] = acc[i][k];
  }
  __syncthreads();
  if (tid < 16){
    int i = tid >> 2, k = tid & 3;
    float s = part[0][tid] + part[1][tid] + part[2][tid] + part[3][tid];
    out[(size_t)(bt0+i)*100 + k0 + k] = s + cls_b[k0+k];
  }
}

extern "C" void kernel_launch(void* const* d_in, const int* in_sizes, int n_in,
                              void* d_out, int out_size, void* d_ws, size_t ws_size,
                              hipStream_t stream){
  const float* inputs    = (const float*)d_in[0];
  const float* in_proj_w = (const float*)d_in[1];
  const float* conv_w    = (const float*)d_in[2];
  const float* conv_b    = (const float*)d_in[3];
  const float* dt_bias   = (const float*)d_in[4];
  const float* A_log     = (const float*)d_in[5];
  const float* cls_w     = (const float*)d_in[6];
  const float* cls_b     = (const float*)d_in[7];
  float* out = (float*)d_out;

  unsigned short* projh= (unsigned short*)d_ws;                 // MTOT*896 bf16
  float* dtraw         = (float*)(projh + (size_t)MTOT*NCC);    // NVALID*24 f32 (compact)
  float* wbuf          = dtraw + (size_t)NVALID*NH;             // MTOT*24 f32
  unsigned short* inh  = (unsigned short*)(wbuf + (size_t)MTOT*NH); // NVALID*192 bf16
  unsigned short* wh   = inh + (size_t)NVALID*DMODEL;           // NCC*192 bf16
  float* partial       = (float*)(wh + (size_t)NCC*DMODEL);     // 512*4096 f32
  float* feat          = partial + (size_t)512*4096;            // 128*4096 f32
  float* ptab          = feat + (size_t)128*4096;               // 8*920 f32
  float* wsum          = ptab + (size_t)8*920;                  // 128*24 f32
  float* cB            = wsum + (size_t)128*NH;                 // 128*160 f32
  float* cbuf          = cB + (size_t)128*160;                  // 128*960 f32
  size_t need = (size_t)((char*)(cbuf + (size_t)128*960) - (char*)d_ws);
  if (ws_size < need) return;

  k_build      <<<1172, 256, 0, stream>>>(inputs, in_proj_w, inh, wh, ptab, dtraw);
  k_gemmall    <<<1408, 256, 0, stream>>>(inh, wh, ptab, dtraw, dt_bias, A_log,
                                          projh, wbuf, wsum);
  k_foldall    <<<752, 256, 0, stream>>>(projh, conv_w, conv_b, wbuf, ptab, wsum,
                                         partial, cB, cbuf);
  k_suffix     <<<dim3(16, BATCH), 256, 0, stream>>>(partial, cB, cbuf, feat);
  k_classifier <<<dim3(32, 25), 256, 0, stream>>>(feat, cls_w, cls_b, out);
}